// Round 5
// baseline (2442.073 us; speedup 1.0000x reference)
//
#include <hip/hip_runtime.h>
#include <stdint.h>
#include <math.h>

// ---------------------------------------------------------------------------
// MRF codebook generator: bit-exact reproduction of the JAX reference.
// Round 18: spatial decoupling — producer blocks + L3 ring + flag sync.
//  - R17 lesson: fusing gumbel gen into the sampler's own block loses to
//    (a) lockstep per-step barriers (gen waves' latency-bound wall time
//    gates wave0) and (b) co-compiled regalloc perturbation (VGPR 100->68).
//  - New: ONE kernel, grid 256. Blocks 0-127 run the EXACT R14-validated
//    701 µs sampler (wave0 only; waves 1-7 exit immediately; no barriers).
//    Blocks 128-255 are 8-wave producers: block 128+b generates batch b's
//    1280 gumbels per step (same derive_keys / gumbel_at / j = b*KC+k =>
//    bit-identical f32 values) into a 16-step ring in workspace (10.5 MB
//    total -> L3-resident), publishing prod[b]=step+1 with device-scope
//    release after a block-wide completion barrier + __threadfence.
//  - Sampler: acquire-spin on prod[b] once per 2 steps (producer is ~1.8x
//    faster per step -> spin is warmup-only), publishes cons[b]=step+1
//    after each step (wave-wide vmcnt(0) drain — free, loads were issued a
//    full body earlier — then relaxed store). Ring slot s is only
//    overwritten at prod step s+DRING, gated on cons >= s+1 — by which
//    time step s's data was consumed from registers. No deadlock: classic
//    bounded buffer, all 256 blocks co-resident by construction.
//  - HBM: the old 168 MB gumbel table write+read round trip is gone.
// cand precompute kernel unchanged since R8. Legacy fallbacks kept.
// ---------------------------------------------------------------------------

#define JAX_PARTITIONABLE 1

#define T_COLS 256
#define B_ROWS 128
#define KC     1280
#define PTOP   1024
#define RRAND  256
#define WWIN   32
#define NCAND  20            // KC / 64
#define DRING  16            // gumbel ring depth (steps); 10.5 MB total
#define BLOCK_S 1024         // legacy fallback block
#define NWAVE_S (BLOCK_S / 64)

__device__ __constant__ int dC[17][17] = {
  {1},
  {1,1},
  {1,2,1},
  {1,3,3,1},
  {1,4,6,4,1},
  {1,5,10,10,5,1},
  {1,6,15,20,15,6,1},
  {1,7,21,35,35,21,7,1},
  {1,8,28,56,70,56,28,8,1},
  {1,9,36,84,126,126,84,36,9,1},
  {1,10,45,120,210,252,210,120,45,10,1},
  {1,11,55,165,330,462,462,330,165,55,11,1},
  {1,12,66,220,495,792,924,792,495,220,66,12,1},
  {1,13,78,286,715,1287,1716,1716,1287,715,286,78,13,1},
  {1,14,91,364,1001,2002,3003,3432,3003,2002,1001,364,91,14,1},
  {1,15,105,455,1365,3003,5005,6435,6435,5005,3003,1365,455,105,15,1},
  {1,16,120,560,1820,4368,8008,11440,12870,11440,8008,4368,1820,560,120,16,1}
};

// Threefry-2x32, 20 rounds, JAX key schedule.
__device__ __forceinline__ void tf_block(uint32_t k0, uint32_t k1,
                                         uint32_t x0, uint32_t x1,
                                         uint32_t& o0, uint32_t& o1) {
  uint32_t ks2 = k0 ^ k1 ^ 0x1BD11BDAu;
  x0 += k0; x1 += k1;
#define TFR(r) { x0 += x1; x1 = (x1 << (r)) | (x1 >> (32 - (r))); x1 ^= x0; }
  TFR(13) TFR(15) TFR(26) TFR(6)   x0 += k1;  x1 += ks2 + 1u;
  TFR(17) TFR(29) TFR(16) TFR(24)  x0 += ks2; x1 += k0 + 2u;
  TFR(13) TFR(15) TFR(26) TFR(6)   x0 += k0;  x1 += k1 + 3u;
  TFR(17) TFR(29) TFR(16) TFR(24)  x0 += k1;  x1 += ks2 + 4u;
  TFR(13) TFR(15) TFR(26) TFR(6)   x0 += ks2; x1 += k0 + 5u;
#undef TFR
  o0 = x0; o1 = x1;
}

// fold_in(key(42), step) -> k_rand/k_samp/randint-k2 per PRNG mode.
__device__ __forceinline__ void derive_keys(int step,
                                            uint32_t* krand, uint32_t* ksamp,
                                            uint32_t* k2) {
  uint32_t y0, y1;
  tf_block(0u, 42u, 0u, (uint32_t)step, y0, y1);
  uint32_t kr0 = y0, kr1 = y1;
#if JAX_PARTITIONABLE
  uint32_t r0, r1;
  tf_block(kr0, kr1, 0u, 0u, r0, r1);            // k_rand
  if (krand) { krand[0] = r0; krand[1] = r1; }
  if (ksamp) { tf_block(kr0, kr1, 0u, 1u, y0, y1); ksamp[0] = y0; ksamp[1] = y1; }
  if (k2)    { tf_block(r0, r1, 0u, 1u, y0, y1);  k2[0] = y0;  k2[1] = y1; }
#else
  uint32_t a0,a1,b0,b1;
  tf_block(kr0, kr1, 0u, 2u, a0, a1);
  tf_block(kr0, kr1, 1u, 3u, b0, b1);
  if (krand) { krand[0] = a0; krand[1] = b0; }
  if (ksamp) { ksamp[0] = a1; ksamp[1] = b1; }
  if (k2) {
    uint32_t c0,c1,d0,d1;
    tf_block(a0, b0, 0u, 2u, c0, c1);
    tf_block(a0, b0, 1u, 3u, d0, d1);
    k2[0] = c1; k2[1] = d1;
  }
#endif
}

// JAX uniform(tiny,1) -> gumbel, fp32 logs correctly-rounded-from-double.
__device__ __forceinline__ float gumbel_from_bits(uint32_t bits) {
  uint32_t fb = (bits >> 9) | 0x3f800000u;
  float f = __uint_as_float(fb) - 1.0f;
  float u = (f == 0.0f) ? 1.17549435e-38f : f;
  float l1 = (float)log((double)u);
  float l2 = (float)log((double)(-l1));
  return -l2;
}

__device__ __forceinline__ float gumbel_at(uint32_t ks0, uint32_t ks1, uint32_t j) {
  uint32_t g0, g1;
#if JAX_PARTITIONABLE
  tf_block(ks0, ks1, 0u, j, g0, g1);
  return gumbel_from_bits(g0 ^ g1);
#else
  uint32_t half = (uint32_t)(B_ROWS * KC / 2);
  if (j < half) { tf_block(ks0, ks1, j, j + half, g0, g1);  return gumbel_from_bits(g0); }
  else          { tf_block(ks0, ks1, j - half, j, g0, g1);  return gumbel_from_bits(g1); }
#endif
}

// ---------------- precompute kernel C: cand[step][k] ------------------------
__global__ void __launch_bounds__(256)
cand_kernel(unsigned short* __restrict__ candg) {
  const int step = blockIdx.x;
  const int tid  = threadIdx.x;
  __shared__ int s_dC[17][17];
  __shared__ int s_gw0[17], s_gw1[17], s_gbase[17];
  __shared__ int s_ngrp;
  __shared__ uint32_t s_k2[2];
  for (int i = tid; i < 289; i += 256) s_dC[i/17][i%17] = dC[i/17][i%17];
  if (tid == 0) {
    uint32_t k2[2];
    derive_keys(step, nullptr, nullptr, k2);
    s_k2[0] = k2[0]; s_k2[1] = k2[1];
    int ws[17], am[17];
    for (int w = 0; w < 17; ++w) {
      int m = 16 * w - 256 + step;
      am[w] = m < 0 ? -m : m;
      ws[w] = w;
    }
    for (int a2 = 1; a2 < 17; ++a2) {
      int wv = ws[a2], kv = am[wv];
      int j2 = a2 - 1;
      while (j2 >= 0 && am[ws[j2]] > kv) { ws[j2 + 1] = ws[j2]; --j2; }
      ws[j2 + 1] = wv;
    }
    int ng = 0, base = 0, idx = 0;
    while (idx < 17) {
      int w0 = ws[idx]; int a0v = am[w0]; int w1 = -1;
      if (idx + 1 < 17 && am[ws[idx + 1]] == a0v) { w1 = ws[idx + 1]; ++idx; }
      ++idx;
      s_gw0[ng] = w0; s_gw1[ng] = w1; s_gbase[ng] = base;
      base += dC[16][w0] + (w1 >= 0 ? dC[16][w1] : 0);
      ++ng;
      if (base >= PTOP) break;
    }
    s_ngrp = ng;
  }
  __syncthreads();
  for (int p = tid; p < PTOP; p += 256) {
    int g = 0;
    for (int t2 = 1; t2 < s_ngrp; ++t2) if (s_gbase[t2] <= p) g = t2;
    int q  = p - s_gbase[g];
    int r0 = s_gw0[g], r1 = s_gw1[g];
    uint32_t code = 0;
    for (int pos = 15; pos >= 0; --pos) {
      int n0 = ((r0 >= 0 && r0 <= pos) ? s_dC[pos][r0] : 0)
             + ((r1 >= 0 && r1 <= pos) ? s_dC[pos][r1] : 0);
      if (q >= n0) { q -= n0; code |= (1u << pos); --r0; if (r1 >= 0) --r1; }
    }
    candg[step * KC + p] = (unsigned short)code;
  }
  {
    int t2 = tid;
    uint32_t a0, a1;
#if JAX_PARTITIONABLE
    tf_block(s_k2[0], s_k2[1], 0u, (uint32_t)t2, a0, a1);
    candg[step * KC + PTOP + t2] = (unsigned short)((a0 ^ a1) & 0xFFFFu);
#else
    if (t2 < 128) { tf_block(s_k2[0], s_k2[1], (uint32_t)t2, (uint32_t)(128 + t2), a0, a1);
                    candg[step * KC + PTOP + t2] = (unsigned short)(a0 & 0xFFFFu); }
    else          { tf_block(s_k2[0], s_k2[1], (uint32_t)(t2 - 128), (uint32_t)t2, a0, a1);
                    candg[step * KC + PTOP + t2] = (unsigned short)(a1 & 0xFFFFu); }
#endif
  }
}

// ---------------- VALU-pipe cross-lane primitives ---------------------------
// offset 32: v_permlane32_swap_b32 with both operands = x -> vsrc result is
// [x.hi32, x.hi32]: lanes 0-31 receive lane i+32.
__device__ __forceinline__ unsigned pl_down32_u(unsigned x) {
  unsigned d = x, s = x;
  asm volatile("s_nop 1\n\tv_permlane32_swap_b32 %0, %1" : "+v"(d), "+v"(s));
  return s;
}
// offset 16: v_permlane16_swap_b32 -> lanes 0-15 get lane i+16.
__device__ __forceinline__ unsigned pl_down16_u(unsigned x) {
  unsigned d = x, s = x;
  asm volatile("s_nop 1\n\tv_permlane16_swap_b32 %0, %1" : "+v"(d), "+v"(s));
  return s;
}
// offsets 8/4/2/1: DPP row_shl:N -> lane n receives lane n+N within its row.
template<int N>
__device__ __forceinline__ unsigned dpp_shl_u(unsigned x) {
  return (unsigned)__builtin_amdgcn_update_dpp(0, (int)x, 0x100 | N, 0xF, 0xF, true);
}
__device__ __forceinline__ float pl_down32_f(float x) {
  return __uint_as_float(pl_down32_u(__float_as_uint(x)));
}
__device__ __forceinline__ float pl_down16_f(float x) {
  return __uint_as_float(pl_down16_u(__float_as_uint(x)));
}
template<int N>
__device__ __forceinline__ float dpp_shl_f(float x) {
  return __uint_as_float(dpp_shl_u<N>(__float_as_uint(x)));
}
__device__ __forceinline__ double pl_down32_d(double x) {
  unsigned lo = pl_down32_u((unsigned)__double2loint(x));
  unsigned hi = pl_down32_u((unsigned)__double2hiint(x));
  return __hiloint2double((int)hi, (int)lo);
}
__device__ __forceinline__ double pl_down16_d(double x) {
  unsigned lo = pl_down16_u((unsigned)__double2loint(x));
  unsigned hi = pl_down16_u((unsigned)__double2hiint(x));
  return __hiloint2double((int)hi, (int)lo);
}
template<int N>
__device__ __forceinline__ double dpp_shl_d(double x) {
  unsigned lo = dpp_shl_u<N>((unsigned)__double2loint(x));
  unsigned hi = dpp_shl_u<N>((unsigned)__double2hiint(x));
  return __hiloint2double((int)hi, (int)lo);
}
// lane-0 broadcast (all lanes active at every call site) -> readfirstlane.
__device__ __forceinline__ float bcast0_f(float x) {
  return __uint_as_float((unsigned)__builtin_amdgcn_readfirstlane((int)__float_as_uint(x)));
}
__device__ __forceinline__ int bcast0_i(int x) {
  return __builtin_amdgcn_readfirstlane(x);
}
__device__ __forceinline__ double bcast0_d(double x) {
  int lo = __builtin_amdgcn_readfirstlane(__double2loint(x));
  int hi = __builtin_amdgcn_readfirstlane(__double2hiint(x));
  return __hiloint2double(hi, lo);
}

// ---------------- overlapped kernel ----------------------------------------
// STEP_BODY: EXACT R14-validated (701 µs, absmax 0.0) sampler step. Only
// changes: gumbel prefetch reads the L3 ring instead of the full table, and
// the tail publishes cons[b] (wave-wide vmcnt drain first — loads were
// issued a full body earlier, so the wait is ~free; it also pins the
// prefetch loads against sinking).
#define STEP_BODY(S, CC, GG, CN, GN)                                          \
  {                                                                           \
    const int step = (S);                                                     \
    /* prefetch step+1 (full step of slack) */                                \
    const int sn = (step + 1 < T_COLS) ? step + 1 : step;                     \
    const size_t rbn = ((size_t)b * DRING + (size_t)(sn & (DRING - 1))) * KC; \
    _Pragma("unroll")                                                         \
    for (int i = 0; i < NCAND; ++i) {                                         \
      CN[i] = candg[sn * KC + lane + 64 * i];                                 \
      GN[i] = gwr[rbn + lane + 64 * i];                                       \
    }                                                                         \
    /* slide window state (lanes 0-15 hold per-bit f64 state) */              \
    if (lane < 16) {                                                          \
      if (step > 0) {                                                         \
        double pw = (double)s_pi[step - 1];                                   \
        if ((c_last >> lane) & 1u) p1_d += pw;                                \
        pt_d += pw;                                                           \
      }                                                                       \
      if (step >= 33) {                                                       \
        double pw = (double)s_pi[step - 33];                                  \
        if (((uint32_t)s_cint[step - 33] >> lane) & 1u) p1_d -= pw;           \
        pt_d -= pw;                                                           \
      }                                                                       \
    }                                                                         \
    float Dl = (float)(pt_d - (p1_d + p1_d));                                 \
    /* S0: 16-lane f64 butterfly on the lane-0 lineage (row_shl 1,2,4,8). */  \
    double s0d = p1_d;                                                        \
    s0d += dpp_shl_d<1>(s0d);                                                 \
    s0d += dpp_shl_d<2>(s0d);                                                 \
    s0d += dpp_shl_d<4>(s0d);                                                 \
    s0d += dpp_shl_d<8>(s0d);                                                 \
    const float S0f  = bcast0_f((float)s0d);                                  \
    const float Pt16 = bcast0_f((float)(16.0 * pt_d));                        \
    {                                                                         \
      int n = lane >> 4, v = lane & 15;                                       \
      float d0 = __shfl(Dl, 4 * n + 0);                                       \
      float d1 = __shfl(Dl, 4 * n + 1);                                       \
      float d2 = __shfl(Dl, 4 * n + 2);                                       \
      float d3 = __shfl(Dl, 4 * n + 3);                                       \
      float t = 0.0f;                                                         \
      if (v & 1) t += d0;                                                     \
      if (v & 2) t += d1;                                                     \
      if (v & 4) t += d2;                                                     \
      if (v & 8) t += d3;                                                     \
      s_T[n][v] = t;                                                          \
    }                                                                         \
    __builtin_amdgcn_wave_barrier();                                          \
    const float pi_i   = s_pi[step];                                          \
    const float i_pf   = (float)step;                                         \
    const float factor = (step > 0) ? (i_pf / fminf(i_pf, 32.0f)) : 0.0f;     \
    float un[NCAND];                                                          \
    _Pragma("unroll")                                                         \
    for (int i = 0; i < NCAND; ++i) {                                         \
      uint32_t c = CC[i];                                                     \
      float sc = S0f + s_T[0][c & 15];                                        \
      sc += s_T[1][(c >> 4) & 15];                                            \
      sc += s_T[2][(c >> 8) & 15];                                            \
      sc += s_T[3][(c >> 12) & 15];                                           \
      float sv = Pt16 - sc;                                                   \
      int w = __popc(c);                                                      \
      int m = 16 * w - 256 + step;                                            \
      float sq  = (float)(m * m) * 0.00390625f;                               \
      float obk = (pi_i * sq) * 0.0625f;                                      \
      un[i] = -(obk + factor * (pi_i * sv));                                  \
    }                                                                         \
    /* rmax: exact global max (fmax associative-exact; hand tree + DPP) */    \
    float wt10[10];                                                           \
    _Pragma("unroll")                                                         \
    for (int q = 0; q < 10; ++q) wt10[q] = fmaxf(un[2*q], un[2*q+1]);         \
    float wt5[5];                                                             \
    _Pragma("unroll")                                                         \
    for (int q = 0; q < 5; ++q) wt5[q] = fmaxf(wt10[2*q], wt10[2*q+1]);       \
    float wm = fmaxf(fmaxf(fmaxf(wt5[0], wt5[1]), fmaxf(wt5[2], wt5[3])),     \
                     wt5[4]);                                                 \
    wm = fmaxf(wm, pl_down32_f(wm));                                          \
    wm = fmaxf(wm, pl_down16_f(wm));                                          \
    wm = fmaxf(wm, dpp_shl_f<8>(wm));                                         \
    wm = fmaxf(wm, dpp_shl_f<4>(wm));                                         \
    wm = fmaxf(wm, dpp_shl_f<2>(wm));                                         \
    wm = fmaxf(wm, dpp_shl_f<1>(wm));                                         \
    wm = bcast0_f(wm);                                                        \
    /* lsum: f64-accumulated fp32 exp terms (common-mode class) */            \
    double a0 = 0.0, a1 = 0.0;                                                \
    _Pragma("unroll")                                                         \
    for (int i = 0; i < NCAND; ++i) {                                         \
      float e = expf(un[i] - wm);                                             \
      if (i & 1) a1 += (double)e; else a0 += (double)e;                       \
    }                                                                         \
    double sw = a0 + a1;                                                      \
    sw += pl_down32_d(sw);                                                    \
    sw += pl_down16_d(sw);                                                    \
    sw += dpp_shl_d<8>(sw);                                                   \
    sw += dpp_shl_d<4>(sw);                                                   \
    sw += dpp_shl_d<2>(sw);                                                   \
    sw += dpp_shl_d<1>(sw);                                                   \
    const float lsum = logf((float)bcast0_d(sw));                             \
    /* exact z argmax, lowest-k ties (per-lane tree then cross-lane tree) */  \
    float z1[10]; int i1[10]; float u1[10];                                   \
    _Pragma("unroll")                                                         \
    for (int q = 0; q < 10; ++q) {                                            \
      float za = ((un[2*q]   - wm) - lsum) + GG[2*q];                         \
      float zb = ((un[2*q+1] - wm) - lsum) + GG[2*q+1];                       \
      int ia = (((64*(2*q)   + lane) << 16) | (int)CC[2*q]);                  \
      int ib = (((64*(2*q+1) + lane) << 16) | (int)CC[2*q+1]);                \
      bool tt = (zb > za);                                                    \
      z1[q] = tt ? zb : za; i1[q] = tt ? ib : ia;                             \
      u1[q] = tt ? un[2*q+1] : un[2*q];                                       \
    }                                                                         \
    float z2[5]; int i2[5]; float u2[5];                                      \
    _Pragma("unroll")                                                         \
    for (int q = 0; q < 5; ++q) {                                             \
      bool tt = (z1[2*q+1] > z1[2*q]);                                        \
      z2[q] = tt ? z1[2*q+1] : z1[2*q]; i2[q] = tt ? i1[2*q+1] : i1[2*q];     \
      u2[q] = tt ? u1[2*q+1] : u1[2*q];                                       \
    }                                                                         \
    float bz; int bi; float bu;                                               \
    {                                                                         \
      float zA, zB; int iA, iB; float uA, uB;                                 \
      bool t0 = (z2[1] > z2[0]);                                              \
      zA = t0 ? z2[1] : z2[0]; iA = t0 ? i2[1] : i2[0];                       \
      uA = t0 ? u2[1] : u2[0];                                                \
      bool t1 = (z2[3] > z2[2]);                                              \
      zB = t1 ? z2[3] : z2[2]; iB = t1 ? i2[3] : i2[2];                       \
      uB = t1 ? u2[3] : u2[2];                                                \
      bool t2 = (zB > zA);                                                    \
      zA = t2 ? zB : zA; iA = t2 ? iB : iA; uA = t2 ? uB : uA;                \
      bool t3 = (z2[4] > zA);                                                 \
      bz = t3 ? z2[4] : zA; bi = t3 ? i2[4] : iA; bu = t3 ? u2[4] : uA;       \
    }                                                                         \
    {                                                                         \
      float oz = pl_down32_f(bz); int oi = (int)pl_down32_u((unsigned)bi);    \
      float ou = pl_down32_f(bu);                                             \
      if (oz > bz || (oz == bz && oi < bi)) { bz = oz; bi = oi; bu = ou; }    \
    }                                                                         \
    {                                                                         \
      float oz = pl_down16_f(bz); int oi = (int)pl_down16_u((unsigned)bi);    \
      float ou = pl_down16_f(bu);                                             \
      if (oz > bz || (oz == bz && oi < bi)) { bz = oz; bi = oi; bu = ou; }    \
    }                                                                         \
    {                                                                         \
      float oz = dpp_shl_f<8>(bz); int oi = (int)dpp_shl_u<8>((unsigned)bi);  \
      float ou = dpp_shl_f<8>(bu);                                            \
      if (oz > bz || (oz == bz && oi < bi)) { bz = oz; bi = oi; bu = ou; }    \
    }                                                                         \
    {                                                                         \
      float oz = dpp_shl_f<4>(bz); int oi = (int)dpp_shl_u<4>((unsigned)bi);  \
      float ou = dpp_shl_f<4>(bu);                                             \
      if (oz > bz || (oz == bz && oi < bi)) { bz = oz; bi = oi; bu = ou; }    \
    }                                                                         \
    {                                                                         \
      float oz = dpp_shl_f<2>(bz); int oi = (int)dpp_shl_u<2>((unsigned)bi);  \
      float ou = dpp_shl_f<2>(bu);                                            \
      if (oz > bz || (oz == bz && oi < bi)) { bz = oz; bi = oi; bu = ou; }    \
    }                                                                         \
    {                                                                         \
      float oz = dpp_shl_f<1>(bz); int oi = (int)dpp_shl_u<1>((unsigned)bi);  \
      float ou = dpp_shl_f<1>(bu);                                            \
      if (oz > bz || (oz == bz && oi < bi)) { bz = oz; bi = oi; bu = ou; }    \
    }                                                                         \
    int wpk = bcast0_i(bi);                                                   \
    c_last = (uint32_t)wpk & 0xFFFFu;                                         \
    /* publish consumer progress: ring slot of this step may be reused by    \
       the producer once cons >= step+1. The vmcnt(0) drains this body's    \
       prefetch loads (issued at body top — wait is ~free) and pins them    \
       against sinking past the store. */                                     \
    asm volatile("s_waitcnt vmcnt(0)" ::: "memory");                          \
    if (lane == 0) {                                                          \
      s_cint[step] = (unsigned short)c_last;                                  \
      lp_acc += (double)((bu - wm) - lsum);                                   \
      __hip_atomic_store(&cons[b], step + 1, __ATOMIC_RELAXED,                \
                         __HIP_MEMORY_SCOPE_AGENT);                           \
    }                                                                         \
  }

__global__ void __launch_bounds__(512, 1)
mrf_overlap(const float* __restrict__ pi, float* __restrict__ out,
            const unsigned short* __restrict__ candg,
            float* __restrict__ gwr,
            int* __restrict__ prod, int* __restrict__ cons) {
#pragma clang fp contract(off)
  const int bid = blockIdx.x;
  const int tid = threadIdx.x;

  if (bid >= B_ROWS) {
    // ---------------- producer block: batch pb's gumbels, step by step ----
    const int pb = bid - B_ROWS;
    for (int sp = 0; sp < T_COLS; ++sp) {
      if (sp >= DRING) {
        // ring slot (sp % DRING) holds step sp-DRING; wait until the
        // consumer has finished body sp-DRING (its data was consumed from
        // registers loaded during body sp-DRING-1).
        if (tid == 0) {
          while (__hip_atomic_load(&cons[pb], __ATOMIC_ACQUIRE,
                                   __HIP_MEMORY_SCOPE_AGENT) < sp - DRING + 1)
            __builtin_amdgcn_s_sleep(8);
        }
        __syncthreads();
      }
      uint32_t ks[2];
      derive_keys(sp, nullptr, ks, nullptr);
      const size_t rb = ((size_t)pb * DRING + (size_t)(sp & (DRING - 1))) * KC;
#pragma unroll
      for (int j = 0; j < 3; ++j) {
        int k = tid + 512 * j;
        if (k < KC)
          gwr[rb + k] = gumbel_at(ks[0], ks[1], (uint32_t)(pb * KC + k));
      }
      __syncthreads();   // all waves' stores complete (per-wave vmcnt drain)
      if (tid == 0) {
        __threadfence(); // device-scope: publish the block's writes
        __hip_atomic_store(&prod[pb], sp + 1, __ATOMIC_RELEASE,
                           __HIP_MEMORY_SCOPE_AGENT);
      }
    }
    return;
  }

  // ---------------- sampler block: wave0 only (waves 1-7 exit) ------------
  if (tid >= 64) return;
  const int b    = bid;
  const int lane = tid;

  __shared__ float          s_pi[T_COLS];
  __shared__ unsigned short s_cint[T_COLS];
  __shared__ float          s_T[4][16];

  for (int t = lane; t < T_COLS; t += 64) s_pi[t] = pi[t];
  // single live wave: intra-wave lgkmcnt ordering is automatic; no barrier.

  double lp_acc = 0.0;                      // lane 0 only
  uint32_t c_last = 0;
  double p1_d = 0.0, pt_d = 0.0;            // sliding window state (lanes<16)

  float    gA[NCAND], gB[NCAND];
  uint32_t cA[NCAND], cB[NCAND];

  // prologue: wait for step 0 gumbels, then load step-0 data into A buffers
  while (__hip_atomic_load(&prod[b], __ATOMIC_ACQUIRE,
                           __HIP_MEMORY_SCOPE_AGENT) < 1)
    __builtin_amdgcn_s_sleep(2);
  {
    const size_t rb0 = (size_t)b * DRING * (size_t)KC;
#pragma unroll
    for (int i = 0; i < NCAND; ++i) {
      cA[i] = candg[lane + 64 * i];
      gA[i] = gwr[rb0 + lane + 64 * i];
    }
  }

  for (int s2 = 0; s2 < T_COLS; s2 += 2) {
    // need gumbels for steps s2..s2+2 (bodies prefetch s2+1 and s2+2)
    {
      int need = (s2 + 3 < T_COLS) ? (s2 + 3) : T_COLS;
      while (__hip_atomic_load(&prod[b], __ATOMIC_ACQUIRE,
                               __HIP_MEMORY_SCOPE_AGENT) < need)
        __builtin_amdgcn_s_sleep(2);
    }
    STEP_BODY(s2,     cA, gA, cB, gB)
    STEP_BODY(s2 + 1, cB, gB, cA, gA)
  }

  // outputs (FP32): c_btls one-hot [B,T,L,S] then log_prob_b [B]
  for (int idx2 = lane; idx2 < T_COLS * 32; idx2 += 64) {
    int t    = idx2 >> 5;
    int rem  = idx2 & 31;
    int l    = rem >> 1;
    int sbit = rem & 1;
    uint32_t code = s_cint[t];
    int bit = (int)((code >> (15 - l)) & 1u);
    out[(size_t)b * 8192 + idx2] = (float)(sbit ? bit : (1 - bit));
  }
  if (lane == 0) {
    out[(size_t)B_ROWS * 8192 + b] = (float)(lp_acc / 256.0);
  }
}

// ---------------- legacy sequential kernel (fallback modes 0/1) -------------
template<int MODE>
__global__ void __launch_bounds__(BLOCK_S)
mrf_seq_kernel(const float* __restrict__ pi, float* __restrict__ out,
               const float* __restrict__ gw,
               const unsigned short* __restrict__ candg) {
#pragma clang fp contract(off)
  const int b    = blockIdx.x;
  const int tid  = threadIdx.x;
  const bool has1 = tid < (KC - BLOCK_S);

  __shared__ float          s_pi[T_COLS];
  __shared__ unsigned short s_cand[KC];
  __shared__ float          s_unnorm[KC];
  __shared__ unsigned short s_cint[T_COLS];
  __shared__ int            s_dC[17][17];
  __shared__ int            s_gw0[17], s_gw1[17], s_gbase[17];
  __shared__ int            s_ngrp;
  __shared__ uint32_t       s_keys[6];
  __shared__ float          s_pw[WWIN];
  __shared__ unsigned short s_wc[WWIN];
  __shared__ float          s_redf[NWAVE_S];
  __shared__ double         s_redd[NWAVE_S];
  __shared__ int            s_redi[NWAVE_S];
  __shared__ float          s_bcast[2];

  for (int t = tid; t < T_COLS; t += BLOCK_S) s_pi[t] = pi[t];
  if (MODE == 0) {
    for (int i = tid; i < 289; i += BLOCK_S) s_dC[i/17][i%17] = dC[i/17][i%17];
  }
  double lp_acc = 0.0;
  __syncthreads();

  for (int step = 0; step < T_COLS; ++step) {
    if (tid == 0) {
      if (MODE == 1) {
        uint32_t ks[2];
        derive_keys(step, nullptr, ks, nullptr);
        s_keys[2] = ks[0]; s_keys[3] = ks[1];
      } else {
        uint32_t ks[2], k2[2];
        derive_keys(step, nullptr, ks, k2);
        s_keys[2] = ks[0]; s_keys[3] = ks[1];
        s_keys[4] = k2[0]; s_keys[5] = k2[1];
        int ws[17], am[17];
        for (int w = 0; w < 17; ++w) {
          int m = 16 * w - 256 + step;
          am[w] = m < 0 ? -m : m;
          ws[w] = w;
        }
        for (int a2 = 1; a2 < 17; ++a2) {
          int wvv = ws[a2], kv = am[wvv];
          int j2 = a2 - 1;
          while (j2 >= 0 && am[ws[j2]] > kv) { ws[j2 + 1] = ws[j2]; --j2; }
          ws[j2 + 1] = wvv;
        }
        int ng = 0, base = 0, idx = 0;
        while (idx < 17) {
          int w0 = ws[idx]; int a0v = am[w0]; int w1 = -1;
          if (idx + 1 < 17 && am[ws[idx + 1]] == a0v) { w1 = ws[idx + 1]; ++idx; }
          ++idx;
          s_gw0[ng] = w0; s_gw1[ng] = w1; s_gbase[ng] = base;
          base += dC[16][w0] + (w1 >= 0 ? dC[16][w1] : 0);
          ++ng;
          if (base >= PTOP) break;
        }
        s_ngrp = ng;
      }
    }
    if (tid < WWIN) {
      int win = step - WWIN + tid;
      s_pw[tid] = (win >= 0) ? s_pi[win] : 0.0f;
      s_wc[tid] = (win >= 0) ? s_cint[win] : (unsigned short)0;
    }
    __syncthreads();

    uint32_t c0, c1 = 0;
    if (MODE >= 1) {
      c0 = candg[step * KC + tid];
      if (has1) c1 = candg[step * KC + BLOCK_S + tid];
    } else {
      {
        int p = tid;
        int g = 0;
        for (int t2 = 1; t2 < s_ngrp; ++t2) if (s_gbase[t2] <= p) g = t2;
        int q  = p - s_gbase[g];
        int r0 = s_gw0[g], r1 = s_gw1[g];
        uint32_t code = 0;
        for (int pos = 15; pos >= 0; --pos) {
          int n0 = ((r0 >= 0 && r0 <= pos) ? s_dC[pos][r0] : 0)
                 + ((r1 >= 0 && r1 <= pos) ? s_dC[pos][r1] : 0);
          if (q >= n0) { q -= n0; code |= (1u << pos); --r0; if (r1 >= 0) --r1; }
        }
        c0 = code;
      }
      if (has1) {
        int t2 = tid;
        uint32_t a0, a1;
#if JAX_PARTITIONABLE
        tf_block(s_keys[4], s_keys[5], 0u, (uint32_t)t2, a0, a1);
        c1 = (a0 ^ a1) & 0xFFFFu;
#else
        if (t2 < 128) { tf_block(s_keys[4], s_keys[5], (uint32_t)t2, (uint32_t)(128 + t2), a0, a1);
                        c1 = a0 & 0xFFFFu; }
        else          { tf_block(s_keys[4], s_keys[5], (uint32_t)(t2 - 128), (uint32_t)t2, a0, a1);
                        c1 = a1 & 0xFFFFu; }
#endif
      }
    }
    s_cand[tid] = (unsigned short)c0;
    if (has1) s_cand[BLOCK_S + tid] = (unsigned short)c1;

    const float pi_i   = s_pi[step];
    const float i_pf   = (float)step;
    const float factor = (step > 0) ? (i_pf / fminf(i_pf, 32.0f)) : 0.0f;

    float un0, un1 = -3.402823466e+38f;
    {
      int w = __popc(c0);
      int m = 16 * w - 256 + step;
      float sq  = (float)(m * m) * 0.00390625f;
      float obk = (pi_i * sq) * 0.0625f;
      float s = 0.0f;
      for (int w2 = 0; w2 < WWIN; ++w2) {
        float ov = (float)(16 - __popc(c0 ^ (uint32_t)s_wc[w2]));
        s = s + s_pw[w2] * ov;
      }
      un0 = -(obk + factor * (pi_i * s));
    }
    if (has1) {
      int w = __popc(c1);
      int m = 16 * w - 256 + step;
      float sq  = (float)(m * m) * 0.00390625f;
      float obk = (pi_i * sq) * 0.0625f;
      float s = 0.0f;
      for (int w2 = 0; w2 < WWIN; ++w2) {
        float ov = (float)(16 - __popc(c1 ^ (uint32_t)s_wc[w2]));
        s = s + s_pw[w2] * ov;
      }
      un1 = -(obk + factor * (pi_i * s));
    }
    s_unnorm[tid] = un0;
    if (has1) s_unnorm[BLOCK_S + tid] = un1;

    float g0v = 0.0f, g1v = 0.0f;
    {
      const uint32_t ks0 = s_keys[2], ks1 = s_keys[3];
      g0v = gumbel_at(ks0, ks1, (uint32_t)(b * KC + tid));
      if (has1) g1v = gumbel_at(ks0, ks1, (uint32_t)(b * KC + BLOCK_S + tid));
    }

    float pmax = has1 ? fmaxf(un0, un1) : un0;
    for (int off = 32; off > 0; off >>= 1) pmax = fmaxf(pmax, __shfl_down(pmax, off));
    if ((tid & 63) == 0) s_redf[tid >> 6] = pmax;
    __syncthreads();
    if (tid == 0) {
      float mm = s_redf[0];
      for (int w2 = 1; w2 < NWAVE_S; ++w2) mm = fmaxf(mm, s_redf[w2]);
      s_bcast[0] = mm;
    }
    __syncthreads();
    const float rmax = s_bcast[0];

    double acc = (double)((float)exp((double)(un0 - rmax)));
    if (has1) acc += (double)((float)exp((double)(un1 - rmax)));
    for (int off = 32; off > 0; off >>= 1) acc += __shfl_down(acc, off);
    if ((tid & 63) == 0) s_redd[tid >> 6] = acc;
    __syncthreads();
    if (tid == 0) {
      double ss = 0.0;
      for (int w2 = 0; w2 < NWAVE_S; ++w2) ss += s_redd[w2];
      float sum_f = (float)ss;
      s_bcast[1] = (float)log((double)sum_f);
    }
    __syncthreads();
    const float lsum = s_bcast[1];

    float bz = ((un0 - rmax) - lsum) + g0v;
    int   bi = tid;
    if (has1) {
      float z1 = ((un1 - rmax) - lsum) + g1v;
      if (z1 > bz) { bz = z1; bi = BLOCK_S + tid; }
    }
    for (int off = 32; off > 0; off >>= 1) {
      float oz = __shfl_down(bz, off);
      int   oi = __shfl_down(bi, off);
      if (oz > bz || (oz == bz && oi < bi)) { bz = oz; bi = oi; }
    }
    if ((tid & 63) == 0) { s_redf[tid >> 6] = bz; s_redi[tid >> 6] = bi; }
    __syncthreads();
    if (tid == 0) {
      float bz2 = s_redf[0]; int bi2 = s_redi[0];
      for (int w2 = 1; w2 < NWAVE_S; ++w2) {
        if (s_redf[w2] > bz2 || (s_redf[w2] == bz2 && s_redi[w2] < bi2)) {
          bz2 = s_redf[w2]; bi2 = s_redi[w2];
        }
      }
      s_cint[step] = s_cand[bi2];
      float lpw = (s_unnorm[bi2] - rmax) - lsum;
      lp_acc += (double)lpw;
    }
    __syncthreads();
  }

  for (int idx2 = tid; idx2 < T_COLS * 32; idx2 += BLOCK_S) {
    int t    = idx2 >> 5;
    int rem  = idx2 & 31;
    int l    = rem >> 1;
    int sbit = rem & 1;
    uint32_t code = s_cint[t];
    int bit = (int)((code >> (15 - l)) & 1u);
    out[(size_t)b * 8192 + idx2] = (float)(sbit ? bit : (1 - bit));
  }
  if (tid == 0) {
    out[(size_t)B_ROWS * 8192 + b] = (float)(lp_acc / 256.0);
  }
}

extern "C" void kernel_launch(void* const* d_in, const int* in_sizes, int n_in,
                              void* d_out, int out_size, void* d_ws, size_t ws_size,
                              hipStream_t stream) {
  const float* pi = (const float*)d_in[0];
  float* out = (float*)d_out;

  const size_t cand_bytes = (size_t)T_COLS * KC * sizeof(unsigned short); // 655,360
  const size_t flag_off   = cand_bytes;                                   // prod+cons
  const size_t flag_bytes = 1024;                                         // 2x128 ints
  const size_t ring_off   = flag_off + flag_bytes;
  const size_t ring_bytes = (size_t)B_ROWS * DRING * KC * sizeof(float);  // 10,485,760

  if (ws_size >= ring_off + ring_bytes) {
    unsigned short* candg = (unsigned short*)d_ws;
    int*   flags = (int*)((char*)d_ws + flag_off);
    float* gwr   = (float*)((char*)d_ws + ring_off);
    // zero prod/cons each launch (workspace may be poisoned between runs)
    hipMemsetAsync((char*)d_ws + flag_off, 0, flag_bytes, stream);
    cand_kernel<<<dim3(T_COLS), dim3(256), 0, stream>>>(candg);
    mrf_overlap<<<dim3(2 * B_ROWS), dim3(512), 0, stream>>>(
        pi, out, candg, gwr, flags, flags + B_ROWS);
  } else if (ws_size >= cand_bytes) {
    unsigned short* candg = (unsigned short*)d_ws;
    cand_kernel<<<dim3(T_COLS), dim3(256), 0, stream>>>(candg);
    mrf_seq_kernel<1><<<dim3(B_ROWS), dim3(BLOCK_S), 0, stream>>>(pi, out, nullptr, candg);
  } else {
    mrf_seq_kernel<0><<<dim3(B_ROWS), dim3(BLOCK_S), 0, stream>>>(pi, out, nullptr, nullptr);
  }
}

// Round 6
// 2201.351 us; speedup vs baseline: 1.1094x; 1.1094x over previous
//
#include <hip/hip_runtime.h>
#include <stdint.h>
#include <math.h>

// ---------------------------------------------------------------------------
// MRF codebook generator: bit-exact reproduction of the JAX reference.
// Round 19: dispatch-level overlap of gumbel precompute with the sampler.
//  - R18 lesson: fine-grained cross-XCD producer->consumer (per-step fences,
//    ring backpressure) forces per-step L2 writebacks/invalidates -> 170 MB
//    of extra HBM write traffic and 9.5 us steps. Coupling must be COARSE.
//  - New: ONE kernel, grid 128 + 32768, block 256.
//      bid <  128 : sampler block (exact R14-validated 701 us pipeline,
//                   wave0 only; reads the FULL gw table as before). Waits
//                   once per 2 steps on done[s+1], done[s+2] >= 128
//                   (lane-0 acquire spin + s_sleep; after warmup this is a
//                   single satisfied load).
//      bid >= 128 : one cohort-block of the ORIGINAL gumbel_kernel
//                   (bb = (bid-128)&127, step = (bid-128)>>7), writing the
//                   same gw table values (bit-identical), then ONE
//                   release-atomicAdd on done[step] at block end.
//    Blocks dispatch in order -> samplers start at t=0 on 128 CUs;
//    producers fill every remaining slot and race ahead of the sampler
//    (cohort s done at ~0.2*s us vs sampler demand at 2.74*s us).
//  - Total HBM traffic unchanged vs the two-kernel baseline (the 168 MB
//    table write happens either way); the ~297 us serialization is gone.
//  - s_setprio(1) on the sampler wave biases SIMD arbitration vs
//    co-resident producer waves during the overlap phase.
// Fallbacks: (old layout) two-kernel R14 path; legacy modes 0/1.
// ---------------------------------------------------------------------------

#define JAX_PARTITIONABLE 1

#define T_COLS 256
#define B_ROWS 128
#define KC     1280
#define PTOP   1024
#define RRAND  256
#define WWIN   32
#define NCAND  20            // KC / 64
#define BLOCK_S 1024         // legacy fallback block
#define NWAVE_S (BLOCK_S / 64)

__device__ __constant__ int dC[17][17] = {
  {1},
  {1,1},
  {1,2,1},
  {1,3,3,1},
  {1,4,6,4,1},
  {1,5,10,10,5,1},
  {1,6,15,20,15,6,1},
  {1,7,21,35,35,21,7,1},
  {1,8,28,56,70,56,28,8,1},
  {1,9,36,84,126,126,84,36,9,1},
  {1,10,45,120,210,252,210,120,45,10,1},
  {1,11,55,165,330,462,462,330,165,55,11,1},
  {1,12,66,220,495,792,924,792,495,220,66,12,1},
  {1,13,78,286,715,1287,1716,1716,1287,715,286,78,13,1},
  {1,14,91,364,1001,2002,3003,3432,3003,2002,1001,364,91,14,1},
  {1,15,105,455,1365,3003,5005,6435,6435,5005,3003,1365,455,105,15,1},
  {1,16,120,560,1820,4368,8008,11440,12870,11440,8008,4368,1820,560,120,16,1}
};

// Threefry-2x32, 20 rounds, JAX key schedule.
__device__ __forceinline__ void tf_block(uint32_t k0, uint32_t k1,
                                         uint32_t x0, uint32_t x1,
                                         uint32_t& o0, uint32_t& o1) {
  uint32_t ks2 = k0 ^ k1 ^ 0x1BD11BDAu;
  x0 += k0; x1 += k1;
#define TFR(r) { x0 += x1; x1 = (x1 << (r)) | (x1 >> (32 - (r))); x1 ^= x0; }
  TFR(13) TFR(15) TFR(26) TFR(6)   x0 += k1;  x1 += ks2 + 1u;
  TFR(17) TFR(29) TFR(16) TFR(24)  x0 += ks2; x1 += k0 + 2u;
  TFR(13) TFR(15) TFR(26) TFR(6)   x0 += k0;  x1 += k1 + 3u;
  TFR(17) TFR(29) TFR(16) TFR(24)  x0 += k1;  x1 += ks2 + 4u;
  TFR(13) TFR(15) TFR(26) TFR(6)   x0 += ks2; x1 += k0 + 5u;
#undef TFR
  o0 = x0; o1 = x1;
}

// fold_in(key(42), step) -> k_rand/k_samp/randint-k2 per PRNG mode.
__device__ __forceinline__ void derive_keys(int step,
                                            uint32_t* krand, uint32_t* ksamp,
                                            uint32_t* k2) {
  uint32_t y0, y1;
  tf_block(0u, 42u, 0u, (uint32_t)step, y0, y1);
  uint32_t kr0 = y0, kr1 = y1;
#if JAX_PARTITIONABLE
  uint32_t r0, r1;
  tf_block(kr0, kr1, 0u, 0u, r0, r1);            // k_rand
  if (krand) { krand[0] = r0; krand[1] = r1; }
  if (ksamp) { tf_block(kr0, kr1, 0u, 1u, y0, y1); ksamp[0] = y0; ksamp[1] = y1; }
  if (k2)    { tf_block(r0, r1, 0u, 1u, y0, y1);  k2[0] = y0;  k2[1] = y1; }
#else
  uint32_t a0,a1,b0,b1;
  tf_block(kr0, kr1, 0u, 2u, a0, a1);
  tf_block(kr0, kr1, 1u, 3u, b0, b1);
  if (krand) { krand[0] = a0; krand[1] = b0; }
  if (ksamp) { ksamp[0] = a1; ksamp[1] = b1; }
  if (k2) {
    uint32_t c0,c1,d0,d1;
    tf_block(a0, b0, 0u, 2u, c0, c1);
    tf_block(a0, b0, 1u, 3u, d0, d1);
    k2[0] = c1; k2[1] = d1;
  }
#endif
}

// JAX uniform(tiny,1) -> gumbel, fp32 logs correctly-rounded-from-double.
__device__ __forceinline__ float gumbel_from_bits(uint32_t bits) {
  uint32_t fb = (bits >> 9) | 0x3f800000u;
  float f = __uint_as_float(fb) - 1.0f;
  float u = (f == 0.0f) ? 1.17549435e-38f : f;
  float l1 = (float)log((double)u);
  float l2 = (float)log((double)(-l1));
  return -l2;
}

__device__ __forceinline__ float gumbel_at(uint32_t ks0, uint32_t ks1, uint32_t j) {
  uint32_t g0, g1;
#if JAX_PARTITIONABLE
  tf_block(ks0, ks1, 0u, j, g0, g1);
  return gumbel_from_bits(g0 ^ g1);
#else
  uint32_t half = (uint32_t)(B_ROWS * KC / 2);
  if (j < half) { tf_block(ks0, ks1, j, j + half, g0, g1);  return gumbel_from_bits(g0); }
  else          { tf_block(ks0, ks1, j - half, j, g0, g1);  return gumbel_from_bits(g1); }
#endif
}

// ---------------- precompute kernel G: gumbel[b][step][k] (fallback) --------
__global__ void __launch_bounds__(256)
gumbel_kernel(float* __restrict__ gw) {
  const int bb   = blockIdx.x & (B_ROWS - 1);
  const int step = blockIdx.x >> 7;
  const int tid  = threadIdx.x;
  __shared__ uint32_t s_ks[2];
  if (tid == 0) {
    uint32_t ks[2];
    derive_keys(step, nullptr, ks, nullptr);
    s_ks[0] = ks[0]; s_ks[1] = ks[1];
  }
  __syncthreads();
  const uint32_t ks0 = s_ks[0], ks1 = s_ks[1];
  const size_t base = ((size_t)bb * T_COLS + step) * KC;
#pragma unroll
  for (int i = 0; i < 5; ++i) {
    int k = tid + 256 * i;
    uint32_t j = (uint32_t)(bb * KC + k);
    gw[base + k] = gumbel_at(ks0, ks1, j);
  }
}

// ---------------- precompute kernel C: cand[step][k] ------------------------
__global__ void __launch_bounds__(256)
cand_kernel(unsigned short* __restrict__ candg) {
  const int step = blockIdx.x;
  const int tid  = threadIdx.x;
  __shared__ int s_dC[17][17];
  __shared__ int s_gw0[17], s_gw1[17], s_gbase[17];
  __shared__ int s_ngrp;
  __shared__ uint32_t s_k2[2];
  for (int i = tid; i < 289; i += 256) s_dC[i/17][i%17] = dC[i/17][i%17];
  if (tid == 0) {
    uint32_t k2[2];
    derive_keys(step, nullptr, nullptr, k2);
    s_k2[0] = k2[0]; s_k2[1] = k2[1];
    int ws[17], am[17];
    for (int w = 0; w < 17; ++w) {
      int m = 16 * w - 256 + step;
      am[w] = m < 0 ? -m : m;
      ws[w] = w;
    }
    for (int a2 = 1; a2 < 17; ++a2) {
      int wv = ws[a2], kv = am[wv];
      int j2 = a2 - 1;
      while (j2 >= 0 && am[ws[j2]] > kv) { ws[j2 + 1] = ws[j2]; --j2; }
      ws[j2 + 1] = wv;
    }
    int ng = 0, base = 0, idx = 0;
    while (idx < 17) {
      int w0 = ws[idx]; int a0v = am[w0]; int w1 = -1;
      if (idx + 1 < 17 && am[ws[idx + 1]] == a0v) { w1 = ws[idx + 1]; ++idx; }
      ++idx;
      s_gw0[ng] = w0; s_gw1[ng] = w1; s_gbase[ng] = base;
      base += dC[16][w0] + (w1 >= 0 ? dC[16][w1] : 0);
      ++ng;
      if (base >= PTOP) break;
    }
    s_ngrp = ng;
  }
  __syncthreads();
  for (int p = tid; p < PTOP; p += 256) {
    int g = 0;
    for (int t2 = 1; t2 < s_ngrp; ++t2) if (s_gbase[t2] <= p) g = t2;
    int q  = p - s_gbase[g];
    int r0 = s_gw0[g], r1 = s_gw1[g];
    uint32_t code = 0;
    for (int pos = 15; pos >= 0; --pos) {
      int n0 = ((r0 >= 0 && r0 <= pos) ? s_dC[pos][r0] : 0)
             + ((r1 >= 0 && r1 <= pos) ? s_dC[pos][r1] : 0);
      if (q >= n0) { q -= n0; code |= (1u << pos); --r0; if (r1 >= 0) --r1; }
    }
    candg[step * KC + p] = (unsigned short)code;
  }
  {
    int t2 = tid;
    uint32_t a0, a1;
#if JAX_PARTITIONABLE
    tf_block(s_k2[0], s_k2[1], 0u, (uint32_t)t2, a0, a1);
    candg[step * KC + PTOP + t2] = (unsigned short)((a0 ^ a1) & 0xFFFFu);
#else
    if (t2 < 128) { tf_block(s_k2[0], s_k2[1], (uint32_t)t2, (uint32_t)(128 + t2), a0, a1);
                    candg[step * KC + PTOP + t2] = (unsigned short)(a0 & 0xFFFFu); }
    else          { tf_block(s_k2[0], s_k2[1], (uint32_t)(t2 - 128), (uint32_t)t2, a0, a1);
                    candg[step * KC + PTOP + t2] = (unsigned short)(a1 & 0xFFFFu); }
#endif
  }
}

// ---------------- VALU-pipe cross-lane primitives ---------------------------
// offset 32: v_permlane32_swap_b32 with both operands = x -> vsrc result is
// [x.hi32, x.hi32]: lanes 0-31 receive lane i+32.
__device__ __forceinline__ unsigned pl_down32_u(unsigned x) {
  unsigned d = x, s = x;
  asm volatile("s_nop 1\n\tv_permlane32_swap_b32 %0, %1" : "+v"(d), "+v"(s));
  return s;
}
// offset 16: v_permlane16_swap_b32 -> lanes 0-15 get lane i+16.
__device__ __forceinline__ unsigned pl_down16_u(unsigned x) {
  unsigned d = x, s = x;
  asm volatile("s_nop 1\n\tv_permlane16_swap_b32 %0, %1" : "+v"(d), "+v"(s));
  return s;
}
// offsets 8/4/2/1: DPP row_shl:N -> lane n receives lane n+N within its row.
template<int N>
__device__ __forceinline__ unsigned dpp_shl_u(unsigned x) {
  return (unsigned)__builtin_amdgcn_update_dpp(0, (int)x, 0x100 | N, 0xF, 0xF, true);
}
__device__ __forceinline__ float pl_down32_f(float x) {
  return __uint_as_float(pl_down32_u(__float_as_uint(x)));
}
__device__ __forceinline__ float pl_down16_f(float x) {
  return __uint_as_float(pl_down16_u(__float_as_uint(x)));
}
template<int N>
__device__ __forceinline__ float dpp_shl_f(float x) {
  return __uint_as_float(dpp_shl_u<N>(__float_as_uint(x)));
}
__device__ __forceinline__ double pl_down32_d(double x) {
  unsigned lo = pl_down32_u((unsigned)__double2loint(x));
  unsigned hi = pl_down32_u((unsigned)__double2hiint(x));
  return __hiloint2double((int)hi, (int)lo);
}
__device__ __forceinline__ double pl_down16_d(double x) {
  unsigned lo = pl_down16_u((unsigned)__double2loint(x));
  unsigned hi = pl_down16_u((unsigned)__double2hiint(x));
  return __hiloint2double((int)hi, (int)lo);
}
template<int N>
__device__ __forceinline__ double dpp_shl_d(double x) {
  unsigned lo = dpp_shl_u<N>((unsigned)__double2loint(x));
  unsigned hi = dpp_shl_u<N>((unsigned)__double2hiint(x));
  return __hiloint2double((int)hi, (int)lo);
}
// lane-0 broadcast (all lanes active at every call site) -> readfirstlane.
__device__ __forceinline__ float bcast0_f(float x) {
  return __uint_as_float((unsigned)__builtin_amdgcn_readfirstlane((int)__float_as_uint(x)));
}
__device__ __forceinline__ int bcast0_i(int x) {
  return __builtin_amdgcn_readfirstlane(x);
}
__device__ __forceinline__ double bcast0_d(double x) {
  int lo = __builtin_amdgcn_readfirstlane(__double2loint(x));
  int hi = __builtin_amdgcn_readfirstlane(__double2hiint(x));
  return __hiloint2double(hi, lo);
}

// ---------------- fused kernel: samplers (bid<128) + producers --------------
// STEP_BODY: EXACT R14-validated (701 us, absmax 0.0) sampler step body.
// Reads candg + full gw table with register demand-prefetch (the schedule
// the compiler handles best — R15/R16 evidence).
#define STEP_BODY(S, CC, GG, CN, GN)                                          \
  {                                                                           \
    const int step = (S);                                                     \
    /* prefetch step+1 (full step of slack) */                                \
    const int sn = (step + 1 < T_COLS) ? step + 1 : step;                     \
    _Pragma("unroll")                                                         \
    for (int i = 0; i < NCAND; ++i) {                                         \
      CN[i] = candg[sn * KC + lane + 64 * i];                                 \
      GN[i] = gw[gb + (size_t)sn * KC + lane + 64 * i];                       \
    }                                                                         \
    /* slide window state (lanes 0-15 hold per-bit f64 state) */              \
    if (lane < 16) {                                                          \
      if (step > 0) {                                                         \
        double pw = (double)s_pi[step - 1];                                   \
        if ((c_last >> lane) & 1u) p1_d += pw;                                \
        pt_d += pw;                                                           \
      }                                                                       \
      if (step >= 33) {                                                       \
        double pw = (double)s_pi[step - 33];                                  \
        if (((uint32_t)s_cint[step - 33] >> lane) & 1u) p1_d -= pw;           \
        pt_d -= pw;                                                           \
      }                                                                       \
    }                                                                         \
    float Dl = (float)(pt_d - (p1_d + p1_d));                                 \
    /* S0: 16-lane f64 butterfly on the lane-0 lineage (row_shl 1,2,4,8). */  \
    double s0d = p1_d;                                                        \
    s0d += dpp_shl_d<1>(s0d);                                                 \
    s0d += dpp_shl_d<2>(s0d);                                                 \
    s0d += dpp_shl_d<4>(s0d);                                                 \
    s0d += dpp_shl_d<8>(s0d);                                                 \
    const float S0f  = bcast0_f((float)s0d);                                  \
    const float Pt16 = bcast0_f((float)(16.0 * pt_d));                        \
    {                                                                         \
      int n = lane >> 4, v = lane & 15;                                       \
      float d0 = __shfl(Dl, 4 * n + 0);                                       \
      float d1 = __shfl(Dl, 4 * n + 1);                                       \
      float d2 = __shfl(Dl, 4 * n + 2);                                       \
      float d3 = __shfl(Dl, 4 * n + 3);                                       \
      float t = 0.0f;                                                         \
      if (v & 1) t += d0;                                                     \
      if (v & 2) t += d1;                                                     \
      if (v & 4) t += d2;                                                     \
      if (v & 8) t += d3;                                                     \
      s_T[n][v] = t;                                                          \
    }                                                                         \
    __builtin_amdgcn_wave_barrier();                                          \
    const float pi_i   = s_pi[step];                                          \
    const float i_pf   = (float)step;                                         \
    const float factor = (step > 0) ? (i_pf / fminf(i_pf, 32.0f)) : 0.0f;     \
    float un[NCAND];                                                          \
    _Pragma("unroll")                                                         \
    for (int i = 0; i < NCAND; ++i) {                                         \
      uint32_t c = CC[i];                                                     \
      float sc = S0f + s_T[0][c & 15];                                        \
      sc += s_T[1][(c >> 4) & 15];                                            \
      sc += s_T[2][(c >> 8) & 15];                                            \
      sc += s_T[3][(c >> 12) & 15];                                           \
      float sv = Pt16 - sc;                                                   \
      int w = __popc(c);                                                      \
      int m = 16 * w - 256 + step;                                            \
      float sq  = (float)(m * m) * 0.00390625f;                               \
      float obk = (pi_i * sq) * 0.0625f;                                      \
      un[i] = -(obk + factor * (pi_i * sv));                                  \
    }                                                                         \
    /* rmax: exact global max (fmax associative-exact; hand tree + DPP) */    \
    float wt10[10];                                                           \
    _Pragma("unroll")                                                         \
    for (int q = 0; q < 10; ++q) wt10[q] = fmaxf(un[2*q], un[2*q+1]);         \
    float wt5[5];                                                             \
    _Pragma("unroll")                                                         \
    for (int q = 0; q < 5; ++q) wt5[q] = fmaxf(wt10[2*q], wt10[2*q+1]);       \
    float wm = fmaxf(fmaxf(fmaxf(wt5[0], wt5[1]), fmaxf(wt5[2], wt5[3])),     \
                     wt5[4]);                                                 \
    wm = fmaxf(wm, pl_down32_f(wm));                                          \
    wm = fmaxf(wm, pl_down16_f(wm));                                          \
    wm = fmaxf(wm, dpp_shl_f<8>(wm));                                         \
    wm = fmaxf(wm, dpp_shl_f<4>(wm));                                         \
    wm = fmaxf(wm, dpp_shl_f<2>(wm));                                         \
    wm = fmaxf(wm, dpp_shl_f<1>(wm));                                         \
    wm = bcast0_f(wm);                                                        \
    /* lsum: f64-accumulated fp32 exp terms (common-mode class) */            \
    double a0 = 0.0, a1 = 0.0;                                                \
    _Pragma("unroll")                                                         \
    for (int i = 0; i < NCAND; ++i) {                                         \
      float e = expf(un[i] - wm);                                             \
      if (i & 1) a1 += (double)e; else a0 += (double)e;                       \
    }                                                                         \
    double sw = a0 + a1;                                                      \
    sw += pl_down32_d(sw);                                                    \
    sw += pl_down16_d(sw);                                                    \
    sw += dpp_shl_d<8>(sw);                                                   \
    sw += dpp_shl_d<4>(sw);                                                   \
    sw += dpp_shl_d<2>(sw);                                                   \
    sw += dpp_shl_d<1>(sw);                                                   \
    const float lsum = logf((float)bcast0_d(sw));                             \
    /* exact z argmax, lowest-k ties (per-lane tree then cross-lane tree) */  \
    float z1[10]; int i1[10]; float u1[10];                                   \
    _Pragma("unroll")                                                         \
    for (int q = 0; q < 10; ++q) {                                            \
      float za = ((un[2*q]   - wm) - lsum) + GG[2*q];                         \
      float zb = ((un[2*q+1] - wm) - lsum) + GG[2*q+1];                       \
      int ia = (((64*(2*q)   + lane) << 16) | (int)CC[2*q]);                  \
      int ib = (((64*(2*q+1) + lane) << 16) | (int)CC[2*q+1]);                \
      bool tt = (zb > za);                                                    \
      z1[q] = tt ? zb : za; i1[q] = tt ? ib : ia;                             \
      u1[q] = tt ? un[2*q+1] : un[2*q];                                       \
    }                                                                         \
    float z2[5]; int i2[5]; float u2[5];                                      \
    _Pragma("unroll")                                                         \
    for (int q = 0; q < 5; ++q) {                                             \
      bool tt = (z1[2*q+1] > z1[2*q]);                                        \
      z2[q] = tt ? z1[2*q+1] : z1[2*q]; i2[q] = tt ? i1[2*q+1] : i1[2*q];     \
      u2[q] = tt ? u1[2*q+1] : u1[2*q];                                       \
    }                                                                         \
    float bz; int bi; float bu;                                               \
    {                                                                         \
      float zA, zB; int iA, iB; float uA, uB;                                 \
      bool t0 = (z2[1] > z2[0]);                                              \
      zA = t0 ? z2[1] : z2[0]; iA = t0 ? i2[1] : i2[0];                       \
      uA = t0 ? u2[1] : u2[0];                                                \
      bool t1 = (z2[3] > z2[2]);                                              \
      zB = t1 ? z2[3] : z2[2]; iB = t1 ? i2[3] : i2[2];                       \
      uB = t1 ? u2[3] : u2[2];                                                \
      bool t2 = (zB > zA);                                                    \
      zA = t2 ? zB : zA; iA = t2 ? iB : iA; uA = t2 ? uB : uA;                \
      bool t3 = (z2[4] > zA);                                                 \
      bz = t3 ? z2[4] : zA; bi = t3 ? i2[4] : iA; bu = t3 ? u2[4] : uA;       \
    }                                                                         \
    {                                                                         \
      float oz = pl_down32_f(bz); int oi = (int)pl_down32_u((unsigned)bi);    \
      float ou = pl_down32_f(bu);                                             \
      if (oz > bz || (oz == bz && oi < bi)) { bz = oz; bi = oi; bu = ou; }    \
    }                                                                         \
    {                                                                         \
      float oz = pl_down16_f(bz); int oi = (int)pl_down16_u((unsigned)bi);    \
      float ou = pl_down16_f(bu);                                             \
      if (oz > bz || (oz == bz && oi < bi)) { bz = oz; bi = oi; bu = ou; }    \
    }                                                                         \
    {                                                                         \
      float oz = dpp_shl_f<8>(bz); int oi = (int)dpp_shl_u<8>((unsigned)bi);  \
      float ou = dpp_shl_f<8>(bu);                                            \
      if (oz > bz || (oz == bz && oi < bi)) { bz = oz; bi = oi; bu = ou; }    \
    }                                                                         \
    {                                                                         \
      float oz = dpp_shl_f<4>(bz); int oi = (int)dpp_shl_u<4>((unsigned)bi);  \
      float ou = dpp_shl_f<4>(bu);                                            \
      if (oz > bz || (oz == bz && oi < bi)) { bz = oz; bi = oi; bu = ou; }    \
    }                                                                         \
    {                                                                         \
      float oz = dpp_shl_f<2>(bz); int oi = (int)dpp_shl_u<2>((unsigned)bi);  \
      float ou = dpp_shl_f<2>(bu);                                            \
      if (oz > bz || (oz == bz && oi < bi)) { bz = oz; bi = oi; bu = ou; }    \
    }                                                                         \
    {                                                                         \
      float oz = dpp_shl_f<1>(bz); int oi = (int)dpp_shl_u<1>((unsigned)bi);  \
      float ou = dpp_shl_f<1>(bu);                                            \
      if (oz > bz || (oz == bz && oi < bi)) { bz = oz; bi = oi; bu = ou; }    \
    }                                                                         \
    int wpk = bcast0_i(bi);                                                   \
    c_last = (uint32_t)wpk & 0xFFFFu;                                         \
    if (lane == 0) {                                                          \
      s_cint[step] = (unsigned short)c_last;                                  \
      lp_acc += (double)((bu - wm) - lsum);                                   \
    }                                                                         \
  }

__global__ void __launch_bounds__(256)
mrf_fused2(const float* __restrict__ pi, float* __restrict__ out,
           const unsigned short* __restrict__ candg,
           float* __restrict__ gw,
           int* __restrict__ done) {
#pragma clang fp contract(off)
  const int bid = blockIdx.x;
  const int tid = threadIdx.x;

  if (bid >= B_ROWS) {
    // ------------- producer block: one (bb, step) cohort of gumbels -------
    // Identical math and layout to the fallback gumbel_kernel.
    const int pbid = bid - B_ROWS;
    const int bb   = pbid & (B_ROWS - 1);
    const int step = pbid >> 7;
    __shared__ uint32_t s_ks[2];
    if (tid == 0) {
      uint32_t ks[2];
      derive_keys(step, nullptr, ks, nullptr);
      s_ks[0] = ks[0]; s_ks[1] = ks[1];
    }
    __syncthreads();
    const uint32_t ks0 = s_ks[0], ks1 = s_ks[1];
    const size_t base = ((size_t)bb * T_COLS + step) * KC;
#pragma unroll
    for (int i = 0; i < 5; ++i) {
      int k = tid + 256 * i;
      uint32_t j = (uint32_t)(bb * KC + k);
      gw[base + k] = gumbel_at(ks0, ks1, j);
    }
    // one release per BLOCK (coarse): __syncthreads drains vmcnt; the
    // release RMW publishes the block's table writes device-wide.
    __syncthreads();
    if (tid == 0) {
      __threadfence();
      __hip_atomic_fetch_add(&done[step], 1, __ATOMIC_RELEASE,
                             __HIP_MEMORY_SCOPE_AGENT);
    }
    return;
  }

  // ---------------- sampler block: wave0 only (threads 64+ exit) ----------
  if (tid >= 64) return;
  const int b    = bid;
  const int lane = tid;
  const size_t gb = (size_t)b * T_COLS * KC;

  __shared__ float          s_pi[T_COLS];
  __shared__ unsigned short s_cint[T_COLS];
  __shared__ float          s_T[4][16];

  for (int t = lane; t < T_COLS; t += 64) s_pi[t] = pi[t];
  // single live wave: intra-wave lgkmcnt ordering suffices; no barrier.

  __builtin_amdgcn_s_setprio(1);            // win SIMD arbitration vs producers

  double lp_acc = 0.0;                      // lane 0 only
  uint32_t c_last = 0;
  double p1_d = 0.0, pt_d = 0.0;            // sliding window state (lanes<16)

  float    gA[NCAND], gB[NCAND];
  uint32_t cA[NCAND], cB[NCAND];

  // prologue: wait for step-0 cohort, then load step-0 data into A buffers
  if (done) {
    if (lane == 0) {
      while (__hip_atomic_load(&done[0], __ATOMIC_ACQUIRE,
                               __HIP_MEMORY_SCOPE_AGENT) < B_ROWS)
        __builtin_amdgcn_s_sleep(8);
    }
  }
#pragma unroll
  for (int i = 0; i < NCAND; ++i) {
    cA[i] = candg[lane + 64 * i];
    gA[i] = gw[gb + lane + 64 * i];
  }

  for (int s2 = 0; s2 < T_COLS; s2 += 2) {
    // bodies s2 and s2+1 prefetch steps s2+1 and s2+2: gate on their cohorts.
    if (done) {
      if (lane == 0) {
        int n1 = (s2 + 1 < T_COLS) ? s2 + 1 : T_COLS - 1;
        int n2 = (s2 + 2 < T_COLS) ? s2 + 2 : T_COLS - 1;
        while (__hip_atomic_load(&done[n1], __ATOMIC_ACQUIRE,
                                 __HIP_MEMORY_SCOPE_AGENT) < B_ROWS)
          __builtin_amdgcn_s_sleep(8);
        while (__hip_atomic_load(&done[n2], __ATOMIC_ACQUIRE,
                                 __HIP_MEMORY_SCOPE_AGENT) < B_ROWS)
          __builtin_amdgcn_s_sleep(8);
      }
    }
    STEP_BODY(s2,     cA, gA, cB, gB)
    STEP_BODY(s2 + 1, cB, gB, cA, gA)
  }

  // outputs (FP32): c_btls one-hot [B,T,L,S] then log_prob_b [B]
  for (int idx2 = lane; idx2 < T_COLS * 32; idx2 += 64) {
    int t    = idx2 >> 5;
    int rem  = idx2 & 31;
    int l    = rem >> 1;
    int sbit = rem & 1;
    uint32_t code = s_cint[t];
    int bit = (int)((code >> (15 - l)) & 1u);
    out[(size_t)b * 8192 + idx2] = (float)(sbit ? bit : (1 - bit));
  }
  if (lane == 0) {
    out[(size_t)B_ROWS * 8192 + b] = (float)(lp_acc / 256.0);
  }
}

// ---------------- legacy sequential kernel (fallback modes 0/1) -------------
template<int MODE>
__global__ void __launch_bounds__(BLOCK_S)
mrf_seq_kernel(const float* __restrict__ pi, float* __restrict__ out,
               const float* __restrict__ gw,
               const unsigned short* __restrict__ candg) {
#pragma clang fp contract(off)
  const int b    = blockIdx.x;
  const int tid  = threadIdx.x;
  const bool has1 = tid < (KC - BLOCK_S);

  __shared__ float          s_pi[T_COLS];
  __shared__ unsigned short s_cand[KC];
  __shared__ float          s_unnorm[KC];
  __shared__ unsigned short s_cint[T_COLS];
  __shared__ int            s_dC[17][17];
  __shared__ int            s_gw0[17], s_gw1[17], s_gbase[17];
  __shared__ int            s_ngrp;
  __shared__ uint32_t       s_keys[6];
  __shared__ float          s_pw[WWIN];
  __shared__ unsigned short s_wc[WWIN];
  __shared__ float          s_redf[NWAVE_S];
  __shared__ double         s_redd[NWAVE_S];
  __shared__ int            s_redi[NWAVE_S];
  __shared__ float          s_bcast[2];

  for (int t = tid; t < T_COLS; t += BLOCK_S) s_pi[t] = pi[t];
  if (MODE == 0) {
    for (int i = tid; i < 289; i += BLOCK_S) s_dC[i/17][i%17] = dC[i/17][i%17];
  }
  double lp_acc = 0.0;
  __syncthreads();

  for (int step = 0; step < T_COLS; ++step) {
    if (tid == 0) {
      if (MODE == 1) {
        uint32_t ks[2];
        derive_keys(step, nullptr, ks, nullptr);
        s_keys[2] = ks[0]; s_keys[3] = ks[1];
      } else {
        uint32_t ks[2], k2[2];
        derive_keys(step, nullptr, ks, k2);
        s_keys[2] = ks[0]; s_keys[3] = ks[1];
        s_keys[4] = k2[0]; s_keys[5] = k2[1];
        int ws[17], am[17];
        for (int w = 0; w < 17; ++w) {
          int m = 16 * w - 256 + step;
          am[w] = m < 0 ? -m : m;
          ws[w] = w;
        }
        for (int a2 = 1; a2 < 17; ++a2) {
          int wvv = ws[a2], kv = am[wvv];
          int j2 = a2 - 1;
          while (j2 >= 0 && am[ws[j2]] > kv) { ws[j2 + 1] = ws[j2]; --j2; }
          ws[j2 + 1] = wvv;
        }
        int ng = 0, base = 0, idx = 0;
        while (idx < 17) {
          int w0 = ws[idx]; int a0v = am[w0]; int w1 = -1;
          if (idx + 1 < 17 && am[ws[idx + 1]] == a0v) { w1 = ws[idx + 1]; ++idx; }
          ++idx;
          s_gw0[ng] = w0; s_gw1[ng] = w1; s_gbase[ng] = base;
          base += dC[16][w0] + (w1 >= 0 ? dC[16][w1] : 0);
          ++ng;
          if (base >= PTOP) break;
        }
        s_ngrp = ng;
      }
    }
    if (tid < WWIN) {
      int win = step - WWIN + tid;
      s_pw[tid] = (win >= 0) ? s_pi[win] : 0.0f;
      s_wc[tid] = (win >= 0) ? s_cint[win] : (unsigned short)0;
    }
    __syncthreads();

    uint32_t c0, c1 = 0;
    if (MODE >= 1) {
      c0 = candg[step * KC + tid];
      if (has1) c1 = candg[step * KC + BLOCK_S + tid];
    } else {
      {
        int p = tid;
        int g = 0;
        for (int t2 = 1; t2 < s_ngrp; ++t2) if (s_gbase[t2] <= p) g = t2;
        int q  = p - s_gbase[g];
        int r0 = s_gw0[g], r1 = s_gw1[g];
        uint32_t code = 0;
        for (int pos = 15; pos >= 0; --pos) {
          int n0 = ((r0 >= 0 && r0 <= pos) ? s_dC[pos][r0] : 0)
                 + ((r1 >= 0 && r1 <= pos) ? s_dC[pos][r1] : 0);
          if (q >= n0) { q -= n0; code |= (1u << pos); --r0; if (r1 >= 0) --r1; }
        }
        c0 = code;
      }
      if (has1) {
        int t2 = tid;
        uint32_t a0, a1;
#if JAX_PARTITIONABLE
        tf_block(s_keys[4], s_keys[5], 0u, (uint32_t)t2, a0, a1);
        c1 = (a0 ^ a1) & 0xFFFFu;
#else
        if (t2 < 128) { tf_block(s_keys[4], s_keys[5], (uint32_t)t2, (uint32_t)(128 + t2), a0, a1);
                        c1 = a0 & 0xFFFFu; }
        else          { tf_block(s_keys[4], s_keys[5], (uint32_t)(t2 - 128), (uint32_t)t2, a0, a1);
                        c1 = a1 & 0xFFFFu; }
#endif
      }
    }
    s_cand[tid] = (unsigned short)c0;
    if (has1) s_cand[BLOCK_S + tid] = (unsigned short)c1;

    const float pi_i   = s_pi[step];
    const float i_pf   = (float)step;
    const float factor = (step > 0) ? (i_pf / fminf(i_pf, 32.0f)) : 0.0f;

    float un0, un1 = -3.402823466e+38f;
    {
      int w = __popc(c0);
      int m = 16 * w - 256 + step;
      float sq  = (float)(m * m) * 0.00390625f;
      float obk = (pi_i * sq) * 0.0625f;
      float s = 0.0f;
      for (int w2 = 0; w2 < WWIN; ++w2) {
        float ov = (float)(16 - __popc(c0 ^ (uint32_t)s_wc[w2]));
        s = s + s_pw[w2] * ov;
      }
      un0 = -(obk + factor * (pi_i * s));
    }
    if (has1) {
      int w = __popc(c1);
      int m = 16 * w - 256 + step;
      float sq  = (float)(m * m) * 0.00390625f;
      float obk = (pi_i * sq) * 0.0625f;
      float s = 0.0f;
      for (int w2 = 0; w2 < WWIN; ++w2) {
        float ov = (float)(16 - __popc(c1 ^ (uint32_t)s_wc[w2]));
        s = s + s_pw[w2] * ov;
      }
      un1 = -(obk + factor * (pi_i * s));
    }
    s_unnorm[tid] = un0;
    if (has1) s_unnorm[BLOCK_S + tid] = un1;

    float g0v = 0.0f, g1v = 0.0f;
    {
      const uint32_t ks0 = s_keys[2], ks1 = s_keys[3];
      g0v = gumbel_at(ks0, ks1, (uint32_t)(b * KC + tid));
      if (has1) g1v = gumbel_at(ks0, ks1, (uint32_t)(b * KC + BLOCK_S + tid));
    }

    float pmax = has1 ? fmaxf(un0, un1) : un0;
    for (int off = 32; off > 0; off >>= 1) pmax = fmaxf(pmax, __shfl_down(pmax, off));
    if ((tid & 63) == 0) s_redf[tid >> 6] = pmax;
    __syncthreads();
    if (tid == 0) {
      float mm = s_redf[0];
      for (int w2 = 1; w2 < NWAVE_S; ++w2) mm = fmaxf(mm, s_redf[w2]);
      s_bcast[0] = mm;
    }
    __syncthreads();
    const float rmax = s_bcast[0];

    double acc = (double)((float)exp((double)(un0 - rmax)));
    if (has1) acc += (double)((float)exp((double)(un1 - rmax)));
    for (int off = 32; off > 0; off >>= 1) acc += __shfl_down(acc, off);
    if ((tid & 63) == 0) s_redd[tid >> 6] = acc;
    __syncthreads();
    if (tid == 0) {
      double ss = 0.0;
      for (int w2 = 0; w2 < NWAVE_S; ++w2) ss += s_redd[w2];
      float sum_f = (float)ss;
      s_bcast[1] = (float)log((double)sum_f);
    }
    __syncthreads();
    const float lsum = s_bcast[1];

    float bz = ((un0 - rmax) - lsum) + g0v;
    int   bi = tid;
    if (has1) {
      float z1 = ((un1 - rmax) - lsum) + g1v;
      if (z1 > bz) { bz = z1; bi = BLOCK_S + tid; }
    }
    for (int off = 32; off > 0; off >>= 1) {
      float oz = __shfl_down(bz, off);
      int   oi = __shfl_down(bi, off);
      if (oz > bz || (oz == bz && oi < bi)) { bz = oz; bi = oi; }
    }
    if ((tid & 63) == 0) { s_redf[tid >> 6] = bz; s_redi[tid >> 6] = bi; }
    __syncthreads();
    if (tid == 0) {
      float bz2 = s_redf[0]; int bi2 = s_redi[0];
      for (int w2 = 1; w2 < NWAVE_S; ++w2) {
        if (s_redf[w2] > bz2 || (s_redf[w2] == bz2 && s_redi[w2] < bi2)) {
          bz2 = s_redf[w2]; bi2 = s_redi[w2];
        }
      }
      s_cint[step] = s_cand[bi2];
      float lpw = (s_unnorm[bi2] - rmax) - lsum;
      lp_acc += (double)lpw;
    }
    __syncthreads();
  }

  for (int idx2 = tid; idx2 < T_COLS * 32; idx2 += BLOCK_S) {
    int t    = idx2 >> 5;
    int rem  = idx2 & 31;
    int l    = rem >> 1;
    int sbit = rem & 1;
    uint32_t code = s_cint[t];
    int bit = (int)((code >> (15 - l)) & 1u);
    out[(size_t)b * 8192 + idx2] = (float)(sbit ? bit : (1 - bit));
  }
  if (tid == 0) {
    out[(size_t)B_ROWS * 8192 + b] = (float)(lp_acc / 256.0);
  }
}

extern "C" void kernel_launch(void* const* d_in, const int* in_sizes, int n_in,
                              void* d_out, int out_size, void* d_ws, size_t ws_size,
                              hipStream_t stream) {
  const float* pi = (const float*)d_in[0];
  float* out = (float*)d_out;

  const size_t cand_bytes = (size_t)T_COLS * KC * sizeof(unsigned short); // 655,360
  const size_t done_bytes = 1024;                                         // 256 ints
  const size_t gw_bytes   = (size_t)B_ROWS * T_COLS * KC * sizeof(float); // 167,772,160

  if (ws_size >= cand_bytes + done_bytes + gw_bytes) {
    // overlapped path: [candg][done][gw]
    unsigned short* candg = (unsigned short*)d_ws;
    int*   done = (int*)((char*)d_ws + cand_bytes);
    float* gw   = (float*)((char*)d_ws + cand_bytes + done_bytes);
    hipMemsetAsync(done, 0, done_bytes, stream);
    cand_kernel<<<dim3(T_COLS), dim3(256), 0, stream>>>(candg);
    mrf_fused2<<<dim3(B_ROWS + T_COLS * B_ROWS), dim3(256), 0, stream>>>(
        pi, out, candg, gw, done);
  } else if (ws_size >= cand_bytes + gw_bytes) {
    // serialized fallback (R14 behavior): [candg][gw]
    unsigned short* candg = (unsigned short*)d_ws;
    float* gw = (float*)((char*)d_ws + cand_bytes);
    gumbel_kernel<<<dim3(T_COLS * B_ROWS), dim3(256), 0, stream>>>(gw);
    cand_kernel<<<dim3(T_COLS), dim3(256), 0, stream>>>(candg);
    mrf_fused2<<<dim3(B_ROWS), dim3(256), 0, stream>>>(
        pi, out, candg, gw, nullptr);
  } else if (ws_size >= cand_bytes) {
    unsigned short* candg = (unsigned short*)d_ws;
    cand_kernel<<<dim3(T_COLS), dim3(256), 0, stream>>>(candg);
    mrf_seq_kernel<1><<<dim3(B_ROWS), dim3(BLOCK_S), 0, stream>>>(pi, out, nullptr, candg);
  } else {
    mrf_seq_kernel<0><<<dim3(B_ROWS), dim3(BLOCK_S), 0, stream>>>(pi, out, nullptr, nullptr);
  }
}

// Round 7
// 1284.881 us; speedup vs baseline: 1.9006x; 1.7133x over previous
//
#include <hip/hip_runtime.h>
#include <stdint.h>
#include <math.h>

// ---------------------------------------------------------------------------
// MRF codebook generator: bit-exact reproduction of the JAX reference.
// Round 20: REVERT to the R14 champion structure (gumbel precompute ->
// cand -> one-wave sampler; 998 us total) + exactly three micro-deltas,
// each numerics-validated (absmax 0.0) in three prior passing runs and
// each removing pure LDS-pipe latency from the serial chain:
//   1. readlane D-broadcast (4 ds_bpermute -> VALU readlane + selects).
//   2. per-lane 64-bit winner-bit history register replaces the dependent
//      s_cint[step-33] LDS read (bit 32 == winner bit of step-33).
//   3. earg[i] = un[i]-wm computed once (exp loop) and reused in z loop
//      (same expression -> same bits).
// NOTHING else changed vs R14: prefetch placement (top of body, registers),
// interleaved un-loop with inline s_T reads, DPP/permlane tree shapes,
// expf/logf lsum path, argmax tie-break, launch config.
// Overlap lines (R17/R18/R19) abandoned: the serial sampler wave is
// hypersensitive to CU-sharing and coherence ops (3x slowdowns measured).
// ---------------------------------------------------------------------------

#define JAX_PARTITIONABLE 1

#define T_COLS 256
#define B_ROWS 128
#define KC     1280
#define PTOP   1024
#define RRAND  256
#define WWIN   32
#define NCAND  20            // KC / 64
#define BLOCK_S 1024         // legacy fallback block
#define NWAVE_S (BLOCK_S / 64)

__device__ __constant__ int dC[17][17] = {
  {1},
  {1,1},
  {1,2,1},
  {1,3,3,1},
  {1,4,6,4,1},
  {1,5,10,10,5,1},
  {1,6,15,20,15,6,1},
  {1,7,21,35,35,21,7,1},
  {1,8,28,56,70,56,28,8,1},
  {1,9,36,84,126,126,84,36,9,1},
  {1,10,45,120,210,252,210,120,45,10,1},
  {1,11,55,165,330,462,462,330,165,55,11,1},
  {1,12,66,220,495,792,924,792,495,220,66,12,1},
  {1,13,78,286,715,1287,1716,1716,1287,715,286,78,13,1},
  {1,14,91,364,1001,2002,3003,3432,3003,2002,1001,364,91,14,1},
  {1,15,105,455,1365,3003,5005,6435,6435,5005,3003,1365,455,105,15,1},
  {1,16,120,560,1820,4368,8008,11440,12870,11440,8008,4368,1820,560,120,16,1}
};

// Threefry-2x32, 20 rounds, JAX key schedule.
__device__ __forceinline__ void tf_block(uint32_t k0, uint32_t k1,
                                         uint32_t x0, uint32_t x1,
                                         uint32_t& o0, uint32_t& o1) {
  uint32_t ks2 = k0 ^ k1 ^ 0x1BD11BDAu;
  x0 += k0; x1 += k1;
#define TFR(r) { x0 += x1; x1 = (x1 << (r)) | (x1 >> (32 - (r))); x1 ^= x0; }
  TFR(13) TFR(15) TFR(26) TFR(6)   x0 += k1;  x1 += ks2 + 1u;
  TFR(17) TFR(29) TFR(16) TFR(24)  x0 += ks2; x1 += k0 + 2u;
  TFR(13) TFR(15) TFR(26) TFR(6)   x0 += k0;  x1 += k1 + 3u;
  TFR(17) TFR(29) TFR(16) TFR(24)  x0 += k1;  x1 += ks2 + 4u;
  TFR(13) TFR(15) TFR(26) TFR(6)   x0 += ks2; x1 += k0 + 5u;
#undef TFR
  o0 = x0; o1 = x1;
}

// fold_in(key(42), step) -> k_rand/k_samp/randint-k2 per PRNG mode.
__device__ __forceinline__ void derive_keys(int step,
                                            uint32_t* krand, uint32_t* ksamp,
                                            uint32_t* k2) {
  uint32_t y0, y1;
  tf_block(0u, 42u, 0u, (uint32_t)step, y0, y1);
  uint32_t kr0 = y0, kr1 = y1;
#if JAX_PARTITIONABLE
  uint32_t r0, r1;
  tf_block(kr0, kr1, 0u, 0u, r0, r1);            // k_rand
  if (krand) { krand[0] = r0; krand[1] = r1; }
  if (ksamp) { tf_block(kr0, kr1, 0u, 1u, y0, y1); ksamp[0] = y0; ksamp[1] = y1; }
  if (k2)    { tf_block(r0, r1, 0u, 1u, y0, y1);  k2[0] = y0;  k2[1] = y1; }
#else
  uint32_t a0,a1,b0,b1;
  tf_block(kr0, kr1, 0u, 2u, a0, a1);
  tf_block(kr0, kr1, 1u, 3u, b0, b1);
  if (krand) { krand[0] = a0; krand[1] = b0; }
  if (ksamp) { ksamp[0] = a1; ksamp[1] = b1; }
  if (k2) {
    uint32_t c0,c1,d0,d1;
    tf_block(a0, b0, 0u, 2u, c0, c1);
    tf_block(a0, b0, 1u, 3u, d0, d1);
    k2[0] = c1; k2[1] = d1;
  }
#endif
}

// JAX uniform(tiny,1) -> gumbel, fp32 logs correctly-rounded-from-double.
__device__ __forceinline__ float gumbel_from_bits(uint32_t bits) {
  uint32_t fb = (bits >> 9) | 0x3f800000u;
  float f = __uint_as_float(fb) - 1.0f;
  float u = (f == 0.0f) ? 1.17549435e-38f : f;
  float l1 = (float)log((double)u);
  float l2 = (float)log((double)(-l1));
  return -l2;
}

__device__ __forceinline__ float gumbel_at(uint32_t ks0, uint32_t ks1, uint32_t j) {
  uint32_t g0, g1;
#if JAX_PARTITIONABLE
  tf_block(ks0, ks1, 0u, j, g0, g1);
  return gumbel_from_bits(g0 ^ g1);
#else
  uint32_t half = (uint32_t)(B_ROWS * KC / 2);
  if (j < half) { tf_block(ks0, ks1, j, j + half, g0, g1);  return gumbel_from_bits(g0); }
  else          { tf_block(ks0, ks1, j - half, j, g0, g1);  return gumbel_from_bits(g1); }
#endif
}

// ---------------- precompute kernel G: gumbel[b][step][k] -------------------
__global__ void __launch_bounds__(256)
gumbel_kernel(float* __restrict__ gw) {
  const int bb   = blockIdx.x & (B_ROWS - 1);
  const int step = blockIdx.x >> 7;
  const int tid  = threadIdx.x;
  __shared__ uint32_t s_ks[2];
  if (tid == 0) {
    uint32_t ks[2];
    derive_keys(step, nullptr, ks, nullptr);
    s_ks[0] = ks[0]; s_ks[1] = ks[1];
  }
  __syncthreads();
  const uint32_t ks0 = s_ks[0], ks1 = s_ks[1];
  const size_t base = ((size_t)bb * T_COLS + step) * KC;
#pragma unroll
  for (int i = 0; i < 5; ++i) {
    int k = tid + 256 * i;
    uint32_t j = (uint32_t)(bb * KC + k);
    gw[base + k] = gumbel_at(ks0, ks1, j);
  }
}

// ---------------- precompute kernel C: cand[step][k] ------------------------
__global__ void __launch_bounds__(256)
cand_kernel(unsigned short* __restrict__ candg) {
  const int step = blockIdx.x;
  const int tid  = threadIdx.x;
  __shared__ int s_dC[17][17];
  __shared__ int s_gw0[17], s_gw1[17], s_gbase[17];
  __shared__ int s_ngrp;
  __shared__ uint32_t s_k2[2];
  for (int i = tid; i < 289; i += 256) s_dC[i/17][i%17] = dC[i/17][i%17];
  if (tid == 0) {
    uint32_t k2[2];
    derive_keys(step, nullptr, nullptr, k2);
    s_k2[0] = k2[0]; s_k2[1] = k2[1];
    int ws[17], am[17];
    for (int w = 0; w < 17; ++w) {
      int m = 16 * w - 256 + step;
      am[w] = m < 0 ? -m : m;
      ws[w] = w;
    }
    for (int a2 = 1; a2 < 17; ++a2) {
      int wv = ws[a2], kv = am[wv];
      int j2 = a2 - 1;
      while (j2 >= 0 && am[ws[j2]] > kv) { ws[j2 + 1] = ws[j2]; --j2; }
      ws[j2 + 1] = wv;
    }
    int ng = 0, base = 0, idx = 0;
    while (idx < 17) {
      int w0 = ws[idx]; int a0v = am[w0]; int w1 = -1;
      if (idx + 1 < 17 && am[ws[idx + 1]] == a0v) { w1 = ws[idx + 1]; ++idx; }
      ++idx;
      s_gw0[ng] = w0; s_gw1[ng] = w1; s_gbase[ng] = base;
      base += dC[16][w0] + (w1 >= 0 ? dC[16][w1] : 0);
      ++ng;
      if (base >= PTOP) break;
    }
    s_ngrp = ng;
  }
  __syncthreads();
  for (int p = tid; p < PTOP; p += 256) {
    int g = 0;
    for (int t2 = 1; t2 < s_ngrp; ++t2) if (s_gbase[t2] <= p) g = t2;
    int q  = p - s_gbase[g];
    int r0 = s_gw0[g], r1 = s_gw1[g];
    uint32_t code = 0;
    for (int pos = 15; pos >= 0; --pos) {
      int n0 = ((r0 >= 0 && r0 <= pos) ? s_dC[pos][r0] : 0)
             + ((r1 >= 0 && r1 <= pos) ? s_dC[pos][r1] : 0);
      if (q >= n0) { q -= n0; code |= (1u << pos); --r0; if (r1 >= 0) --r1; }
    }
    candg[step * KC + p] = (unsigned short)code;
  }
  {
    int t2 = tid;
    uint32_t a0, a1;
#if JAX_PARTITIONABLE
    tf_block(s_k2[0], s_k2[1], 0u, (uint32_t)t2, a0, a1);
    candg[step * KC + PTOP + t2] = (unsigned short)((a0 ^ a1) & 0xFFFFu);
#else
    if (t2 < 128) { tf_block(s_k2[0], s_k2[1], (uint32_t)t2, (uint32_t)(128 + t2), a0, a1);
                    candg[step * KC + PTOP + t2] = (unsigned short)(a0 & 0xFFFFu); }
    else          { tf_block(s_k2[0], s_k2[1], (uint32_t)(t2 - 128), (uint32_t)t2, a0, a1);
                    candg[step * KC + PTOP + t2] = (unsigned short)(a1 & 0xFFFFu); }
#endif
  }
}

// ---------------- VALU-pipe cross-lane primitives ---------------------------
// offset 32: v_permlane32_swap_b32 with both operands = x -> vsrc result is
// [x.hi32, x.hi32]: lanes 0-31 receive lane i+32.
__device__ __forceinline__ unsigned pl_down32_u(unsigned x) {
  unsigned d = x, s = x;
  asm volatile("s_nop 1\n\tv_permlane32_swap_b32 %0, %1" : "+v"(d), "+v"(s));
  return s;
}
// offset 16: v_permlane16_swap_b32 -> lanes 0-15 get lane i+16.
__device__ __forceinline__ unsigned pl_down16_u(unsigned x) {
  unsigned d = x, s = x;
  asm volatile("s_nop 1\n\tv_permlane16_swap_b32 %0, %1" : "+v"(d), "+v"(s));
  return s;
}
// offsets 8/4/2/1: DPP row_shl:N -> lane n receives lane n+N within its row.
template<int N>
__device__ __forceinline__ unsigned dpp_shl_u(unsigned x) {
  return (unsigned)__builtin_amdgcn_update_dpp(0, (int)x, 0x100 | N, 0xF, 0xF, true);
}
__device__ __forceinline__ float pl_down32_f(float x) {
  return __uint_as_float(pl_down32_u(__float_as_uint(x)));
}
__device__ __forceinline__ float pl_down16_f(float x) {
  return __uint_as_float(pl_down16_u(__float_as_uint(x)));
}
template<int N>
__device__ __forceinline__ float dpp_shl_f(float x) {
  return __uint_as_float(dpp_shl_u<N>(__float_as_uint(x)));
}
__device__ __forceinline__ double pl_down32_d(double x) {
  unsigned lo = pl_down32_u((unsigned)__double2loint(x));
  unsigned hi = pl_down32_u((unsigned)__double2hiint(x));
  return __hiloint2double((int)hi, (int)lo);
}
__device__ __forceinline__ double pl_down16_d(double x) {
  unsigned lo = pl_down16_u((unsigned)__double2loint(x));
  unsigned hi = pl_down16_u((unsigned)__double2hiint(x));
  return __hiloint2double((int)hi, (int)lo);
}
template<int N>
__device__ __forceinline__ double dpp_shl_d(double x) {
  unsigned lo = dpp_shl_u<N>((unsigned)__double2loint(x));
  unsigned hi = dpp_shl_u<N>((unsigned)__double2hiint(x));
  return __hiloint2double((int)hi, (int)lo);
}
// lane-0 broadcast (all lanes active at every call site) -> readfirstlane.
__device__ __forceinline__ float bcast0_f(float x) {
  return __uint_as_float((unsigned)__builtin_amdgcn_readfirstlane((int)__float_as_uint(x)));
}
__device__ __forceinline__ int bcast0_i(int x) {
  return __builtin_amdgcn_readfirstlane(x);
}
__device__ __forceinline__ double bcast0_d(double x) {
  int lo = __builtin_amdgcn_readfirstlane(__double2loint(x));
  int hi = __builtin_amdgcn_readfirstlane(__double2hiint(x));
  return __hiloint2double(hi, lo);
}
// readlane: wave-uniform fetch of lane l's float (VALU, no LDS).
#define RL_F(v, l) \
  __uint_as_float((unsigned)__builtin_amdgcn_readlane((int)__float_as_uint(v), (l)))

// ---------------- one-wave sequential kernel (MODE 2) -----------------------
// Step body macro: CC/GG = current-step cand/gumbel regs, CN/GN = prefetch
// target regs for step S+1. All loop indices are unroll-constant.
// R14 schedule exactly; deltas: readlane-D (no ds_bpermute), hist register
// (no s_cint[step-33] read), earg reuse.
#define STEP_BODY(S, CC, GG, CN, GN)                                          \
  {                                                                           \
    const int step = (S);                                                     \
    /* prefetch step+1 (full step of slack) */                                \
    const int sn = (step + 1 < T_COLS) ? step + 1 : step;                     \
    _Pragma("unroll")                                                         \
    for (int i = 0; i < NCAND; ++i) {                                         \
      CN[i] = candg[sn * KC + lane + 64 * i];                                 \
      GN[i] = gw[gb + (size_t)sn * KC + lane + 64 * i];                       \
    }                                                                         \
    /* slide window state (lanes 0-15 hold per-bit f64 state); step-33       \
       winner bit from the in-register history shift (bit 32). */            \
    if (lane < 16) {                                                          \
      if (step > 0) {                                                         \
        double pw = (double)s_pi[step - 1];                                   \
        if ((c_last >> lane) & 1u) p1_d += pw;                                \
        pt_d += pw;                                                           \
      }                                                                       \
      if (step >= 33) {                                                       \
        double pw = (double)s_pi[step - 33];                                  \
        if ((hist >> 32) & 1ull) p1_d -= pw;                                  \
        pt_d -= pw;                                                           \
      }                                                                       \
    }                                                                         \
    float Dl = (float)(pt_d - (p1_d + p1_d));                                 \
    /* S0: 16-lane f64 butterfly on the lane-0 lineage (row_shl 1,2,4,8). */  \
    double s0d = p1_d;                                                        \
    s0d += dpp_shl_d<1>(s0d);                                                 \
    s0d += dpp_shl_d<2>(s0d);                                                 \
    s0d += dpp_shl_d<4>(s0d);                                                 \
    s0d += dpp_shl_d<8>(s0d);                                                 \
    const float S0f  = bcast0_f((float)s0d);                                  \
    const float Pt16 = bcast0_f((float)(16.0 * pt_d));                        \
    {                                                                         \
      /* T-table build from readlane'd D values (no ds_bpermute): d0..d3     \
         are the same values the old __shfl(Dl, 4n+j) delivered, and the     \
         masked-add order is unchanged. */                                    \
      const float D0  = RL_F(Dl, 0),  D1  = RL_F(Dl, 1);                      \
      const float D2  = RL_F(Dl, 2),  D3  = RL_F(Dl, 3);                      \
      const float D4  = RL_F(Dl, 4),  D5  = RL_F(Dl, 5);                      \
      const float D6  = RL_F(Dl, 6),  D7  = RL_F(Dl, 7);                      \
      const float D8  = RL_F(Dl, 8),  D9  = RL_F(Dl, 9);                      \
      const float D10 = RL_F(Dl, 10), D11 = RL_F(Dl, 11);                     \
      const float D12 = RL_F(Dl, 12), D13 = RL_F(Dl, 13);                     \
      const float D14 = RL_F(Dl, 14), D15 = RL_F(Dl, 15);                     \
      int n = lane >> 4, v = lane & 15;                                       \
      float d0 = (n == 0) ? D0 : (n == 1) ? D4 : (n == 2) ? D8  : D12;        \
      float d1 = (n == 0) ? D1 : (n == 1) ? D5 : (n == 2) ? D9  : D13;        \
      float d2 = (n == 0) ? D2 : (n == 1) ? D6 : (n == 2) ? D10 : D14;        \
      float d3 = (n == 0) ? D3 : (n == 1) ? D7 : (n == 2) ? D11 : D15;        \
      float t = 0.0f;                                                         \
      if (v & 1) t += d0;                                                     \
      if (v & 2) t += d1;                                                     \
      if (v & 4) t += d2;                                                     \
      if (v & 8) t += d3;                                                     \
      s_T[n][v] = t;                                                          \
    }                                                                         \
    __builtin_amdgcn_wave_barrier();                                          \
    const float pi_i   = s_pi[step];                                          \
    const float i_pf   = (float)step;                                         \
    const float factor = (step > 0) ? (i_pf / fminf(i_pf, 32.0f)) : 0.0f;     \
    float un[NCAND];                                                          \
    _Pragma("unroll")                                                         \
    for (int i = 0; i < NCAND; ++i) {                                         \
      uint32_t c = CC[i];                                                     \
      float sc = S0f + s_T[0][c & 15];                                        \
      sc += s_T[1][(c >> 4) & 15];                                            \
      sc += s_T[2][(c >> 8) & 15];                                            \
      sc += s_T[3][(c >> 12) & 15];                                           \
      float sv = Pt16 - sc;                                                   \
      int w = __popc(c);                                                      \
      int m = 16 * w - 256 + step;                                            \
      float sq  = (float)(m * m) * 0.00390625f;                               \
      float obk = (pi_i * sq) * 0.0625f;                                      \
      un[i] = -(obk + factor * (pi_i * sv));                                  \
    }                                                                         \
    /* rmax: exact global max (fmax associative-exact; hand tree + DPP) */    \
    float wt10[10];                                                           \
    _Pragma("unroll")                                                         \
    for (int q = 0; q < 10; ++q) wt10[q] = fmaxf(un[2*q], un[2*q+1]);         \
    float wt5[5];                                                             \
    _Pragma("unroll")                                                         \
    for (int q = 0; q < 5; ++q) wt5[q] = fmaxf(wt10[2*q], wt10[2*q+1]);       \
    float wm = fmaxf(fmaxf(fmaxf(wt5[0], wt5[1]), fmaxf(wt5[2], wt5[3])),     \
                     wt5[4]);                                                 \
    wm = fmaxf(wm, pl_down32_f(wm));                                          \
    wm = fmaxf(wm, pl_down16_f(wm));                                          \
    wm = fmaxf(wm, dpp_shl_f<8>(wm));                                         \
    wm = fmaxf(wm, dpp_shl_f<4>(wm));                                         \
    wm = fmaxf(wm, dpp_shl_f<2>(wm));                                         \
    wm = fmaxf(wm, dpp_shl_f<1>(wm));                                         \
    wm = bcast0_f(wm);                                                        \
    /* lsum: f64-accumulated fp32 exp terms; earg kept for the z loop. */     \
    float earg[NCAND];                                                        \
    double a0 = 0.0, a1 = 0.0;                                                \
    _Pragma("unroll")                                                         \
    for (int i = 0; i < NCAND; ++i) {                                         \
      earg[i] = un[i] - wm;                                                   \
      float e = expf(earg[i]);                                                \
      if (i & 1) a1 += (double)e; else a0 += (double)e;                       \
    }                                                                         \
    double sw = a0 + a1;                                                      \
    sw += pl_down32_d(sw);                                                    \
    sw += pl_down16_d(sw);                                                    \
    sw += dpp_shl_d<8>(sw);                                                   \
    sw += dpp_shl_d<4>(sw);                                                   \
    sw += dpp_shl_d<2>(sw);                                                   \
    sw += dpp_shl_d<1>(sw);                                                   \
    const float lsum = logf((float)bcast0_d(sw));                             \
    /* exact z argmax, lowest-k ties: per-lane adjacent-range tree (left     \
       wins ties => lowest slot), then 6-level cross-lane tree with          \
       explicit (z, index) tie-break. z = (earg - lsum) + g, same bits. */    \
    float z1[10]; int i1[10]; float u1[10];                                   \
    _Pragma("unroll")                                                         \
    for (int q = 0; q < 10; ++q) {                                            \
      float za = (earg[2*q]   - lsum) + GG[2*q];                              \
      float zb = (earg[2*q+1] - lsum) + GG[2*q+1];                            \
      int ia = (((64*(2*q)   + lane) << 16) | (int)CC[2*q]);                  \
      int ib = (((64*(2*q+1) + lane) << 16) | (int)CC[2*q+1]);                \
      bool tt = (zb > za);                                                    \
      z1[q] = tt ? zb : za; i1[q] = tt ? ib : ia;                             \
      u1[q] = tt ? un[2*q+1] : un[2*q];                                       \
    }                                                                         \
    float z2[5]; int i2[5]; float u2[5];                                      \
    _Pragma("unroll")                                                         \
    for (int q = 0; q < 5; ++q) {                                             \
      bool tt = (z1[2*q+1] > z1[2*q]);                                        \
      z2[q] = tt ? z1[2*q+1] : z1[2*q]; i2[q] = tt ? i1[2*q+1] : i1[2*q];     \
      u2[q] = tt ? u1[2*q+1] : u1[2*q];                                       \
    }                                                                         \
    float bz; int bi; float bu;                                               \
    {                                                                         \
      float zA, zB; int iA, iB; float uA, uB;                                 \
      bool t0 = (z2[1] > z2[0]);                                              \
      zA = t0 ? z2[1] : z2[0]; iA = t0 ? i2[1] : i2[0];                       \
      uA = t0 ? u2[1] : u2[0];                                                \
      bool t1 = (z2[3] > z2[2]);                                              \
      zB = t1 ? z2[3] : z2[2]; iB = t1 ? i2[3] : i2[2];                       \
      uB = t1 ? u2[3] : u2[2];                                                \
      bool t2 = (zB > zA);                                                    \
      zA = t2 ? zB : zA; iA = t2 ? iB : iA; uA = t2 ? uB : uA;                \
      bool t3 = (z2[4] > zA);                                                 \
      bz = t3 ? z2[4] : zA; bi = t3 ? i2[4] : iA; bu = t3 ? u2[4] : uA;       \
    }                                                                         \
    {                                                                         \
      float oz = pl_down32_f(bz); int oi = (int)pl_down32_u((unsigned)bi);    \
      float ou = pl_down32_f(bu);                                             \
      if (oz > bz || (oz == bz && oi < bi)) { bz = oz; bi = oi; bu = ou; }    \
    }                                                                         \
    {                                                                         \
      float oz = pl_down16_f(bz); int oi = (int)pl_down16_u((unsigned)bi);    \
      float ou = pl_down16_f(bu);                                             \
      if (oz > bz || (oz == bz && oi < bi)) { bz = oz; bi = oi; bu = ou; }    \
    }                                                                         \
    {                                                                         \
      float oz = dpp_shl_f<8>(bz); int oi = (int)dpp_shl_u<8>((unsigned)bi);  \
      float ou = dpp_shl_f<8>(bu);                                            \
      if (oz > bz || (oz == bz && oi < bi)) { bz = oz; bi = oi; bu = ou; }    \
    }                                                                         \
    {                                                                         \
      float oz = dpp_shl_f<4>(bz); int oi = (int)dpp_shl_u<4>((unsigned)bi);  \
      float ou = dpp_shl_f<4>(bu);                                            \
      if (oz > bz || (oz == bz && oi < bi)) { bz = oz; bi = oi; bu = ou; }    \
    }                                                                         \
    {                                                                         \
      float oz = dpp_shl_f<2>(bz); int oi = (int)dpp_shl_u<2>((unsigned)bi);  \
      float ou = dpp_shl_f<2>(bu);                                            \
      if (oz > bz || (oz == bz && oi < bi)) { bz = oz; bi = oi; bu = ou; }    \
    }                                                                         \
    {                                                                         \
      float oz = dpp_shl_f<1>(bz); int oi = (int)dpp_shl_u<1>((unsigned)bi);  \
      float ou = dpp_shl_f<1>(bu);                                            \
      if (oz > bz || (oz == bz && oi < bi)) { bz = oz; bi = oi; bu = ou; }    \
    }                                                                         \
    int wpk = bcast0_i(bi);                                                   \
    c_last = (uint32_t)wpk & 0xFFFFu;                                         \
    hist = (hist << 1) | (uint64_t)((c_last >> lane) & 1u);                   \
    if (lane == 0) {                                                          \
      s_cint[step] = (unsigned short)c_last;                                  \
      lp_acc += (double)((bu - wm) - lsum);                                   \
    }                                                                         \
  }

__global__ void __launch_bounds__(64, 1)
mrf_seq_wave(const float* __restrict__ pi, float* __restrict__ out,
             const float* __restrict__ gw,
             const unsigned short* __restrict__ candg) {
#pragma clang fp contract(off)
  const int b    = blockIdx.x;
  const int lane = threadIdx.x;            // 0..63 (one wave)
  const size_t gb = (size_t)b * T_COLS * KC;

  __shared__ float          s_pi[T_COLS];
  __shared__ unsigned short s_cint[T_COLS];
  __shared__ float          s_T[4][16];

  for (int t = lane; t < T_COLS; t += 64) s_pi[t] = pi[t];
  __syncthreads();                          // one wave: cheap full fence

  double lp_acc = 0.0;                      // lane 0 only
  uint32_t c_last = 0;
  uint64_t hist = 0;                        // per-lane winner-bit history
  double p1_d = 0.0, pt_d = 0.0;            // sliding window state (lanes<16)

  // prologue: load step-0 data into A buffers
  float    gA[NCAND], gB[NCAND];
  uint32_t cA[NCAND], cB[NCAND];
#pragma unroll
  for (int i = 0; i < NCAND; ++i) {
    cA[i] = candg[lane + 64 * i];
    gA[i] = gw[gb + lane + 64 * i];
  }

  for (int s2 = 0; s2 < T_COLS; s2 += 2) {
    STEP_BODY(s2,     cA, gA, cB, gB)
    STEP_BODY(s2 + 1, cB, gB, cA, gA)
  }

  __syncthreads();
  // outputs (FP32): c_btls one-hot [B,T,L,S] then log_prob_b [B]
  for (int idx2 = lane; idx2 < T_COLS * 32; idx2 += 64) {
    int t    = idx2 >> 5;
    int rem  = idx2 & 31;
    int l    = rem >> 1;
    int sbit = rem & 1;
    uint32_t code = s_cint[t];
    int bit = (int)((code >> (15 - l)) & 1u);
    out[(size_t)b * 8192 + idx2] = (float)(sbit ? bit : (1 - bit));
  }
  if (lane == 0) {
    out[(size_t)B_ROWS * 8192 + b] = (float)(lp_acc / 256.0);
  }
}

// ---------------- legacy sequential kernel (fallback modes 0/1) -------------
template<int MODE>
__global__ void __launch_bounds__(BLOCK_S)
mrf_seq_kernel(const float* __restrict__ pi, float* __restrict__ out,
               const float* __restrict__ gw,
               const unsigned short* __restrict__ candg) {
#pragma clang fp contract(off)
  const int b    = blockIdx.x;
  const int tid  = threadIdx.x;
  const bool has1 = tid < (KC - BLOCK_S);

  __shared__ float          s_pi[T_COLS];
  __shared__ unsigned short s_cand[KC];
  __shared__ float          s_unnorm[KC];
  __shared__ unsigned short s_cint[T_COLS];
  __shared__ int            s_dC[17][17];
  __shared__ int            s_gw0[17], s_gw1[17], s_gbase[17];
  __shared__ int            s_ngrp;
  __shared__ uint32_t       s_keys[6];
  __shared__ float          s_pw[WWIN];
  __shared__ unsigned short s_wc[WWIN];
  __shared__ float          s_redf[NWAVE_S];
  __shared__ double         s_redd[NWAVE_S];
  __shared__ int            s_redi[NWAVE_S];
  __shared__ float          s_bcast[2];

  for (int t = tid; t < T_COLS; t += BLOCK_S) s_pi[t] = pi[t];
  if (MODE == 0) {
    for (int i = tid; i < 289; i += BLOCK_S) s_dC[i/17][i%17] = dC[i/17][i%17];
  }
  double lp_acc = 0.0;
  __syncthreads();

  for (int step = 0; step < T_COLS; ++step) {
    if (tid == 0) {
      if (MODE == 1) {
        uint32_t ks[2];
        derive_keys(step, nullptr, ks, nullptr);
        s_keys[2] = ks[0]; s_keys[3] = ks[1];
      } else {
        uint32_t ks[2], k2[2];
        derive_keys(step, nullptr, ks, k2);
        s_keys[2] = ks[0]; s_keys[3] = ks[1];
        s_keys[4] = k2[0]; s_keys[5] = k2[1];
        int ws[17], am[17];
        for (int w = 0; w < 17; ++w) {
          int m = 16 * w - 256 + step;
          am[w] = m < 0 ? -m : m;
          ws[w] = w;
        }
        for (int a2 = 1; a2 < 17; ++a2) {
          int wvv = ws[a2], kv = am[wvv];
          int j2 = a2 - 1;
          while (j2 >= 0 && am[ws[j2]] > kv) { ws[j2 + 1] = ws[j2]; --j2; }
          ws[j2 + 1] = wvv;
        }
        int ng = 0, base = 0, idx = 0;
        while (idx < 17) {
          int w0 = ws[idx]; int a0v = am[w0]; int w1 = -1;
          if (idx + 1 < 17 && am[ws[idx + 1]] == a0v) { w1 = ws[idx + 1]; ++idx; }
          ++idx;
          s_gw0[ng] = w0; s_gw1[ng] = w1; s_gbase[ng] = base;
          base += dC[16][w0] + (w1 >= 0 ? dC[16][w1] : 0);
          ++ng;
          if (base >= PTOP) break;
        }
        s_ngrp = ng;
      }
    }
    if (tid < WWIN) {
      int win = step - WWIN + tid;
      s_pw[tid] = (win >= 0) ? s_pi[win] : 0.0f;
      s_wc[tid] = (win >= 0) ? s_cint[win] : (unsigned short)0;
    }
    __syncthreads();

    uint32_t c0, c1 = 0;
    if (MODE >= 1) {
      c0 = candg[step * KC + tid];
      if (has1) c1 = candg[step * KC + BLOCK_S + tid];
    } else {
      {
        int p = tid;
        int g = 0;
        for (int t2 = 1; t2 < s_ngrp; ++t2) if (s_gbase[t2] <= p) g = t2;
        int q  = p - s_gbase[g];
        int r0 = s_gw0[g], r1 = s_gw1[g];
        uint32_t code = 0;
        for (int pos = 15; pos >= 0; --pos) {
          int n0 = ((r0 >= 0 && r0 <= pos) ? s_dC[pos][r0] : 0)
                 + ((r1 >= 0 && r1 <= pos) ? s_dC[pos][r1] : 0);
          if (q >= n0) { q -= n0; code |= (1u << pos); --r0; if (r1 >= 0) --r1; }
        }
        c0 = code;
      }
      if (has1) {
        int t2 = tid;
        uint32_t a0, a1;
#if JAX_PARTITIONABLE
        tf_block(s_keys[4], s_keys[5], 0u, (uint32_t)t2, a0, a1);
        c1 = (a0 ^ a1) & 0xFFFFu;
#else
        if (t2 < 128) { tf_block(s_keys[4], s_keys[5], (uint32_t)t2, (uint32_t)(128 + t2), a0, a1);
                        c1 = a0 & 0xFFFFu; }
        else          { tf_block(s_keys[4], s_keys[5], (uint32_t)(t2 - 128), (uint32_t)t2, a0, a1);
                        c1 = a1 & 0xFFFFu; }
#endif
      }
    }
    s_cand[tid] = (unsigned short)c0;
    if (has1) s_cand[BLOCK_S + tid] = (unsigned short)c1;

    const float pi_i   = s_pi[step];
    const float i_pf   = (float)step;
    const float factor = (step > 0) ? (i_pf / fminf(i_pf, 32.0f)) : 0.0f;

    float un0, un1 = -3.402823466e+38f;
    {
      int w = __popc(c0);
      int m = 16 * w - 256 + step;
      float sq  = (float)(m * m) * 0.00390625f;
      float obk = (pi_i * sq) * 0.0625f;
      float s = 0.0f;
      for (int w2 = 0; w2 < WWIN; ++w2) {
        float ov = (float)(16 - __popc(c0 ^ (uint32_t)s_wc[w2]));
        s = s + s_pw[w2] * ov;
      }
      un0 = -(obk + factor * (pi_i * s));
    }
    if (has1) {
      int w = __popc(c1);
      int m = 16 * w - 256 + step;
      float sq  = (float)(m * m) * 0.00390625f;
      float obk = (pi_i * sq) * 0.0625f;
      float s = 0.0f;
      for (int w2 = 0; w2 < WWIN; ++w2) {
        float ov = (float)(16 - __popc(c1 ^ (uint32_t)s_wc[w2]));
        s = s + s_pw[w2] * ov;
      }
      un1 = -(obk + factor * (pi_i * s));
    }
    s_unnorm[tid] = un0;
    if (has1) s_unnorm[BLOCK_S + tid] = un1;

    float g0v = 0.0f, g1v = 0.0f;
    {
      const uint32_t ks0 = s_keys[2], ks1 = s_keys[3];
      g0v = gumbel_at(ks0, ks1, (uint32_t)(b * KC + tid));
      if (has1) g1v = gumbel_at(ks0, ks1, (uint32_t)(b * KC + BLOCK_S + tid));
    }

    float pmax = has1 ? fmaxf(un0, un1) : un0;
    for (int off = 32; off > 0; off >>= 1) pmax = fmaxf(pmax, __shfl_down(pmax, off));
    if ((tid & 63) == 0) s_redf[tid >> 6] = pmax;
    __syncthreads();
    if (tid == 0) {
      float mm = s_redf[0];
      for (int w2 = 1; w2 < NWAVE_S; ++w2) mm = fmaxf(mm, s_redf[w2]);
      s_bcast[0] = mm;
    }
    __syncthreads();
    const float rmax = s_bcast[0];

    double acc = (double)((float)exp((double)(un0 - rmax)));
    if (has1) acc += (double)((float)exp((double)(un1 - rmax)));
    for (int off = 32; off > 0; off >>= 1) acc += __shfl_down(acc, off);
    if ((tid & 63) == 0) s_redd[tid >> 6] = acc;
    __syncthreads();
    if (tid == 0) {
      double ss = 0.0;
      for (int w2 = 0; w2 < NWAVE_S; ++w2) ss += s_redd[w2];
      float sum_f = (float)ss;
      s_bcast[1] = (float)log((double)sum_f);
    }
    __syncthreads();
    const float lsum = s_bcast[1];

    float bz = ((un0 - rmax) - lsum) + g0v;
    int   bi = tid;
    if (has1) {
      float z1 = ((un1 - rmax) - lsum) + g1v;
      if (z1 > bz) { bz = z1; bi = BLOCK_S + tid; }
    }
    for (int off = 32; off > 0; off >>= 1) {
      float oz = __shfl_down(bz, off);
      int   oi = __shfl_down(bi, off);
      if (oz > bz || (oz == bz && oi < bi)) { bz = oz; bi = oi; }
    }
    if ((tid & 63) == 0) { s_redf[tid >> 6] = bz; s_redi[tid >> 6] = bi; }
    __syncthreads();
    if (tid == 0) {
      float bz2 = s_redf[0]; int bi2 = s_redi[0];
      for (int w2 = 1; w2 < NWAVE_S; ++w2) {
        if (s_redf[w2] > bz2 || (s_redf[w2] == bz2 && s_redi[w2] < bi2)) {
          bz2 = s_redf[w2]; bi2 = s_redi[w2];
        }
      }
      s_cint[step] = s_cand[bi2];
      float lpw = (s_unnorm[bi2] - rmax) - lsum;
      lp_acc += (double)lpw;
    }
    __syncthreads();
  }

  for (int idx2 = tid; idx2 < T_COLS * 32; idx2 += BLOCK_S) {
    int t    = idx2 >> 5;
    int rem  = idx2 & 31;
    int l    = rem >> 1;
    int sbit = rem & 1;
    uint32_t code = s_cint[t];
    int bit = (int)((code >> (15 - l)) & 1u);
    out[(size_t)b * 8192 + idx2] = (float)(sbit ? bit : (1 - bit));
  }
  if (tid == 0) {
    out[(size_t)B_ROWS * 8192 + b] = (float)(lp_acc / 256.0);
  }
}

extern "C" void kernel_launch(void* const* d_in, const int* in_sizes, int n_in,
                              void* d_out, int out_size, void* d_ws, size_t ws_size,
                              hipStream_t stream) {
  const float* pi = (const float*)d_in[0];
  float* out = (float*)d_out;

  const size_t cand_bytes = (size_t)T_COLS * KC * sizeof(unsigned short); // 655,360
  const size_t gw_bytes   = (size_t)B_ROWS * T_COLS * KC * sizeof(float); // 167,772,160

  if (ws_size >= cand_bytes + gw_bytes) {
    unsigned short* candg = (unsigned short*)d_ws;
    float* gw = (float*)((char*)d_ws + cand_bytes);
    gumbel_kernel<<<dim3(T_COLS * B_ROWS), dim3(256), 0, stream>>>(gw);
    cand_kernel<<<dim3(T_COLS), dim3(256), 0, stream>>>(candg);
    mrf_seq_wave<<<dim3(B_ROWS), dim3(64), 0, stream>>>(pi, out, gw, candg);
  } else if (ws_size >= cand_bytes) {
    unsigned short* candg = (unsigned short*)d_ws;
    cand_kernel<<<dim3(T_COLS), dim3(256), 0, stream>>>(candg);
    mrf_seq_kernel<1><<<dim3(B_ROWS), dim3(BLOCK_S), 0, stream>>>(pi, out, nullptr, candg);
  } else {
    mrf_seq_kernel<0><<<dim3(B_ROWS), dim3(BLOCK_S), 0, stream>>>(pi, out, nullptr, nullptr);
  }
}

// Round 8
// 997.804 us; speedup vs baseline: 2.4474x; 1.2877x over previous
//
#include <hip/hip_runtime.h>
#include <stdint.h>
#include <math.h>

// ---------------------------------------------------------------------------
// MRF codebook generator: bit-exact reproduction of the JAX reference.
// Round 21: EXACT byte-for-byte revert to the R14 champion (998.8 us total,
// 701 us sampler). Six rounds of perturbation all regressed:
//   R15 (sched_barrier + t-arrays + readlane-D): 968  — real culprit was
//        the readlane-D bundle (see R20 post-mortem), not the pinning.
//   R16 (global_load_lds staging): 1004 — conservative vmcnt before ds_read.
//   R17 (in-block producer waves): 1010 — lockstep barrier coupling.
//   R18 (cross-XCD ring): 2439 — per-step coherence writebacks (170 MB).
//   R19 (dispatch-order cohorts): 2210 — producer co-residency + acquire
//        polls starve the serial wave.
//   R20 (readlane-D + hist + earg alone): 991 — +37% VALU-busy cycles.
// The R14 schedule (register demand-prefetch at body top, __shfl T-build,
// s_cint window read, DPP/permlane reduction trees) is a sharp local
// optimum: one resident wave pays full dep-latency on every serial op, and
// every attempted "improvement" lengthened the chain or injected stalls.
// ---------------------------------------------------------------------------

#define JAX_PARTITIONABLE 1

#define T_COLS 256
#define B_ROWS 128
#define KC     1280
#define PTOP   1024
#define RRAND  256
#define WWIN   32
#define NCAND  20            // KC / 64
#define BLOCK_S 1024         // legacy fallback block
#define NWAVE_S (BLOCK_S / 64)

__device__ __constant__ int dC[17][17] = {
  {1},
  {1,1},
  {1,2,1},
  {1,3,3,1},
  {1,4,6,4,1},
  {1,5,10,10,5,1},
  {1,6,15,20,15,6,1},
  {1,7,21,35,35,21,7,1},
  {1,8,28,56,70,56,28,8,1},
  {1,9,36,84,126,126,84,36,9,1},
  {1,10,45,120,210,252,210,120,45,10,1},
  {1,11,55,165,330,462,462,330,165,55,11,1},
  {1,12,66,220,495,792,924,792,495,220,66,12,1},
  {1,13,78,286,715,1287,1716,1716,1287,715,286,78,13,1},
  {1,14,91,364,1001,2002,3003,3432,3003,2002,1001,364,91,14,1},
  {1,15,105,455,1365,3003,5005,6435,6435,5005,3003,1365,455,105,15,1},
  {1,16,120,560,1820,4368,8008,11440,12870,11440,8008,4368,1820,560,120,16,1}
};

// Threefry-2x32, 20 rounds, JAX key schedule.
__device__ __forceinline__ void tf_block(uint32_t k0, uint32_t k1,
                                         uint32_t x0, uint32_t x1,
                                         uint32_t& o0, uint32_t& o1) {
  uint32_t ks2 = k0 ^ k1 ^ 0x1BD11BDAu;
  x0 += k0; x1 += k1;
#define TFR(r) { x0 += x1; x1 = (x1 << (r)) | (x1 >> (32 - (r))); x1 ^= x0; }
  TFR(13) TFR(15) TFR(26) TFR(6)   x0 += k1;  x1 += ks2 + 1u;
  TFR(17) TFR(29) TFR(16) TFR(24)  x0 += ks2; x1 += k0 + 2u;
  TFR(13) TFR(15) TFR(26) TFR(6)   x0 += k0;  x1 += k1 + 3u;
  TFR(17) TFR(29) TFR(16) TFR(24)  x0 += k1;  x1 += ks2 + 4u;
  TFR(13) TFR(15) TFR(26) TFR(6)   x0 += ks2; x1 += k0 + 5u;
#undef TFR
  o0 = x0; o1 = x1;
}

// fold_in(key(42), step) -> k_rand/k_samp/randint-k2 per PRNG mode.
__device__ __forceinline__ void derive_keys(int step,
                                            uint32_t* krand, uint32_t* ksamp,
                                            uint32_t* k2) {
  uint32_t y0, y1;
  tf_block(0u, 42u, 0u, (uint32_t)step, y0, y1);
  uint32_t kr0 = y0, kr1 = y1;
#if JAX_PARTITIONABLE
  uint32_t r0, r1;
  tf_block(kr0, kr1, 0u, 0u, r0, r1);            // k_rand
  if (krand) { krand[0] = r0; krand[1] = r1; }
  if (ksamp) { tf_block(kr0, kr1, 0u, 1u, y0, y1); ksamp[0] = y0; ksamp[1] = y1; }
  if (k2)    { tf_block(r0, r1, 0u, 1u, y0, y1);  k2[0] = y0;  k2[1] = y1; }
#else
  uint32_t a0,a1,b0,b1;
  tf_block(kr0, kr1, 0u, 2u, a0, a1);
  tf_block(kr0, kr1, 1u, 3u, b0, b1);
  if (krand) { krand[0] = a0; krand[1] = b0; }
  if (ksamp) { ksamp[0] = a1; ksamp[1] = b1; }
  if (k2) {
    uint32_t c0,c1,d0,d1;
    tf_block(a0, b0, 0u, 2u, c0, c1);
    tf_block(a0, b0, 1u, 3u, d0, d1);
    k2[0] = c1; k2[1] = d1;
  }
#endif
}

// JAX uniform(tiny,1) -> gumbel, fp32 logs correctly-rounded-from-double.
__device__ __forceinline__ float gumbel_from_bits(uint32_t bits) {
  uint32_t fb = (bits >> 9) | 0x3f800000u;
  float f = __uint_as_float(fb) - 1.0f;
  float u = (f == 0.0f) ? 1.17549435e-38f : f;
  float l1 = (float)log((double)u);
  float l2 = (float)log((double)(-l1));
  return -l2;
}

__device__ __forceinline__ float gumbel_at(uint32_t ks0, uint32_t ks1, uint32_t j) {
  uint32_t g0, g1;
#if JAX_PARTITIONABLE
  tf_block(ks0, ks1, 0u, j, g0, g1);
  return gumbel_from_bits(g0 ^ g1);
#else
  uint32_t half = (uint32_t)(B_ROWS * KC / 2);
  if (j < half) { tf_block(ks0, ks1, j, j + half, g0, g1);  return gumbel_from_bits(g0); }
  else          { tf_block(ks0, ks1, j - half, j, g0, g1);  return gumbel_from_bits(g1); }
#endif
}

// ---------------- precompute kernel G: gumbel[b][step][k] -------------------
__global__ void __launch_bounds__(256)
gumbel_kernel(float* __restrict__ gw) {
  const int bb   = blockIdx.x & (B_ROWS - 1);
  const int step = blockIdx.x >> 7;
  const int tid  = threadIdx.x;
  __shared__ uint32_t s_ks[2];
  if (tid == 0) {
    uint32_t ks[2];
    derive_keys(step, nullptr, ks, nullptr);
    s_ks[0] = ks[0]; s_ks[1] = ks[1];
  }
  __syncthreads();
  const uint32_t ks0 = s_ks[0], ks1 = s_ks[1];
  const size_t base = ((size_t)bb * T_COLS + step) * KC;
#pragma unroll
  for (int i = 0; i < 5; ++i) {
    int k = tid + 256 * i;
    uint32_t j = (uint32_t)(bb * KC + k);
    gw[base + k] = gumbel_at(ks0, ks1, j);
  }
}

// ---------------- precompute kernel C: cand[step][k] ------------------------
__global__ void __launch_bounds__(256)
cand_kernel(unsigned short* __restrict__ candg) {
  const int step = blockIdx.x;
  const int tid  = threadIdx.x;
  __shared__ int s_dC[17][17];
  __shared__ int s_gw0[17], s_gw1[17], s_gbase[17];
  __shared__ int s_ngrp;
  __shared__ uint32_t s_k2[2];
  for (int i = tid; i < 289; i += 256) s_dC[i/17][i%17] = dC[i/17][i%17];
  if (tid == 0) {
    uint32_t k2[2];
    derive_keys(step, nullptr, nullptr, k2);
    s_k2[0] = k2[0]; s_k2[1] = k2[1];
    int ws[17], am[17];
    for (int w = 0; w < 17; ++w) {
      int m = 16 * w - 256 + step;
      am[w] = m < 0 ? -m : m;
      ws[w] = w;
    }
    for (int a2 = 1; a2 < 17; ++a2) {
      int wv = ws[a2], kv = am[wv];
      int j2 = a2 - 1;
      while (j2 >= 0 && am[ws[j2]] > kv) { ws[j2 + 1] = ws[j2]; --j2; }
      ws[j2 + 1] = wv;
    }
    int ng = 0, base = 0, idx = 0;
    while (idx < 17) {
      int w0 = ws[idx]; int a0v = am[w0]; int w1 = -1;
      if (idx + 1 < 17 && am[ws[idx + 1]] == a0v) { w1 = ws[idx + 1]; ++idx; }
      ++idx;
      s_gw0[ng] = w0; s_gw1[ng] = w1; s_gbase[ng] = base;
      base += dC[16][w0] + (w1 >= 0 ? dC[16][w1] : 0);
      ++ng;
      if (base >= PTOP) break;
    }
    s_ngrp = ng;
  }
  __syncthreads();
  for (int p = tid; p < PTOP; p += 256) {
    int g = 0;
    for (int t2 = 1; t2 < s_ngrp; ++t2) if (s_gbase[t2] <= p) g = t2;
    int q  = p - s_gbase[g];
    int r0 = s_gw0[g], r1 = s_gw1[g];
    uint32_t code = 0;
    for (int pos = 15; pos >= 0; --pos) {
      int n0 = ((r0 >= 0 && r0 <= pos) ? s_dC[pos][r0] : 0)
             + ((r1 >= 0 && r1 <= pos) ? s_dC[pos][r1] : 0);
      if (q >= n0) { q -= n0; code |= (1u << pos); --r0; if (r1 >= 0) --r1; }
    }
    candg[step * KC + p] = (unsigned short)code;
  }
  {
    int t2 = tid;
    uint32_t a0, a1;
#if JAX_PARTITIONABLE
    tf_block(s_k2[0], s_k2[1], 0u, (uint32_t)t2, a0, a1);
    candg[step * KC + PTOP + t2] = (unsigned short)((a0 ^ a1) & 0xFFFFu);
#else
    if (t2 < 128) { tf_block(s_k2[0], s_k2[1], (uint32_t)t2, (uint32_t)(128 + t2), a0, a1);
                    candg[step * KC + PTOP + t2] = (unsigned short)(a0 & 0xFFFFu); }
    else          { tf_block(s_k2[0], s_k2[1], (uint32_t)(t2 - 128), (uint32_t)t2, a0, a1);
                    candg[step * KC + PTOP + t2] = (unsigned short)(a1 & 0xFFFFu); }
#endif
  }
}

// ---------------- VALU-pipe cross-lane primitives ---------------------------
// Replacements for __shfl_down(x, off) that deliver the SAME source value to
// every lane on the lane-0 reduction lineage, but run on the VALU pipe
// (~4-8 cy dep latency) instead of LDS ds_bpermute/ds_swizzle (~120 cy).

// offset 32: v_permlane32_swap_b32 vdst,vsrc swaps vdst.row1 (lanes 32-63)
// with vsrc.row0 (lanes 0-31). With both operands = x, the vsrc result is
// [x.hi32, x.hi32]: lanes 0-31 receive lane i+32.  (Aliased-register case
// degenerates to a full swap, which still yields lane i+32 in lanes 0-31.)
__device__ __forceinline__ unsigned pl_down32_u(unsigned x) {
  unsigned d = x, s = x;
  asm volatile("s_nop 1\n\tv_permlane32_swap_b32 %0, %1" : "+v"(d), "+v"(s));
  return s;
}
// offset 16: v_permlane16_swap_b32 swaps vdst odd 16-rows with vsrc even
// 16-rows -> vsrc result rows = [x.r1, x.r1, x.r3, x.r3]: lanes 0-15 get
// lane i+16 (and lanes 32-47 get i+16, unused-but-consistent).
__device__ __forceinline__ unsigned pl_down16_u(unsigned x) {
  unsigned d = x, s = x;
  asm volatile("s_nop 1\n\tv_permlane16_swap_b32 %0, %1" : "+v"(d), "+v"(s));
  return s;
}
// offsets 8/4/2/1: DPP row_shl:N -> lane n receives lane n+N within its
// 16-lane row (rocPRIM scan convention: row_shr:N = lane n-N, so row_shl:N
// = lane n+N). bound_ctrl: out-of-row sources read 0 (only lanes outside
// the lane-0 lineage, never consumed).
template<int N>
__device__ __forceinline__ unsigned dpp_shl_u(unsigned x) {
  return (unsigned)__builtin_amdgcn_update_dpp(0, (int)x, 0x100 | N, 0xF, 0xF, true);
}
__device__ __forceinline__ float pl_down32_f(float x) {
  return __uint_as_float(pl_down32_u(__float_as_uint(x)));
}
__device__ __forceinline__ float pl_down16_f(float x) {
  return __uint_as_float(pl_down16_u(__float_as_uint(x)));
}
template<int N>
__device__ __forceinline__ float dpp_shl_f(float x) {
  return __uint_as_float(dpp_shl_u<N>(__float_as_uint(x)));
}
__device__ __forceinline__ double pl_down32_d(double x) {
  unsigned lo = pl_down32_u((unsigned)__double2loint(x));
  unsigned hi = pl_down32_u((unsigned)__double2hiint(x));
  return __hiloint2double((int)hi, (int)lo);
}
__device__ __forceinline__ double pl_down16_d(double x) {
  unsigned lo = pl_down16_u((unsigned)__double2loint(x));
  unsigned hi = pl_down16_u((unsigned)__double2hiint(x));
  return __hiloint2double((int)hi, (int)lo);
}
template<int N>
__device__ __forceinline__ double dpp_shl_d(double x) {
  unsigned lo = dpp_shl_u<N>((unsigned)__double2loint(x));
  unsigned hi = dpp_shl_u<N>((unsigned)__double2hiint(x));
  return __hiloint2double((int)hi, (int)lo);
}
// lane-0 broadcast (all lanes active at every call site) -> readfirstlane.
__device__ __forceinline__ float bcast0_f(float x) {
  return __uint_as_float((unsigned)__builtin_amdgcn_readfirstlane((int)__float_as_uint(x)));
}
__device__ __forceinline__ int bcast0_i(int x) {
  return __builtin_amdgcn_readfirstlane(x);
}
__device__ __forceinline__ double bcast0_d(double x) {
  int lo = __builtin_amdgcn_readfirstlane(__double2loint(x));
  int hi = __builtin_amdgcn_readfirstlane(__double2hiint(x));
  return __hiloint2double(hi, lo);
}

// ---------------- one-wave sequential kernel (MODE 2) -----------------------
// Step body macro: CC/GG = current-step cand/gumbel regs, CN/GN = prefetch
// target regs for step S+1. All loop indices are unroll-constant.
#define STEP_BODY(S, CC, GG, CN, GN)                                          \
  {                                                                           \
    const int step = (S);                                                     \
    /* prefetch step+1 (full step of slack) */                                \
    const int sn = (step + 1 < T_COLS) ? step + 1 : step;                     \
    _Pragma("unroll")                                                         \
    for (int i = 0; i < NCAND; ++i) {                                         \
      CN[i] = candg[sn * KC + lane + 64 * i];                                 \
      GN[i] = gw[gb + (size_t)sn * KC + lane + 64 * i];                       \
    }                                                                         \
    /* slide window state (lanes 0-15 hold per-bit f64 state) */              \
    if (lane < 16) {                                                          \
      if (step > 0) {                                                         \
        double pw = (double)s_pi[step - 1];                                   \
        if ((c_last >> lane) & 1u) p1_d += pw;                                \
        pt_d += pw;                                                           \
      }                                                                       \
      if (step >= 33) {                                                       \
        double pw = (double)s_pi[step - 33];                                  \
        if (((uint32_t)s_cint[step - 33] >> lane) & 1u) p1_d -= pw;           \
        pt_d -= pw;                                                           \
      }                                                                       \
    }                                                                         \
    float Dl = (float)(pt_d - (p1_d + p1_d));                                 \
    /* S0: 16-lane f64 xor-butterfly; on lane-0's lineage xor==+offset at    \
       every level, so row_shl 1,2,4,8 reproduces it bit-exactly. */          \
    double s0d = p1_d;                                                        \
    s0d += dpp_shl_d<1>(s0d);                                                 \
    s0d += dpp_shl_d<2>(s0d);                                                 \
    s0d += dpp_shl_d<4>(s0d);                                                 \
    s0d += dpp_shl_d<8>(s0d);                                                 \
    const float S0f  = bcast0_f((float)s0d);                                  \
    const float Pt16 = bcast0_f((float)(16.0 * pt_d));                        \
    {                                                                         \
      int n = lane >> 4, v = lane & 15;                                       \
      float d0 = __shfl(Dl, 4 * n + 0);                                       \
      float d1 = __shfl(Dl, 4 * n + 1);                                       \
      float d2 = __shfl(Dl, 4 * n + 2);                                       \
      float d3 = __shfl(Dl, 4 * n + 3);                                       \
      float t = 0.0f;                                                         \
      if (v & 1) t += d0;                                                     \
      if (v & 2) t += d1;                                                     \
      if (v & 4) t += d2;                                                     \
      if (v & 8) t += d3;                                                     \
      s_T[n][v] = t;                                                          \
    }                                                                         \
    __builtin_amdgcn_wave_barrier();                                          \
    const float pi_i   = s_pi[step];                                          \
    const float i_pf   = (float)step;                                         \
    const float factor = (step > 0) ? (i_pf / fminf(i_pf, 32.0f)) : 0.0f;     \
    float un[NCAND];                                                          \
    _Pragma("unroll")                                                         \
    for (int i = 0; i < NCAND; ++i) {                                         \
      uint32_t c = CC[i];                                                     \
      float sc = S0f + s_T[0][c & 15];                                        \
      sc += s_T[1][(c >> 4) & 15];                                            \
      sc += s_T[2][(c >> 8) & 15];                                            \
      sc += s_T[3][(c >> 12) & 15];                                           \
      float sv = Pt16 - sc;                                                   \
      int w = __popc(c);                                                      \
      int m = 16 * w - 256 + step;                                            \
      float sq  = (float)(m * m) * 0.00390625f;                               \
      float obk = (pi_i * sq) * 0.0625f;                                      \
      un[i] = -(obk + factor * (pi_i * sv));                                  \
    }                                                                         \
    /* rmax: exact global max (fmax associative-exact; hand tree + DPP) */    \
    float wt10[10];                                                           \
    _Pragma("unroll")                                                         \
    for (int q = 0; q < 10; ++q) wt10[q] = fmaxf(un[2*q], un[2*q+1]);         \
    float wt5[5];                                                             \
    _Pragma("unroll")                                                         \
    for (int q = 0; q < 5; ++q) wt5[q] = fmaxf(wt10[2*q], wt10[2*q+1]);       \
    float wm = fmaxf(fmaxf(fmaxf(wt5[0], wt5[1]), fmaxf(wt5[2], wt5[3])),     \
                     wt5[4]);                                                 \
    wm = fmaxf(wm, pl_down32_f(wm));                                          \
    wm = fmaxf(wm, pl_down16_f(wm));                                          \
    wm = fmaxf(wm, dpp_shl_f<8>(wm));                                         \
    wm = fmaxf(wm, dpp_shl_f<4>(wm));                                         \
    wm = fmaxf(wm, dpp_shl_f<2>(wm));                                         \
    wm = fmaxf(wm, dpp_shl_f<1>(wm));                                         \
    wm = bcast0_f(wm);                                                        \
    /* lsum: f64-accumulated fp32 exp terms (common-mode class); same        \
       shfl_down-shaped f64 tree, moved to VALU pipe. */                      \
    double a0 = 0.0, a1 = 0.0;                                                \
    _Pragma("unroll")                                                         \
    for (int i = 0; i < NCAND; ++i) {                                         \
      float e = expf(un[i] - wm);                                             \
      if (i & 1) a1 += (double)e; else a0 += (double)e;                       \
    }                                                                         \
    double sw = a0 + a1;                                                      \
    sw += pl_down32_d(sw);                                                    \
    sw += pl_down16_d(sw);                                                    \
    sw += dpp_shl_d<8>(sw);                                                   \
    sw += dpp_shl_d<4>(sw);                                                   \
    sw += dpp_shl_d<2>(sw);                                                   \
    sw += dpp_shl_d<1>(sw);                                                   \
    const float lsum = logf((float)bcast0_d(sw));                             \
    /* exact z argmax, lowest-k ties: per-lane adjacent-range tree (left     \
       wins ties => lowest slot, identical to the linear scan), then the     \
       same 6-level cross-lane tree with explicit (z, index) tie-break. */    \
    float z1[10]; int i1[10]; float u1[10];                                   \
    _Pragma("unroll")                                                         \
    for (int q = 0; q < 10; ++q) {                                            \
      float za = ((un[2*q]   - wm) - lsum) + GG[2*q];                         \
      float zb = ((un[2*q+1] - wm) - lsum) + GG[2*q+1];                       \
      int ia = (((64*(2*q)   + lane) << 16) | (int)CC[2*q]);                  \
      int ib = (((64*(2*q+1) + lane) << 16) | (int)CC[2*q+1]);                \
      bool tt = (zb > za);                                                    \
      z1[q] = tt ? zb : za; i1[q] = tt ? ib : ia;                             \
      u1[q] = tt ? un[2*q+1] : un[2*q];                                       \
    }                                                                         \
    float z2[5]; int i2[5]; float u2[5];                                      \
    _Pragma("unroll")                                                         \
    for (int q = 0; q < 5; ++q) {                                             \
      bool tt = (z1[2*q+1] > z1[2*q]);                                        \
      z2[q] = tt ? z1[2*q+1] : z1[2*q]; i2[q] = tt ? i1[2*q+1] : i1[2*q];     \
      u2[q] = tt ? u1[2*q+1] : u1[2*q];                                       \
    }                                                                         \
    float bz; int bi; float bu;                                               \
    {                                                                         \
      float zA, zB; int iA, iB; float uA, uB;                                 \
      bool t0 = (z2[1] > z2[0]);                                              \
      zA = t0 ? z2[1] : z2[0]; iA = t0 ? i2[1] : i2[0];                       \
      uA = t0 ? u2[1] : u2[0];                                                \
      bool t1 = (z2[3] > z2[2]);                                              \
      zB = t1 ? z2[3] : z2[2]; iB = t1 ? i2[3] : i2[2];                       \
      uB = t1 ? u2[3] : u2[2];                                                \
      bool t2 = (zB > zA);                                                    \
      zA = t2 ? zB : zA; iA = t2 ? iB : iA; uA = t2 ? uB : uA;                \
      bool t3 = (z2[4] > zA);                                                 \
      bz = t3 ? z2[4] : zA; bi = t3 ? i2[4] : iA; bu = t3 ? u2[4] : uA;       \
    }                                                                         \
    {                                                                         \
      float oz = pl_down32_f(bz); int oi = (int)pl_down32_u((unsigned)bi);    \
      float ou = pl_down32_f(bu);                                             \
      if (oz > bz || (oz == bz && oi < bi)) { bz = oz; bi = oi; bu = ou; }    \
    }                                                                         \
    {                                                                         \
      float oz = pl_down16_f(bz); int oi = (int)pl_down16_u((unsigned)bi);    \
      float ou = pl_down16_f(bu);                                             \
      if (oz > bz || (oz == bz && oi < bi)) { bz = oz; bi = oi; bu = ou; }    \
    }                                                                         \
    {                                                                         \
      float oz = dpp_shl_f<8>(bz); int oi = (int)dpp_shl_u<8>((unsigned)bi);  \
      float ou = dpp_shl_f<8>(bu);                                            \
      if (oz > bz || (oz == bz && oi < bi)) { bz = oz; bi = oi; bu = ou; }    \
    }                                                                         \
    {                                                                         \
      float oz = dpp_shl_f<4>(bz); int oi = (int)dpp_shl_u<4>((unsigned)bi);  \
      float ou = dpp_shl_f<4>(bu);                                            \
      if (oz > bz || (oz == bz && oi < bi)) { bz = oz; bi = oi; bu = ou; }    \
    }                                                                         \
    {                                                                         \
      float oz = dpp_shl_f<2>(bz); int oi = (int)dpp_shl_u<2>((unsigned)bi);  \
      float ou = dpp_shl_f<2>(bu);                                            \
      if (oz > bz || (oz == bz && oi < bi)) { bz = oz; bi = oi; bu = ou; }    \
    }                                                                         \
    {                                                                         \
      float oz = dpp_shl_f<1>(bz); int oi = (int)dpp_shl_u<1>((unsigned)bi);  \
      float ou = dpp_shl_f<1>(bu);                                             \
      if (oz > bz || (oz == bz && oi < bi)) { bz = oz; bi = oi; bu = ou; }    \
    }                                                                         \
    int wpk = bcast0_i(bi);                                                   \
    c_last = (uint32_t)wpk & 0xFFFFu;                                         \
    if (lane == 0) {                                                          \
      s_cint[step] = (unsigned short)c_last;                                  \
      lp_acc += (double)((bu - wm) - lsum);                                   \
    }                                                                         \
  }

__global__ void __launch_bounds__(64, 1)
mrf_seq_wave(const float* __restrict__ pi, float* __restrict__ out,
             const float* __restrict__ gw,
             const unsigned short* __restrict__ candg) {
#pragma clang fp contract(off)
  const int b    = blockIdx.x;
  const int lane = threadIdx.x;            // 0..63 (one wave)
  const size_t gb = (size_t)b * T_COLS * KC;

  __shared__ float          s_pi[T_COLS];
  __shared__ unsigned short s_cint[T_COLS];
  __shared__ float          s_T[4][16];

  for (int t = lane; t < T_COLS; t += 64) s_pi[t] = pi[t];
  __syncthreads();                          // one wave: cheap full fence

  double lp_acc = 0.0;                      // lane 0 only
  uint32_t c_last = 0;
  double p1_d = 0.0, pt_d = 0.0;            // sliding window state (lanes<16)

  // prologue: load step-0 data into A buffers
  float    gA[NCAND], gB[NCAND];
  uint32_t cA[NCAND], cB[NCAND];
#pragma unroll
  for (int i = 0; i < NCAND; ++i) {
    cA[i] = candg[lane + 64 * i];
    gA[i] = gw[gb + lane + 64 * i];
  }

  for (int s2 = 0; s2 < T_COLS; s2 += 2) {
    STEP_BODY(s2,     cA, gA, cB, gB)
    STEP_BODY(s2 + 1, cB, gB, cA, gA)
  }

  __syncthreads();
  // outputs (FP32): c_btls one-hot [B,T,L,S] then log_prob_b [B]
  for (int idx2 = lane; idx2 < T_COLS * 32; idx2 += 64) {
    int t    = idx2 >> 5;
    int rem  = idx2 & 31;
    int l    = rem >> 1;
    int sbit = rem & 1;
    uint32_t code = s_cint[t];
    int bit = (int)((code >> (15 - l)) & 1u);
    out[(size_t)b * 8192 + idx2] = (float)(sbit ? bit : (1 - bit));
  }
  if (lane == 0) {
    out[(size_t)B_ROWS * 8192 + b] = (float)(lp_acc / 256.0);
  }
}

// ---------------- legacy sequential kernel (fallback modes 0/1) -------------
template<int MODE>
__global__ void __launch_bounds__(BLOCK_S)
mrf_seq_kernel(const float* __restrict__ pi, float* __restrict__ out,
               const float* __restrict__ gw,
               const unsigned short* __restrict__ candg) {
#pragma clang fp contract(off)
  const int b    = blockIdx.x;
  const int tid  = threadIdx.x;
  const bool has1 = tid < (KC - BLOCK_S);

  __shared__ float          s_pi[T_COLS];
  __shared__ unsigned short s_cand[KC];
  __shared__ float          s_unnorm[KC];
  __shared__ unsigned short s_cint[T_COLS];
  __shared__ int            s_dC[17][17];
  __shared__ int            s_gw0[17], s_gw1[17], s_gbase[17];
  __shared__ int            s_ngrp;
  __shared__ uint32_t       s_keys[6];
  __shared__ float          s_pw[WWIN];
  __shared__ unsigned short s_wc[WWIN];
  __shared__ float          s_redf[NWAVE_S];
  __shared__ double         s_redd[NWAVE_S];
  __shared__ int            s_redi[NWAVE_S];
  __shared__ float          s_bcast[2];

  for (int t = tid; t < T_COLS; t += BLOCK_S) s_pi[t] = pi[t];
  if (MODE == 0) {
    for (int i = tid; i < 289; i += BLOCK_S) s_dC[i/17][i%17] = dC[i/17][i%17];
  }
  double lp_acc = 0.0;
  __syncthreads();

  for (int step = 0; step < T_COLS; ++step) {
    if (MODE <= 1 && tid == 0) {
      if (MODE == 1) {
        uint32_t ks[2];
        derive_keys(step, nullptr, ks, nullptr);
        s_keys[2] = ks[0]; s_keys[3] = ks[1];
      } else {
        uint32_t ks[2], k2[2];
        derive_keys(step, nullptr, ks, k2);
        s_keys[2] = ks[0]; s_keys[3] = ks[1];
        s_keys[4] = k2[0]; s_keys[5] = k2[1];
        int ws[17], am[17];
        for (int w = 0; w < 17; ++w) {
          int m = 16 * w - 256 + step;
          am[w] = m < 0 ? -m : m;
          ws[w] = w;
        }
        for (int a2 = 1; a2 < 17; ++a2) {
          int wvv = ws[a2], kv = am[wvv];
          int j2 = a2 - 1;
          while (j2 >= 0 && am[ws[j2]] > kv) { ws[j2 + 1] = ws[j2]; --j2; }
          ws[j2 + 1] = wvv;
        }
        int ng = 0, base = 0, idx = 0;
        while (idx < 17) {
          int w0 = ws[idx]; int a0v = am[w0]; int w1 = -1;
          if (idx + 1 < 17 && am[ws[idx + 1]] == a0v) { w1 = ws[idx + 1]; ++idx; }
          ++idx;
          s_gw0[ng] = w0; s_gw1[ng] = w1; s_gbase[ng] = base;
          base += dC[16][w0] + (w1 >= 0 ? dC[16][w1] : 0);
          ++ng;
          if (base >= PTOP) break;
        }
        s_ngrp = ng;
      }
    }
    if (tid < WWIN) {
      int win = step - WWIN + tid;
      s_pw[tid] = (win >= 0) ? s_pi[win] : 0.0f;
      s_wc[tid] = (win >= 0) ? s_cint[win] : (unsigned short)0;
    }
    __syncthreads();

    uint32_t c0, c1 = 0;
    if (MODE >= 1) {
      c0 = candg[step * KC + tid];
      if (has1) c1 = candg[step * KC + BLOCK_S + tid];
    } else {
      {
        int p = tid;
        int g = 0;
        for (int t2 = 1; t2 < s_ngrp; ++t2) if (s_gbase[t2] <= p) g = t2;
        int q  = p - s_gbase[g];
        int r0 = s_gw0[g], r1 = s_gw1[g];
        uint32_t code = 0;
        for (int pos = 15; pos >= 0; --pos) {
          int n0 = ((r0 >= 0 && r0 <= pos) ? s_dC[pos][r0] : 0)
                 + ((r1 >= 0 && r1 <= pos) ? s_dC[pos][r1] : 0);
          if (q >= n0) { q -= n0; code |= (1u << pos); --r0; if (r1 >= 0) --r1; }
        }
        c0 = code;
      }
      if (has1) {
        int t2 = tid;
        uint32_t a0, a1;
#if JAX_PARTITIONABLE
        tf_block(s_keys[4], s_keys[5], 0u, (uint32_t)t2, a0, a1);
        c1 = (a0 ^ a1) & 0xFFFFu;
#else
        if (t2 < 128) { tf_block(s_keys[4], s_keys[5], (uint32_t)t2, (uint32_t)(128 + t2), a0, a1);
                        c1 = a0 & 0xFFFFu; }
        else          { tf_block(s_keys[4], s_keys[5], (uint32_t)(t2 - 128), (uint32_t)t2, a0, a1);
                        c1 = a1 & 0xFFFFu; }
#endif
      }
    }
    s_cand[tid] = (unsigned short)c0;
    if (has1) s_cand[BLOCK_S + tid] = (unsigned short)c1;

    const float pi_i   = s_pi[step];
    const float i_pf   = (float)step;
    const float factor = (step > 0) ? (i_pf / fminf(i_pf, 32.0f)) : 0.0f;

    float un0, un1 = -3.402823466e+38f;
    {
      int w = __popc(c0);
      int m = 16 * w - 256 + step;
      float sq  = (float)(m * m) * 0.00390625f;
      float obk = (pi_i * sq) * 0.0625f;
      float s = 0.0f;
      for (int w2 = 0; w2 < WWIN; ++w2) {
        float ov = (float)(16 - __popc(c0 ^ (uint32_t)s_wc[w2]));
        s = s + s_pw[w2] * ov;
      }
      un0 = -(obk + factor * (pi_i * s));
    }
    if (has1) {
      int w = __popc(c1);
      int m = 16 * w - 256 + step;
      float sq  = (float)(m * m) * 0.00390625f;
      float obk = (pi_i * sq) * 0.0625f;
      float s = 0.0f;
      for (int w2 = 0; w2 < WWIN; ++w2) {
        float ov = (float)(16 - __popc(c1 ^ (uint32_t)s_wc[w2]));
        s = s + s_pw[w2] * ov;
      }
      un1 = -(obk + factor * (pi_i * s));
    }
    s_unnorm[tid] = un0;
    if (has1) s_unnorm[BLOCK_S + tid] = un1;

    float g0v = 0.0f, g1v = 0.0f;
    if (MODE == 2) {
      const size_t gbase = ((size_t)b * T_COLS + step) * KC;
      g0v = gw[gbase + tid];
      if (has1) g1v = gw[gbase + BLOCK_S + tid];
    } else {
      const uint32_t ks0 = s_keys[2], ks1 = s_keys[3];
      g0v = gumbel_at(ks0, ks1, (uint32_t)(b * KC + tid));
      if (has1) g1v = gumbel_at(ks0, ks1, (uint32_t)(b * KC + BLOCK_S + tid));
    }

    float pmax = has1 ? fmaxf(un0, un1) : un0;
    for (int off = 32; off > 0; off >>= 1) pmax = fmaxf(pmax, __shfl_down(pmax, off));
    if ((tid & 63) == 0) s_redf[tid >> 6] = pmax;
    __syncthreads();
    if (tid == 0) {
      float mm = s_redf[0];
      for (int w2 = 1; w2 < NWAVE_S; ++w2) mm = fmaxf(mm, s_redf[w2]);
      s_bcast[0] = mm;
    }
    __syncthreads();
    const float rmax = s_bcast[0];

    double acc = (double)((float)exp((double)(un0 - rmax)));
    if (has1) acc += (double)((float)exp((double)(un1 - rmax)));
    for (int off = 32; off > 0; off >>= 1) acc += __shfl_down(acc, off);
    if ((tid & 63) == 0) s_redd[tid >> 6] = acc;
    __syncthreads();
    if (tid == 0) {
      double ss = 0.0;
      for (int w2 = 0; w2 < NWAVE_S; ++w2) ss += s_redd[w2];
      float sum_f = (float)ss;
      s_bcast[1] = (float)log((double)sum_f);
    }
    __syncthreads();
    const float lsum = s_bcast[1];

    float bz = ((un0 - rmax) - lsum) + g0v;
    int   bi = tid;
    if (has1) {
      float z1 = ((un1 - rmax) - lsum) + g1v;
      if (z1 > bz) { bz = z1; bi = BLOCK_S + tid; }
    }
    for (int off = 32; off > 0; off >>= 1) {
      float oz = __shfl_down(bz, off);
      int   oi = __shfl_down(bi, off);
      if (oz > bz || (oz == bz && oi < bi)) { bz = oz; bi = oi; }
    }
    if ((tid & 63) == 0) { s_redf[tid >> 6] = bz; s_redi[tid >> 6] = bi; }
    __syncthreads();
    if (tid == 0) {
      float bz2 = s_redf[0]; int bi2 = s_redi[0];
      for (int w2 = 1; w2 < NWAVE_S; ++w2) {
        if (s_redf[w2] > bz2 || (s_redf[w2] == bz2 && s_redi[w2] < bi2)) {
          bz2 = s_redf[w2]; bi2 = s_redi[w2];
        }
      }
      s_cint[step] = s_cand[bi2];
      float lpw = (s_unnorm[bi2] - rmax) - lsum;
      lp_acc += (double)lpw;
    }
    __syncthreads();
  }

  for (int idx2 = tid; idx2 < T_COLS * 32; idx2 += BLOCK_S) {
    int t    = idx2 >> 5;
    int rem  = idx2 & 31;
    int l    = rem >> 1;
    int sbit = rem & 1;
    uint32_t code = s_cint[t];
    int bit = (int)((code >> (15 - l)) & 1u);
    out[(size_t)b * 8192 + idx2] = (float)(sbit ? bit : (1 - bit));
  }
  if (tid == 0) {
    out[(size_t)B_ROWS * 8192 + b] = (float)(lp_acc / 256.0);
  }
}

extern "C" void kernel_launch(void* const* d_in, const int* in_sizes, int n_in,
                              void* d_out, int out_size, void* d_ws, size_t ws_size,
                              hipStream_t stream) {
  const float* pi = (const float*)d_in[0];
  float* out = (float*)d_out;

  const size_t cand_bytes = (size_t)T_COLS * KC * sizeof(unsigned short); // 655,360
  const size_t gw_bytes   = (size_t)B_ROWS * T_COLS * KC * sizeof(float); // 167,772,160

  if (ws_size >= cand_bytes + gw_bytes) {
    unsigned short* candg = (unsigned short*)d_ws;
    float* gw = (float*)((char*)d_ws + cand_bytes);
    gumbel_kernel<<<dim3(T_COLS * B_ROWS), dim3(256), 0, stream>>>(gw);
    cand_kernel<<<dim3(T_COLS), dim3(256), 0, stream>>>(candg);
    mrf_seq_wave<<<dim3(B_ROWS), dim3(64), 0, stream>>>(pi, out, gw, candg);
  } else if (ws_size >= cand_bytes) {
    unsigned short* candg = (unsigned short*)d_ws;
    cand_kernel<<<dim3(T_COLS), dim3(256), 0, stream>>>(candg);
    mrf_seq_kernel<1><<<dim3(B_ROWS), dim3(BLOCK_S), 0, stream>>>(pi, out, nullptr, candg);
  } else {
    mrf_seq_kernel<0><<<dim3(B_ROWS), dim3(BLOCK_S), 0, stream>>>(pi, out, nullptr, nullptr);
  }
}

// Round 9
// 996.289 us; speedup vs baseline: 2.4512x; 1.0015x over previous
//
#include <hip/hip_runtime.h>
#include <stdint.h>
#include <math.h>

// ---------------------------------------------------------------------------
// MRF codebook generator: bit-exact reproduction of the JAX reference.
// Round 22: champion (R14/R21, 997.8 us) + ONE change: a single
// __builtin_amdgcn_sched_barrier(0) after the prefetch loop in STEP_BODY.
//  - Evidence: VGPR=100 at launch_bounds(64,1) (512 available) => the
//    pre-RA scheduler sinks part of the 40 prefetch loads toward their
//    next-step uses to cut register pressure, re-exposing L3/HBM latency
//    (~1500-2000 cy of the 6600 cy step; VALUBusy 8%).
//  - Ledger: R15 bundled this pinning WITH the readlane/hist/earg poison
//    (968 us); R20 measured the poison alone (991 us) => pinning was worth
//    -23 us on the poisoned base and was never tested on the clean champion.
//  - This is a pure scheduling directive: zero arithmetic changes, so
//    absmax must stay 0.0. Decision table: VGPR>=160 & dur<660 -> ship;
//    VGPR~100 & dur~701 -> null, revert; dur>730 -> spills, revert.
// Everything else is byte-identical to R21 (the re-validated champion).
// ---------------------------------------------------------------------------

#define JAX_PARTITIONABLE 1

#define T_COLS 256
#define B_ROWS 128
#define KC     1280
#define PTOP   1024
#define RRAND  256
#define WWIN   32
#define NCAND  20            // KC / 64
#define BLOCK_S 1024         // legacy fallback block
#define NWAVE_S (BLOCK_S / 64)

__device__ __constant__ int dC[17][17] = {
  {1},
  {1,1},
  {1,2,1},
  {1,3,3,1},
  {1,4,6,4,1},
  {1,5,10,10,5,1},
  {1,6,15,20,15,6,1},
  {1,7,21,35,35,21,7,1},
  {1,8,28,56,70,56,28,8,1},
  {1,9,36,84,126,126,84,36,9,1},
  {1,10,45,120,210,252,210,120,45,10,1},
  {1,11,55,165,330,462,462,330,165,55,11,1},
  {1,12,66,220,495,792,924,792,495,220,66,12,1},
  {1,13,78,286,715,1287,1716,1716,1287,715,286,78,13,1},
  {1,14,91,364,1001,2002,3003,3432,3003,2002,1001,364,91,14,1},
  {1,15,105,455,1365,3003,5005,6435,6435,5005,3003,1365,455,105,15,1},
  {1,16,120,560,1820,4368,8008,11440,12870,11440,8008,4368,1820,560,120,16,1}
};

// Threefry-2x32, 20 rounds, JAX key schedule.
__device__ __forceinline__ void tf_block(uint32_t k0, uint32_t k1,
                                         uint32_t x0, uint32_t x1,
                                         uint32_t& o0, uint32_t& o1) {
  uint32_t ks2 = k0 ^ k1 ^ 0x1BD11BDAu;
  x0 += k0; x1 += k1;
#define TFR(r) { x0 += x1; x1 = (x1 << (r)) | (x1 >> (32 - (r))); x1 ^= x0; }
  TFR(13) TFR(15) TFR(26) TFR(6)   x0 += k1;  x1 += ks2 + 1u;
  TFR(17) TFR(29) TFR(16) TFR(24)  x0 += ks2; x1 += k0 + 2u;
  TFR(13) TFR(15) TFR(26) TFR(6)   x0 += k0;  x1 += k1 + 3u;
  TFR(17) TFR(29) TFR(16) TFR(24)  x0 += k1;  x1 += ks2 + 4u;
  TFR(13) TFR(15) TFR(26) TFR(6)   x0 += ks2; x1 += k0 + 5u;
#undef TFR
  o0 = x0; o1 = x1;
}

// fold_in(key(42), step) -> k_rand/k_samp/randint-k2 per PRNG mode.
__device__ __forceinline__ void derive_keys(int step,
                                            uint32_t* krand, uint32_t* ksamp,
                                            uint32_t* k2) {
  uint32_t y0, y1;
  tf_block(0u, 42u, 0u, (uint32_t)step, y0, y1);
  uint32_t kr0 = y0, kr1 = y1;
#if JAX_PARTITIONABLE
  uint32_t r0, r1;
  tf_block(kr0, kr1, 0u, 0u, r0, r1);            // k_rand
  if (krand) { krand[0] = r0; krand[1] = r1; }
  if (ksamp) { tf_block(kr0, kr1, 0u, 1u, y0, y1); ksamp[0] = y0; ksamp[1] = y1; }
  if (k2)    { tf_block(r0, r1, 0u, 1u, y0, y1);  k2[0] = y0;  k2[1] = y1; }
#else
  uint32_t a0,a1,b0,b1;
  tf_block(kr0, kr1, 0u, 2u, a0, a1);
  tf_block(kr0, kr1, 1u, 3u, b0, b1);
  if (krand) { krand[0] = a0; krand[1] = b0; }
  if (ksamp) { ksamp[0] = a1; ksamp[1] = b1; }
  if (k2) {
    uint32_t c0,c1,d0,d1;
    tf_block(a0, b0, 0u, 2u, c0, c1);
    tf_block(a0, b0, 1u, 3u, d0, d1);
    k2[0] = c1; k2[1] = d1;
  }
#endif
}

// JAX uniform(tiny,1) -> gumbel, fp32 logs correctly-rounded-from-double.
__device__ __forceinline__ float gumbel_from_bits(uint32_t bits) {
  uint32_t fb = (bits >> 9) | 0x3f800000u;
  float f = __uint_as_float(fb) - 1.0f;
  float u = (f == 0.0f) ? 1.17549435e-38f : f;
  float l1 = (float)log((double)u);
  float l2 = (float)log((double)(-l1));
  return -l2;
}

__device__ __forceinline__ float gumbel_at(uint32_t ks0, uint32_t ks1, uint32_t j) {
  uint32_t g0, g1;
#if JAX_PARTITIONABLE
  tf_block(ks0, ks1, 0u, j, g0, g1);
  return gumbel_from_bits(g0 ^ g1);
#else
  uint32_t half = (uint32_t)(B_ROWS * KC / 2);
  if (j < half) { tf_block(ks0, ks1, j, j + half, g0, g1);  return gumbel_from_bits(g0); }
  else          { tf_block(ks0, ks1, j - half, j, g0, g1);  return gumbel_from_bits(g1); }
#endif
}

// ---------------- precompute kernel G: gumbel[b][step][k] -------------------
__global__ void __launch_bounds__(256)
gumbel_kernel(float* __restrict__ gw) {
  const int bb   = blockIdx.x & (B_ROWS - 1);
  const int step = blockIdx.x >> 7;
  const int tid  = threadIdx.x;
  __shared__ uint32_t s_ks[2];
  if (tid == 0) {
    uint32_t ks[2];
    derive_keys(step, nullptr, ks, nullptr);
    s_ks[0] = ks[0]; s_ks[1] = ks[1];
  }
  __syncthreads();
  const uint32_t ks0 = s_ks[0], ks1 = s_ks[1];
  const size_t base = ((size_t)bb * T_COLS + step) * KC;
#pragma unroll
  for (int i = 0; i < 5; ++i) {
    int k = tid + 256 * i;
    uint32_t j = (uint32_t)(bb * KC + k);
    gw[base + k] = gumbel_at(ks0, ks1, j);
  }
}

// ---------------- precompute kernel C: cand[step][k] ------------------------
__global__ void __launch_bounds__(256)
cand_kernel(unsigned short* __restrict__ candg) {
  const int step = blockIdx.x;
  const int tid  = threadIdx.x;
  __shared__ int s_dC[17][17];
  __shared__ int s_gw0[17], s_gw1[17], s_gbase[17];
  __shared__ int s_ngrp;
  __shared__ uint32_t s_k2[2];
  for (int i = tid; i < 289; i += 256) s_dC[i/17][i%17] = dC[i/17][i%17];
  if (tid == 0) {
    uint32_t k2[2];
    derive_keys(step, nullptr, nullptr, k2);
    s_k2[0] = k2[0]; s_k2[1] = k2[1];
    int ws[17], am[17];
    for (int w = 0; w < 17; ++w) {
      int m = 16 * w - 256 + step;
      am[w] = m < 0 ? -m : m;
      ws[w] = w;
    }
    for (int a2 = 1; a2 < 17; ++a2) {
      int wv = ws[a2], kv = am[wv];
      int j2 = a2 - 1;
      while (j2 >= 0 && am[ws[j2]] > kv) { ws[j2 + 1] = ws[j2]; --j2; }
      ws[j2 + 1] = wv;
    }
    int ng = 0, base = 0, idx = 0;
    while (idx < 17) {
      int w0 = ws[idx]; int a0v = am[w0]; int w1 = -1;
      if (idx + 1 < 17 && am[ws[idx + 1]] == a0v) { w1 = ws[idx + 1]; ++idx; }
      ++idx;
      s_gw0[ng] = w0; s_gw1[ng] = w1; s_gbase[ng] = base;
      base += dC[16][w0] + (w1 >= 0 ? dC[16][w1] : 0);
      ++ng;
      if (base >= PTOP) break;
    }
    s_ngrp = ng;
  }
  __syncthreads();
  for (int p = tid; p < PTOP; p += 256) {
    int g = 0;
    for (int t2 = 1; t2 < s_ngrp; ++t2) if (s_gbase[t2] <= p) g = t2;
    int q  = p - s_gbase[g];
    int r0 = s_gw0[g], r1 = s_gw1[g];
    uint32_t code = 0;
    for (int pos = 15; pos >= 0; --pos) {
      int n0 = ((r0 >= 0 && r0 <= pos) ? s_dC[pos][r0] : 0)
             + ((r1 >= 0 && r1 <= pos) ? s_dC[pos][r1] : 0);
      if (q >= n0) { q -= n0; code |= (1u << pos); --r0; if (r1 >= 0) --r1; }
    }
    candg[step * KC + p] = (unsigned short)code;
  }
  {
    int t2 = tid;
    uint32_t a0, a1;
#if JAX_PARTITIONABLE
    tf_block(s_k2[0], s_k2[1], 0u, (uint32_t)t2, a0, a1);
    candg[step * KC + PTOP + t2] = (unsigned short)((a0 ^ a1) & 0xFFFFu);
#else
    if (t2 < 128) { tf_block(s_k2[0], s_k2[1], (uint32_t)t2, (uint32_t)(128 + t2), a0, a1);
                    candg[step * KC + PTOP + t2] = (unsigned short)(a0 & 0xFFFFu); }
    else          { tf_block(s_k2[0], s_k2[1], (uint32_t)(t2 - 128), (uint32_t)t2, a0, a1);
                    candg[step * KC + PTOP + t2] = (unsigned short)(a1 & 0xFFFFu); }
#endif
  }
}

// ---------------- VALU-pipe cross-lane primitives ---------------------------
// Replacements for __shfl_down(x, off) that deliver the SAME source value to
// every lane on the lane-0 reduction lineage, but run on the VALU pipe
// (~4-8 cy dep latency) instead of LDS ds_bpermute/ds_swizzle (~120 cy).

// offset 32: v_permlane32_swap_b32 vdst,vsrc swaps vdst.row1 (lanes 32-63)
// with vsrc.row0 (lanes 0-31). With both operands = x, the vsrc result is
// [x.hi32, x.hi32]: lanes 0-31 receive lane i+32.  (Aliased-register case
// degenerates to a full swap, which still yields lane i+32 in lanes 0-31.)
__device__ __forceinline__ unsigned pl_down32_u(unsigned x) {
  unsigned d = x, s = x;
  asm volatile("s_nop 1\n\tv_permlane32_swap_b32 %0, %1" : "+v"(d), "+v"(s));
  return s;
}
// offset 16: v_permlane16_swap_b32 swaps vdst odd 16-rows with vsrc even
// 16-rows -> vsrc result rows = [x.r1, x.r1, x.r3, x.r3]: lanes 0-15 get
// lane i+16 (and lanes 32-47 get i+16, unused-but-consistent).
__device__ __forceinline__ unsigned pl_down16_u(unsigned x) {
  unsigned d = x, s = x;
  asm volatile("s_nop 1\n\tv_permlane16_swap_b32 %0, %1" : "+v"(d), "+v"(s));
  return s;
}
// offsets 8/4/2/1: DPP row_shl:N -> lane n receives lane n+N within its
// 16-lane row (rocPRIM scan convention: row_shr:N = lane n-N, so row_shl:N
// = lane n+N). bound_ctrl: out-of-row sources read 0 (only lanes outside
// the lane-0 lineage, never consumed).
template<int N>
__device__ __forceinline__ unsigned dpp_shl_u(unsigned x) {
  return (unsigned)__builtin_amdgcn_update_dpp(0, (int)x, 0x100 | N, 0xF, 0xF, true);
}
__device__ __forceinline__ float pl_down32_f(float x) {
  return __uint_as_float(pl_down32_u(__float_as_uint(x)));
}
__device__ __forceinline__ float pl_down16_f(float x) {
  return __uint_as_float(pl_down16_u(__float_as_uint(x)));
}
template<int N>
__device__ __forceinline__ float dpp_shl_f(float x) {
  return __uint_as_float(dpp_shl_u<N>(__float_as_uint(x)));
}
__device__ __forceinline__ double pl_down32_d(double x) {
  unsigned lo = pl_down32_u((unsigned)__double2loint(x));
  unsigned hi = pl_down32_u((unsigned)__double2hiint(x));
  return __hiloint2double((int)hi, (int)lo);
}
__device__ __forceinline__ double pl_down16_d(double x) {
  unsigned lo = pl_down16_u((unsigned)__double2loint(x));
  unsigned hi = pl_down16_u((unsigned)__double2hiint(x));
  return __hiloint2double((int)hi, (int)lo);
}
template<int N>
__device__ __forceinline__ double dpp_shl_d(double x) {
  unsigned lo = dpp_shl_u<N>((unsigned)__double2loint(x));
  unsigned hi = dpp_shl_u<N>((unsigned)__double2hiint(x));
  return __hiloint2double((int)hi, (int)lo);
}
// lane-0 broadcast (all lanes active at every call site) -> readfirstlane.
__device__ __forceinline__ float bcast0_f(float x) {
  return __uint_as_float((unsigned)__builtin_amdgcn_readfirstlane((int)__float_as_uint(x)));
}
__device__ __forceinline__ int bcast0_i(int x) {
  return __builtin_amdgcn_readfirstlane(x);
}
__device__ __forceinline__ double bcast0_d(double x) {
  int lo = __builtin_amdgcn_readfirstlane(__double2loint(x));
  int hi = __builtin_amdgcn_readfirstlane(__double2hiint(x));
  return __hiloint2double(hi, lo);
}

// ---------------- one-wave sequential kernel (MODE 2) -----------------------
// Step body macro: CC/GG = current-step cand/gumbel regs, CN/GN = prefetch
// target regs for step S+1. All loop indices are unroll-constant.
// R22 delta vs R21: sched_barrier(0) after the prefetch loop — pins the 40
// loads at body top so the pre-RA scheduler cannot sink them to next step's
// uses. Scheduling directive only; zero arithmetic changes.
#define STEP_BODY(S, CC, GG, CN, GN)                                          \
  {                                                                           \
    const int step = (S);                                                     \
    /* prefetch step+1 (full step of slack) */                                \
    const int sn = (step + 1 < T_COLS) ? step + 1 : step;                     \
    _Pragma("unroll")                                                         \
    for (int i = 0; i < NCAND; ++i) {                                         \
      CN[i] = candg[sn * KC + lane + 64 * i];                                 \
      GN[i] = gw[gb + (size_t)sn * KC + lane + 64 * i];                       \
    }                                                                         \
    __builtin_amdgcn_sched_barrier(0);  /* pin prefetch issue here */         \
    /* slide window state (lanes 0-15 hold per-bit f64 state) */              \
    if (lane < 16) {                                                          \
      if (step > 0) {                                                         \
        double pw = (double)s_pi[step - 1];                                   \
        if ((c_last >> lane) & 1u) p1_d += pw;                                \
        pt_d += pw;                                                           \
      }                                                                       \
      if (step >= 33) {                                                       \
        double pw = (double)s_pi[step - 33];                                  \
        if (((uint32_t)s_cint[step - 33] >> lane) & 1u) p1_d -= pw;           \
        pt_d -= pw;                                                           \
      }                                                                       \
    }                                                                         \
    float Dl = (float)(pt_d - (p1_d + p1_d));                                 \
    /* S0: 16-lane f64 xor-butterfly; on lane-0's lineage xor==+offset at    \
       every level, so row_shl 1,2,4,8 reproduces it bit-exactly. */          \
    double s0d = p1_d;                                                        \
    s0d += dpp_shl_d<1>(s0d);                                                 \
    s0d += dpp_shl_d<2>(s0d);                                                 \
    s0d += dpp_shl_d<4>(s0d);                                                 \
    s0d += dpp_shl_d<8>(s0d);                                                 \
    const float S0f  = bcast0_f((float)s0d);                                  \
    const float Pt16 = bcast0_f((float)(16.0 * pt_d));                        \
    {                                                                         \
      int n = lane >> 4, v = lane & 15;                                       \
      float d0 = __shfl(Dl, 4 * n + 0);                                       \
      float d1 = __shfl(Dl, 4 * n + 1);                                       \
      float d2 = __shfl(Dl, 4 * n + 2);                                       \
      float d3 = __shfl(Dl, 4 * n + 3);                                       \
      float t = 0.0f;                                                         \
      if (v & 1) t += d0;                                                     \
      if (v & 2) t += d1;                                                     \
      if (v & 4) t += d2;                                                     \
      if (v & 8) t += d3;                                                     \
      s_T[n][v] = t;                                                          \
    }                                                                         \
    __builtin_amdgcn_wave_barrier();                                          \
    const float pi_i   = s_pi[step];                                          \
    const float i_pf   = (float)step;                                         \
    const float factor = (step > 0) ? (i_pf / fminf(i_pf, 32.0f)) : 0.0f;     \
    float un[NCAND];                                                          \
    _Pragma("unroll")                                                         \
    for (int i = 0; i < NCAND; ++i) {                                         \
      uint32_t c = CC[i];                                                     \
      float sc = S0f + s_T[0][c & 15];                                        \
      sc += s_T[1][(c >> 4) & 15];                                            \
      sc += s_T[2][(c >> 8) & 15];                                            \
      sc += s_T[3][(c >> 12) & 15];                                           \
      float sv = Pt16 - sc;                                                   \
      int w = __popc(c);                                                      \
      int m = 16 * w - 256 + step;                                            \
      float sq  = (float)(m * m) * 0.00390625f;                               \
      float obk = (pi_i * sq) * 0.0625f;                                      \
      un[i] = -(obk + factor * (pi_i * sv));                                  \
    }                                                                         \
    /* rmax: exact global max (fmax associative-exact; hand tree + DPP) */    \
    float wt10[10];                                                           \
    _Pragma("unroll")                                                         \
    for (int q = 0; q < 10; ++q) wt10[q] = fmaxf(un[2*q], un[2*q+1]);         \
    float wt5[5];                                                             \
    _Pragma("unroll")                                                         \
    for (int q = 0; q < 5; ++q) wt5[q] = fmaxf(wt10[2*q], wt10[2*q+1]);       \
    float wm = fmaxf(fmaxf(fmaxf(wt5[0], wt5[1]), fmaxf(wt5[2], wt5[3])),     \
                     wt5[4]);                                                 \
    wm = fmaxf(wm, pl_down32_f(wm));                                          \
    wm = fmaxf(wm, pl_down16_f(wm));                                          \
    wm = fmaxf(wm, dpp_shl_f<8>(wm));                                         \
    wm = fmaxf(wm, dpp_shl_f<4>(wm));                                         \
    wm = fmaxf(wm, dpp_shl_f<2>(wm));                                         \
    wm = fmaxf(wm, dpp_shl_f<1>(wm));                                         \
    wm = bcast0_f(wm);                                                        \
    /* lsum: f64-accumulated fp32 exp terms (common-mode class); same        \
       shfl_down-shaped f64 tree, moved to VALU pipe. */                      \
    double a0 = 0.0, a1 = 0.0;                                                \
    _Pragma("unroll")                                                         \
    for (int i = 0; i < NCAND; ++i) {                                         \
      float e = expf(un[i] - wm);                                             \
      if (i & 1) a1 += (double)e; else a0 += (double)e;                       \
    }                                                                         \
    double sw = a0 + a1;                                                      \
    sw += pl_down32_d(sw);                                                    \
    sw += pl_down16_d(sw);                                                    \
    sw += dpp_shl_d<8>(sw);                                                   \
    sw += dpp_shl_d<4>(sw);                                                   \
    sw += dpp_shl_d<2>(sw);                                                   \
    sw += dpp_shl_d<1>(sw);                                                   \
    const float lsum = logf((float)bcast0_d(sw));                             \
    /* exact z argmax, lowest-k ties: per-lane adjacent-range tree (left     \
       wins ties => lowest slot, identical to the linear scan), then the     \
       same 6-level cross-lane tree with explicit (z, index) tie-break. */    \
    float z1[10]; int i1[10]; float u1[10];                                   \
    _Pragma("unroll")                                                         \
    for (int q = 0; q < 10; ++q) {                                            \
      float za = ((un[2*q]   - wm) - lsum) + GG[2*q];                         \
      float zb = ((un[2*q+1] - wm) - lsum) + GG[2*q+1];                       \
      int ia = (((64*(2*q)   + lane) << 16) | (int)CC[2*q]);                  \
      int ib = (((64*(2*q+1) + lane) << 16) | (int)CC[2*q+1]);                \
      bool tt = (zb > za);                                                    \
      z1[q] = tt ? zb : za; i1[q] = tt ? ib : ia;                             \
      u1[q] = tt ? un[2*q+1] : un[2*q];                                       \
    }                                                                         \
    float z2[5]; int i2[5]; float u2[5];                                      \
    _Pragma("unroll")                                                         \
    for (int q = 0; q < 5; ++q) {                                             \
      bool tt = (z1[2*q+1] > z1[2*q]);                                        \
      z2[q] = tt ? z1[2*q+1] : z1[2*q]; i2[q] = tt ? i1[2*q+1] : i1[2*q];     \
      u2[q] = tt ? u1[2*q+1] : u1[2*q];                                       \
    }                                                                         \
    float bz; int bi; float bu;                                               \
    {                                                                         \
      float zA, zB; int iA, iB; float uA, uB;                                 \
      bool t0 = (z2[1] > z2[0]);                                              \
      zA = t0 ? z2[1] : z2[0]; iA = t0 ? i2[1] : i2[0];                       \
      uA = t0 ? u2[1] : u2[0];                                                \
      bool t1 = (z2[3] > z2[2]);                                              \
      zB = t1 ? z2[3] : z2[2]; iB = t1 ? i2[3] : i2[2];                       \
      uB = t1 ? u2[3] : u2[2];                                                \
      bool t2 = (zB > zA);                                                    \
      zA = t2 ? zB : zA; iA = t2 ? iB : iA; uA = t2 ? uB : uA;                \
      bool t3 = (z2[4] > zA);                                                 \
      bz = t3 ? z2[4] : zA; bi = t3 ? i2[4] : iA; bu = t3 ? u2[4] : uA;       \
    }                                                                         \
    {                                                                         \
      float oz = pl_down32_f(bz); int oi = (int)pl_down32_u((unsigned)bi);    \
      float ou = pl_down32_f(bu);                                             \
      if (oz > bz || (oz == bz && oi < bi)) { bz = oz; bi = oi; bu = ou; }    \
    }                                                                         \
    {                                                                         \
      float oz = pl_down16_f(bz); int oi = (int)pl_down16_u((unsigned)bi);    \
      float ou = pl_down16_f(bu);                                             \
      if (oz > bz || (oz == bz && oi < bi)) { bz = oz; bi = oi; bu = ou; }    \
    }                                                                         \
    {                                                                         \
      float oz = dpp_shl_f<8>(bz); int oi = (int)dpp_shl_u<8>((unsigned)bi);  \
      float ou = dpp_shl_f<8>(bu);                                            \
      if (oz > bz || (oz == bz && oi < bi)) { bz = oz; bi = oi; bu = ou; }    \
    }                                                                         \
    {                                                                         \
      float oz = dpp_shl_f<4>(bz); int oi = (int)dpp_shl_u<4>((unsigned)bi);  \
      float ou = dpp_shl_f<4>(bu);                                             \
      if (oz > bz || (oz == bz && oi < bi)) { bz = oz; bi = oi; bu = ou; }    \
    }                                                                         \
    {                                                                         \
      float oz = dpp_shl_f<2>(bz); int oi = (int)dpp_shl_u<2>((unsigned)bi);  \
      float ou = dpp_shl_f<2>(bu);                                             \
      if (oz > bz || (oz == bz && oi < bi)) { bz = oz; bi = oi; bu = ou; }    \
    }                                                                         \
    {                                                                         \
      float oz = dpp_shl_f<1>(bz); int oi = (int)dpp_shl_u<1>((unsigned)bi);  \
      float ou = dpp_shl_f<1>(bu);                                             \
      if (oz > bz || (oz == bz && oi < bi)) { bz = oz; bi = oi; bu = ou; }    \
    }                                                                         \
    int wpk = bcast0_i(bi);                                                   \
    c_last = (uint32_t)wpk & 0xFFFFu;                                         \
    if (lane == 0) {                                                          \
      s_cint[step] = (unsigned short)c_last;                                  \
      lp_acc += (double)((bu - wm) - lsum);                                   \
    }                                                                         \
  }

__global__ void __launch_bounds__(64, 1)
mrf_seq_wave(const float* __restrict__ pi, float* __restrict__ out,
             const float* __restrict__ gw,
             const unsigned short* __restrict__ candg) {
#pragma clang fp contract(off)
  const int b    = blockIdx.x;
  const int lane = threadIdx.x;            // 0..63 (one wave)
  const size_t gb = (size_t)b * T_COLS * KC;

  __shared__ float          s_pi[T_COLS];
  __shared__ unsigned short s_cint[T_COLS];
  __shared__ float          s_T[4][16];

  for (int t = lane; t < T_COLS; t += 64) s_pi[t] = pi[t];
  __syncthreads();                          // one wave: cheap full fence

  double lp_acc = 0.0;                      // lane 0 only
  uint32_t c_last = 0;
  double p1_d = 0.0, pt_d = 0.0;            // sliding window state (lanes<16)

  // prologue: load step-0 data into A buffers
  float    gA[NCAND], gB[NCAND];
  uint32_t cA[NCAND], cB[NCAND];
#pragma unroll
  for (int i = 0; i < NCAND; ++i) {
    cA[i] = candg[lane + 64 * i];
    gA[i] = gw[gb + lane + 64 * i];
  }

  for (int s2 = 0; s2 < T_COLS; s2 += 2) {
    STEP_BODY(s2,     cA, gA, cB, gB)
    STEP_BODY(s2 + 1, cB, gB, cA, gA)
  }

  __syncthreads();
  // outputs (FP32): c_btls one-hot [B,T,L,S] then log_prob_b [B]
  for (int idx2 = lane; idx2 < T_COLS * 32; idx2 += 64) {
    int t    = idx2 >> 5;
    int rem  = idx2 & 31;
    int l    = rem >> 1;
    int sbit = rem & 1;
    uint32_t code = s_cint[t];
    int bit = (int)((code >> (15 - l)) & 1u);
    out[(size_t)b * 8192 + idx2] = (float)(sbit ? bit : (1 - bit));
  }
  if (lane == 0) {
    out[(size_t)B_ROWS * 8192 + b] = (float)(lp_acc / 256.0);
  }
}

// ---------------- legacy sequential kernel (fallback modes 0/1) -------------
template<int MODE>
__global__ void __launch_bounds__(BLOCK_S)
mrf_seq_kernel(const float* __restrict__ pi, float* __restrict__ out,
               const float* __restrict__ gw,
               const unsigned short* __restrict__ candg) {
#pragma clang fp contract(off)
  const int b    = blockIdx.x;
  const int tid  = threadIdx.x;
  const bool has1 = tid < (KC - BLOCK_S);

  __shared__ float          s_pi[T_COLS];
  __shared__ unsigned short s_cand[KC];
  __shared__ float          s_unnorm[KC];
  __shared__ unsigned short s_cint[T_COLS];
  __shared__ int            s_dC[17][17];
  __shared__ int            s_gw0[17], s_gw1[17], s_gbase[17];
  __shared__ int            s_ngrp;
  __shared__ uint32_t       s_keys[6];
  __shared__ float          s_pw[WWIN];
  __shared__ unsigned short s_wc[WWIN];
  __shared__ float          s_redf[NWAVE_S];
  __shared__ double         s_redd[NWAVE_S];
  __shared__ int            s_redi[NWAVE_S];
  __shared__ float          s_bcast[2];

  for (int t = tid; t < T_COLS; t += BLOCK_S) s_pi[t] = pi[t];
  if (MODE == 0) {
    for (int i = tid; i < 289; i += BLOCK_S) s_dC[i/17][i%17] = dC[i/17][i%17];
  }
  double lp_acc = 0.0;
  __syncthreads();

  for (int step = 0; step < T_COLS; ++step) {
    if (MODE <= 1 && tid == 0) {
      if (MODE == 1) {
        uint32_t ks[2];
        derive_keys(step, nullptr, ks, nullptr);
        s_keys[2] = ks[0]; s_keys[3] = ks[1];
      } else {
        uint32_t ks[2], k2[2];
        derive_keys(step, nullptr, ks, k2);
        s_keys[2] = ks[0]; s_keys[3] = ks[1];
        s_keys[4] = k2[0]; s_keys[5] = k2[1];
        int ws[17], am[17];
        for (int w = 0; w < 17; ++w) {
          int m = 16 * w - 256 + step;
          am[w] = m < 0 ? -m : m;
          ws[w] = w;
        }
        for (int a2 = 1; a2 < 17; ++a2) {
          int wvv = ws[a2], kv = am[wvv];
          int j2 = a2 - 1;
          while (j2 >= 0 && am[ws[j2]] > kv) { ws[j2 + 1] = ws[j2]; --j2; }
          ws[j2 + 1] = wvv;
        }
        int ng = 0, base = 0, idx = 0;
        while (idx < 17) {
          int w0 = ws[idx]; int a0v = am[w0]; int w1 = -1;
          if (idx + 1 < 17 && am[ws[idx + 1]] == a0v) { w1 = ws[idx + 1]; ++idx; }
          ++idx;
          s_gw0[ng] = w0; s_gw1[ng] = w1; s_gbase[ng] = base;
          base += dC[16][w0] + (w1 >= 0 ? dC[16][w1] : 0);
          ++ng;
          if (base >= PTOP) break;
        }
        s_ngrp = ng;
      }
    }
    if (tid < WWIN) {
      int win = step - WWIN + tid;
      s_pw[tid] = (win >= 0) ? s_pi[win] : 0.0f;
      s_wc[tid] = (win >= 0) ? s_cint[win] : (unsigned short)0;
    }
    __syncthreads();

    uint32_t c0, c1 = 0;
    if (MODE >= 1) {
      c0 = candg[step * KC + tid];
      if (has1) c1 = candg[step * KC + BLOCK_S + tid];
    } else {
      {
        int p = tid;
        int g = 0;
        for (int t2 = 1; t2 < s_ngrp; ++t2) if (s_gbase[t2] <= p) g = t2;
        int q  = p - s_gbase[g];
        int r0 = s_gw0[g], r1 = s_gw1[g];
        uint32_t code = 0;
        for (int pos = 15; pos >= 0; --pos) {
          int n0 = ((r0 >= 0 && r0 <= pos) ? s_dC[pos][r0] : 0)
                 + ((r1 >= 0 && r1 <= pos) ? s_dC[pos][r1] : 0);
          if (q >= n0) { q -= n0; code |= (1u << pos); --r0; if (r1 >= 0) --r1; }
        }
        c0 = code;
      }
      if (has1) {
        int t2 = tid;
        uint32_t a0, a1;
#if JAX_PARTITIONABLE
        tf_block(s_keys[4], s_keys[5], 0u, (uint32_t)t2, a0, a1);
        c1 = (a0 ^ a1) & 0xFFFFu;
#else
        if (t2 < 128) { tf_block(s_keys[4], s_keys[5], (uint32_t)t2, (uint32_t)(128 + t2), a0, a1);
                        c1 = a0 & 0xFFFFu; }
        else          { tf_block(s_keys[4], s_keys[5], (uint32_t)(t2 - 128), (uint32_t)t2, a0, a1);
                        c1 = a1 & 0xFFFFu; }
#endif
      }
    }
    s_cand[tid] = (unsigned short)c0;
    if (has1) s_cand[BLOCK_S + tid] = (unsigned short)c1;

    const float pi_i   = s_pi[step];
    const float i_pf   = (float)step;
    const float factor = (step > 0) ? (i_pf / fminf(i_pf, 32.0f)) : 0.0f;

    float un0, un1 = -3.402823466e+38f;
    {
      int w = __popc(c0);
      int m = 16 * w - 256 + step;
      float sq  = (float)(m * m) * 0.00390625f;
      float obk = (pi_i * sq) * 0.0625f;
      float s = 0.0f;
      for (int w2 = 0; w2 < WWIN; ++w2) {
        float ov = (float)(16 - __popc(c0 ^ (uint32_t)s_wc[w2]));
        s = s + s_pw[w2] * ov;
      }
      un0 = -(obk + factor * (pi_i * s));
    }
    if (has1) {
      int w = __popc(c1);
      int m = 16 * w - 256 + step;
      float sq  = (float)(m * m) * 0.00390625f;
      float obk = (pi_i * sq) * 0.0625f;
      float s = 0.0f;
      for (int w2 = 0; w2 < WWIN; ++w2) {
        float ov = (float)(16 - __popc(c1 ^ (uint32_t)s_wc[w2]));
        s = s + s_pw[w2] * ov;
      }
      un1 = -(obk + factor * (pi_i * s));
    }
    s_unnorm[tid] = un0;
    if (has1) s_unnorm[BLOCK_S + tid] = un1;

    float g0v = 0.0f, g1v = 0.0f;
    if (MODE == 2) {
      const size_t gbase = ((size_t)b * T_COLS + step) * KC;
      g0v = gw[gbase + tid];
      if (has1) g1v = gw[gbase + BLOCK_S + tid];
    } else {
      const uint32_t ks0 = s_keys[2], ks1 = s_keys[3];
      g0v = gumbel_at(ks0, ks1, (uint32_t)(b * KC + tid));
      if (has1) g1v = gumbel_at(ks0, ks1, (uint32_t)(b * KC + BLOCK_S + tid));
    }

    float pmax = has1 ? fmaxf(un0, un1) : un0;
    for (int off = 32; off > 0; off >>= 1) pmax = fmaxf(pmax, __shfl_down(pmax, off));
    if ((tid & 63) == 0) s_redf[tid >> 6] = pmax;
    __syncthreads();
    if (tid == 0) {
      float mm = s_redf[0];
      for (int w2 = 1; w2 < NWAVE_S; ++w2) mm = fmaxf(mm, s_redf[w2]);
      s_bcast[0] = mm;
    }
    __syncthreads();
    const float rmax = s_bcast[0];

    double acc = (double)((float)exp((double)(un0 - rmax)));
    if (has1) acc += (double)((float)exp((double)(un1 - rmax)));
    for (int off = 32; off > 0; off >>= 1) acc += __shfl_down(acc, off);
    if ((tid & 63) == 0) s_redd[tid >> 6] = acc;
    __syncthreads();
    if (tid == 0) {
      double ss = 0.0;
      for (int w2 = 0; w2 < NWAVE_S; ++w2) ss += s_redd[w2];
      float sum_f = (float)ss;
      s_bcast[1] = (float)log((double)sum_f);
    }
    __syncthreads();
    const float lsum = s_bcast[1];

    float bz = ((un0 - rmax) - lsum) + g0v;
    int   bi = tid;
    if (has1) {
      float z1 = ((un1 - rmax) - lsum) + g1v;
      if (z1 > bz) { bz = z1; bi = BLOCK_S + tid; }
    }
    for (int off = 32; off > 0; off >>= 1) {
      float oz = __shfl_down(bz, off);
      int   oi = __shfl_down(bi, off);
      if (oz > bz || (oz == bz && oi < bi)) { bz = oz; bi = oi; }
    }
    if ((tid & 63) == 0) { s_redf[tid >> 6] = bz; s_redi[tid >> 6] = bi; }
    __syncthreads();
    if (tid == 0) {
      float bz2 = s_redf[0]; int bi2 = s_redi[0];
      for (int w2 = 1; w2 < NWAVE_S; ++w2) {
        if (s_redf[w2] > bz2 || (s_redf[w2] == bz2 && s_redi[w2] < bi2)) {
          bz2 = s_redf[w2]; bi2 = s_redi[w2];
        }
      }
      s_cint[step] = s_cand[bi2];
      float lpw = (s_unnorm[bi2] - rmax) - lsum;
      lp_acc += (double)lpw;
    }
    __syncthreads();
  }

  for (int idx2 = tid; idx2 < T_COLS * 32; idx2 += BLOCK_S) {
    int t    = idx2 >> 5;
    int rem  = idx2 & 31;
    int l    = rem >> 1;
    int sbit = rem & 1;
    uint32_t code = s_cint[t];
    int bit = (int)((code >> (15 - l)) & 1u);
    out[(size_t)b * 8192 + idx2] = (float)(sbit ? bit : (1 - bit));
  }
  if (tid == 0) {
    out[(size_t)B_ROWS * 8192 + b] = (float)(lp_acc / 256.0);
  }
}

extern "C" void kernel_launch(void* const* d_in, const int* in_sizes, int n_in,
                              void* d_out, int out_size, void* d_ws, size_t ws_size,
                              hipStream_t stream) {
  const float* pi = (const float*)d_in[0];
  float* out = (float*)d_out;

  const size_t cand_bytes = (size_t)T_COLS * KC * sizeof(unsigned short); // 655,360
  const size_t gw_bytes   = (size_t)B_ROWS * T_COLS * KC * sizeof(float); // 167,772,160

  if (ws_size >= cand_bytes + gw_bytes) {
    unsigned short* candg = (unsigned short*)d_ws;
    float* gw = (float*)((char*)d_ws + cand_bytes);
    gumbel_kernel<<<dim3(T_COLS * B_ROWS), dim3(256), 0, stream>>>(gw);
    cand_kernel<<<dim3(T_COLS), dim3(256), 0, stream>>>(candg);
    mrf_seq_wave<<<dim3(B_ROWS), dim3(64), 0, stream>>>(pi, out, gw, candg);
  } else if (ws_size >= cand_bytes) {
    unsigned short* candg = (unsigned short*)d_ws;
    cand_kernel<<<dim3(T_COLS), dim3(256), 0, stream>>>(candg);
    mrf_seq_kernel<1><<<dim3(B_ROWS), dim3(BLOCK_S), 0, stream>>>(pi, out, nullptr, candg);
  } else {
    mrf_seq_kernel<0><<<dim3(B_ROWS), dim3(BLOCK_S), 0, stream>>>(pi, out, nullptr, nullptr);
  }
}

// Round 10
// 879.381 us; speedup vs baseline: 2.7770x; 1.1329x over previous
//
#include <hip/hip_runtime.h>
#include <stdint.h>
#include <math.h>

// ---------------------------------------------------------------------------
// MRF codebook generator: bit-exact reproduction of the JAX reference.
// Round 23: symmetric 4-wave candidate split of the sequential sampler.
//  - R22 closed the prefetch-sink theory (sched_barrier null). The champion
//    step (6550 cy) is issue+dep-latency bound on ONE wave (1 of 4 SIMDs,
//    VALUBusy 8%). Steps are serial and B=128 is fixed, so the remaining
//    parallelism axis is the per-step candidate work: 20 cands/lane -> 4
//    lockstep waves x 5 cands/lane on the 4 SIMDs of one CU.
//  - Three combine points per step (rmax, lsum-partial, argmax) via LDS +
//    raw {s_waitcnt lgkmcnt(0); s_barrier} (no vmcnt drain -> prefetch
//    loads stay in flight across barriers, full-body slack preserved).
//  - Numerics: un/wm/z/argmax bit-identical (max exact; argmax uses the
//    explicit (z, lowest-k) total-order compare, partition-invariant).
//    Only the f64 ASSOCIATION of the exp-sum changes (4 fixed-order
//    partials); lsum is rounded to f32 and is a common additive constant
//    in every z -> sampled codes invariant except ~2^-26 boundary events;
//    worst case is <=1-ulp wobble in log_prob_b.
//  - Scalar parts (window f64 state, S0 butterfly, T-build) duplicated per
//    wave (parallel, identical values; s_T same-value writes are benign).
//    All waves derive identical c_last from the identical combined argmax.
//  - R17 difference: those were ASYMMETRIC producer/consumer waves with
//    different workloads; these are symmetric lockstep waves.
// Precompute kernels and fallbacks unchanged.
// ---------------------------------------------------------------------------

#define JAX_PARTITIONABLE 1

#define T_COLS 256
#define B_ROWS 128
#define KC     1280
#define PTOP   1024
#define RRAND  256
#define WWIN   32
#define NCAND  20            // KC / 64
#define NWAVES 4             // sampler waves per block
#define NCPL   5             // candidates per lane per wave (NCAND/NWAVES)
#define BLOCK_S 1024         // legacy fallback block
#define NWAVE_S (BLOCK_S / 64)

__device__ __constant__ int dC[17][17] = {
  {1},
  {1,1},
  {1,2,1},
  {1,3,3,1},
  {1,4,6,4,1},
  {1,5,10,10,5,1},
  {1,6,15,20,15,6,1},
  {1,7,21,35,35,21,7,1},
  {1,8,28,56,70,56,28,8,1},
  {1,9,36,84,126,126,84,36,9,1},
  {1,10,45,120,210,252,210,120,45,10,1},
  {1,11,55,165,330,462,462,330,165,55,11,1},
  {1,12,66,220,495,792,924,792,495,220,66,12,1},
  {1,13,78,286,715,1287,1716,1716,1287,715,286,78,13,1},
  {1,14,91,364,1001,2002,3003,3432,3003,2002,1001,364,91,14,1},
  {1,15,105,455,1365,3003,5005,6435,6435,5005,3003,1365,455,105,15,1},
  {1,16,120,560,1820,4368,8008,11440,12870,11440,8008,4368,1820,560,120,16,1}
};

// Threefry-2x32, 20 rounds, JAX key schedule.
__device__ __forceinline__ void tf_block(uint32_t k0, uint32_t k1,
                                         uint32_t x0, uint32_t x1,
                                         uint32_t& o0, uint32_t& o1) {
  uint32_t ks2 = k0 ^ k1 ^ 0x1BD11BDAu;
  x0 += k0; x1 += k1;
#define TFR(r) { x0 += x1; x1 = (x1 << (r)) | (x1 >> (32 - (r))); x1 ^= x0; }
  TFR(13) TFR(15) TFR(26) TFR(6)   x0 += k1;  x1 += ks2 + 1u;
  TFR(17) TFR(29) TFR(16) TFR(24)  x0 += ks2; x1 += k0 + 2u;
  TFR(13) TFR(15) TFR(26) TFR(6)   x0 += k0;  x1 += k1 + 3u;
  TFR(17) TFR(29) TFR(16) TFR(24)  x0 += k1;  x1 += ks2 + 4u;
  TFR(13) TFR(15) TFR(26) TFR(6)   x0 += ks2; x1 += k0 + 5u;
#undef TFR
  o0 = x0; o1 = x1;
}

// fold_in(key(42), step) -> k_rand/k_samp/randint-k2 per PRNG mode.
__device__ __forceinline__ void derive_keys(int step,
                                            uint32_t* krand, uint32_t* ksamp,
                                            uint32_t* k2) {
  uint32_t y0, y1;
  tf_block(0u, 42u, 0u, (uint32_t)step, y0, y1);
  uint32_t kr0 = y0, kr1 = y1;
#if JAX_PARTITIONABLE
  uint32_t r0, r1;
  tf_block(kr0, kr1, 0u, 0u, r0, r1);            // k_rand
  if (krand) { krand[0] = r0; krand[1] = r1; }
  if (ksamp) { tf_block(kr0, kr1, 0u, 1u, y0, y1); ksamp[0] = y0; ksamp[1] = y1; }
  if (k2)    { tf_block(r0, r1, 0u, 1u, y0, y1);  k2[0] = y0;  k2[1] = y1; }
#else
  uint32_t a0,a1,b0,b1;
  tf_block(kr0, kr1, 0u, 2u, a0, a1);
  tf_block(kr0, kr1, 1u, 3u, b0, b1);
  if (krand) { krand[0] = a0; krand[1] = b0; }
  if (ksamp) { ksamp[0] = a1; ksamp[1] = b1; }
  if (k2) {
    uint32_t c0,c1,d0,d1;
    tf_block(a0, b0, 0u, 2u, c0, c1);
    tf_block(a0, b0, 1u, 3u, d0, d1);
    k2[0] = c1; k2[1] = d1;
  }
#endif
}

// JAX uniform(tiny,1) -> gumbel, fp32 logs correctly-rounded-from-double.
__device__ __forceinline__ float gumbel_from_bits(uint32_t bits) {
  uint32_t fb = (bits >> 9) | 0x3f800000u;
  float f = __uint_as_float(fb) - 1.0f;
  float u = (f == 0.0f) ? 1.17549435e-38f : f;
  float l1 = (float)log((double)u);
  float l2 = (float)log((double)(-l1));
  return -l2;
}

__device__ __forceinline__ float gumbel_at(uint32_t ks0, uint32_t ks1, uint32_t j) {
  uint32_t g0, g1;
#if JAX_PARTITIONABLE
  tf_block(ks0, ks1, 0u, j, g0, g1);
  return gumbel_from_bits(g0 ^ g1);
#else
  uint32_t half = (uint32_t)(B_ROWS * KC / 2);
  if (j < half) { tf_block(ks0, ks1, j, j + half, g0, g1);  return gumbel_from_bits(g0); }
  else          { tf_block(ks0, ks1, j - half, j, g0, g1);  return gumbel_from_bits(g1); }
#endif
}

// ---------------- precompute kernel G: gumbel[b][step][k] -------------------
__global__ void __launch_bounds__(256)
gumbel_kernel(float* __restrict__ gw) {
  const int bb   = blockIdx.x & (B_ROWS - 1);
  const int step = blockIdx.x >> 7;
  const int tid  = threadIdx.x;
  __shared__ uint32_t s_ks[2];
  if (tid == 0) {
    uint32_t ks[2];
    derive_keys(step, nullptr, ks, nullptr);
    s_ks[0] = ks[0]; s_ks[1] = ks[1];
  }
  __syncthreads();
  const uint32_t ks0 = s_ks[0], ks1 = s_ks[1];
  const size_t base = ((size_t)bb * T_COLS + step) * KC;
#pragma unroll
  for (int i = 0; i < 5; ++i) {
    int k = tid + 256 * i;
    uint32_t j = (uint32_t)(bb * KC + k);
    gw[base + k] = gumbel_at(ks0, ks1, j);
  }
}

// ---------------- precompute kernel C: cand[step][k] ------------------------
__global__ void __launch_bounds__(256)
cand_kernel(unsigned short* __restrict__ candg) {
  const int step = blockIdx.x;
  const int tid  = threadIdx.x;
  __shared__ int s_dC[17][17];
  __shared__ int s_gw0[17], s_gw1[17], s_gbase[17];
  __shared__ int s_ngrp;
  __shared__ uint32_t s_k2[2];
  for (int i = tid; i < 289; i += 256) s_dC[i/17][i%17] = dC[i/17][i%17];
  if (tid == 0) {
    uint32_t k2[2];
    derive_keys(step, nullptr, nullptr, k2);
    s_k2[0] = k2[0]; s_k2[1] = k2[1];
    int ws[17], am[17];
    for (int w = 0; w < 17; ++w) {
      int m = 16 * w - 256 + step;
      am[w] = m < 0 ? -m : m;
      ws[w] = w;
    }
    for (int a2 = 1; a2 < 17; ++a2) {
      int wv = ws[a2], kv = am[wv];
      int j2 = a2 - 1;
      while (j2 >= 0 && am[ws[j2]] > kv) { ws[j2 + 1] = ws[j2]; --j2; }
      ws[j2 + 1] = wv;
    }
    int ng = 0, base = 0, idx = 0;
    while (idx < 17) {
      int w0 = ws[idx]; int a0v = am[w0]; int w1 = -1;
      if (idx + 1 < 17 && am[ws[idx + 1]] == a0v) { w1 = ws[idx + 1]; ++idx; }
      ++idx;
      s_gw0[ng] = w0; s_gw1[ng] = w1; s_gbase[ng] = base;
      base += dC[16][w0] + (w1 >= 0 ? dC[16][w1] : 0);
      ++ng;
      if (base >= PTOP) break;
    }
    s_ngrp = ng;
  }
  __syncthreads();
  for (int p = tid; p < PTOP; p += 256) {
    int g = 0;
    for (int t2 = 1; t2 < s_ngrp; ++t2) if (s_gbase[t2] <= p) g = t2;
    int q  = p - s_gbase[g];
    int r0 = s_gw0[g], r1 = s_gw1[g];
    uint32_t code = 0;
    for (int pos = 15; pos >= 0; --pos) {
      int n0 = ((r0 >= 0 && r0 <= pos) ? s_dC[pos][r0] : 0)
             + ((r1 >= 0 && r1 <= pos) ? s_dC[pos][r1] : 0);
      if (q >= n0) { q -= n0; code |= (1u << pos); --r0; if (r1 >= 0) --r1; }
    }
    candg[step * KC + p] = (unsigned short)code;
  }
  {
    int t2 = tid;
    uint32_t a0, a1;
#if JAX_PARTITIONABLE
    tf_block(s_k2[0], s_k2[1], 0u, (uint32_t)t2, a0, a1);
    candg[step * KC + PTOP + t2] = (unsigned short)((a0 ^ a1) & 0xFFFFu);
#else
    if (t2 < 128) { tf_block(s_k2[0], s_k2[1], (uint32_t)t2, (uint32_t)(128 + t2), a0, a1);
                    candg[step * KC + PTOP + t2] = (unsigned short)(a0 & 0xFFFFu); }
    else          { tf_block(s_k2[0], s_k2[1], (uint32_t)(t2 - 128), (uint32_t)t2, a0, a1);
                    candg[step * KC + PTOP + t2] = (unsigned short)(a1 & 0xFFFFu); }
#endif
  }
}

// ---------------- VALU-pipe cross-lane primitives ---------------------------
// offset 32: v_permlane32_swap_b32 with both operands = x -> vsrc result is
// [x.hi32, x.hi32]: lanes 0-31 receive lane i+32.
__device__ __forceinline__ unsigned pl_down32_u(unsigned x) {
  unsigned d = x, s = x;
  asm volatile("s_nop 1\n\tv_permlane32_swap_b32 %0, %1" : "+v"(d), "+v"(s));
  return s;
}
// offset 16: v_permlane16_swap_b32 -> lanes 0-15 get lane i+16.
__device__ __forceinline__ unsigned pl_down16_u(unsigned x) {
  unsigned d = x, s = x;
  asm volatile("s_nop 1\n\tv_permlane16_swap_b32 %0, %1" : "+v"(d), "+v"(s));
  return s;
}
// offsets 8/4/2/1: DPP row_shl:N -> lane n receives lane n+N within its row.
template<int N>
__device__ __forceinline__ unsigned dpp_shl_u(unsigned x) {
  return (unsigned)__builtin_amdgcn_update_dpp(0, (int)x, 0x100 | N, 0xF, 0xF, true);
}
__device__ __forceinline__ float pl_down32_f(float x) {
  return __uint_as_float(pl_down32_u(__float_as_uint(x)));
}
__device__ __forceinline__ float pl_down16_f(float x) {
  return __uint_as_float(pl_down16_u(__float_as_uint(x)));
}
template<int N>
__device__ __forceinline__ float dpp_shl_f(float x) {
  return __uint_as_float(dpp_shl_u<N>(__float_as_uint(x)));
}
__device__ __forceinline__ double pl_down32_d(double x) {
  unsigned lo = pl_down32_u((unsigned)__double2loint(x));
  unsigned hi = pl_down32_u((unsigned)__double2hiint(x));
  return __hiloint2double((int)hi, (int)lo);
}
__device__ __forceinline__ double pl_down16_d(double x) {
  unsigned lo = pl_down16_u((unsigned)__double2loint(x));
  unsigned hi = pl_down16_u((unsigned)__double2hiint(x));
  return __hiloint2double((int)hi, (int)lo);
}
template<int N>
__device__ __forceinline__ double dpp_shl_d(double x) {
  unsigned lo = dpp_shl_u<N>((unsigned)__double2loint(x));
  unsigned hi = dpp_shl_u<N>((unsigned)__double2hiint(x));
  return __hiloint2double((int)hi, (int)lo);
}
// lane-0 broadcast (all lanes active at every call site) -> readfirstlane.
__device__ __forceinline__ float bcast0_f(float x) {
  return __uint_as_float((unsigned)__builtin_amdgcn_readfirstlane((int)__float_as_uint(x)));
}
__device__ __forceinline__ int bcast0_i(int x) {
  return __builtin_amdgcn_readfirstlane(x);
}
__device__ __forceinline__ double bcast0_d(double x) {
  int lo = __builtin_amdgcn_readfirstlane(__double2loint(x));
  int hi = __builtin_amdgcn_readfirstlane(__double2hiint(x));
  return __hiloint2double(hi, lo);
}

// cross-wave barrier WITHOUT vmcnt drain: LDS writes visible (lgkmcnt) +
// s_barrier. Prefetch global loads stay in flight across it.
#define LGKM_BAR()                                                            \
  do {                                                                        \
    asm volatile("s_waitcnt lgkmcnt(0)" ::: "memory");                        \
    __builtin_amdgcn_s_barrier();                                             \
  } while (0)

// ---------------- 4-wave sequential kernel (MODE 2) -------------------------
// Wave wid handles candidates ig = NCPL*wid + i (i = 0..NCPL-1), k = 64*ig
// + lane. Three LDS combine points per step. CC/GG = current regs, CN/GN =
// prefetch regs for step S+1.
#define STEP_BODY4(S, CC, GG, CN, GN)                                         \
  {                                                                           \
    const int step = (S);                                                     \
    /* prefetch step+1 (full body of slack; barriers don't drain vmcnt) */    \
    const int sn = (step + 1 < T_COLS) ? step + 1 : step;                     \
    _Pragma("unroll")                                                         \
    for (int i = 0; i < NCPL; ++i) {                                          \
      CN[i] = candg[sn * KC + (NCPL * wid + i) * 64 + lane];                  \
      GN[i] = gw[gb + (size_t)sn * KC + (NCPL * wid + i) * 64 + lane];        \
    }                                                                         \
    /* slide window state (lanes 0-15, per wave, identical values) */         \
    if (lane < 16) {                                                          \
      if (step > 0) {                                                         \
        double pw = (double)s_pi[step - 1];                                   \
        if ((c_last >> lane) & 1u) p1_d += pw;                                \
        pt_d += pw;                                                           \
      }                                                                       \
      if (step >= 33) {                                                       \
        double pw = (double)s_pi[step - 33];                                  \
        if (((uint32_t)s_cint[step - 33] >> lane) & 1u) p1_d -= pw;           \
        pt_d -= pw;                                                           \
      }                                                                       \
    }                                                                         \
    float Dl = (float)(pt_d - (p1_d + p1_d));                                 \
    /* S0: 16-lane f64 butterfly on the lane-0 lineage (row_shl 1,2,4,8). */  \
    double s0d = p1_d;                                                        \
    s0d += dpp_shl_d<1>(s0d);                                                 \
    s0d += dpp_shl_d<2>(s0d);                                                 \
    s0d += dpp_shl_d<4>(s0d);                                                 \
    s0d += dpp_shl_d<8>(s0d);                                                 \
    const float S0f  = bcast0_f((float)s0d);                                  \
    const float Pt16 = bcast0_f((float)(16.0 * pt_d));                        \
    {                                                                         \
      /* T-build: identical values in every wave; same-value writes to s_T   \
         are benign. Each wave reads after its own wave_barrier. */           \
      int n = lane >> 4, v = lane & 15;                                       \
      float d0 = __shfl(Dl, 4 * n + 0);                                       \
      float d1 = __shfl(Dl, 4 * n + 1);                                       \
      float d2 = __shfl(Dl, 4 * n + 2);                                       \
      float d3 = __shfl(Dl, 4 * n + 3);                                       \
      float t = 0.0f;                                                         \
      if (v & 1) t += d0;                                                     \
      if (v & 2) t += d1;                                                     \
      if (v & 4) t += d2;                                                     \
      if (v & 8) t += d3;                                                     \
      s_T[n][v] = t;                                                          \
    }                                                                         \
    __builtin_amdgcn_wave_barrier();                                          \
    const float pi_i   = s_pi[step];                                          \
    const float i_pf   = (float)step;                                         \
    const float factor = (step > 0) ? (i_pf / fminf(i_pf, 32.0f)) : 0.0f;     \
    float un[NCPL];                                                           \
    _Pragma("unroll")                                                         \
    for (int i = 0; i < NCPL; ++i) {                                          \
      uint32_t c = CC[i];                                                     \
      float sc = S0f + s_T[0][c & 15];                                        \
      sc += s_T[1][(c >> 4) & 15];                                            \
      sc += s_T[2][(c >> 8) & 15];                                            \
      sc += s_T[3][(c >> 12) & 15];                                           \
      float sv = Pt16 - sc;                                                   \
      int w = __popc(c);                                                      \
      int m = 16 * w - 256 + step;                                            \
      float sq  = (float)(m * m) * 0.00390625f;                               \
      float obk = (pi_i * sq) * 0.0625f;                                      \
      un[i] = -(obk + factor * (pi_i * sv));                                  \
    }                                                                         \
    /* rmax: per-wave per-lane max of 5 (exact), combine 4 waves via LDS,    \
       then the 6-level cross-lane tree (max is association-free). */         \
    float wmw = fmaxf(fmaxf(fmaxf(un[0], un[1]), fmaxf(un[2], un[3])),        \
                      un[4]);                                                 \
    s_cf[wid][lane] = wmw;                                                    \
    LGKM_BAR();                                                               \
    float wm = fmaxf(fmaxf(s_cf[0][lane], s_cf[1][lane]),                     \
                     fmaxf(s_cf[2][lane], s_cf[3][lane]));                    \
    wm = fmaxf(wm, pl_down32_f(wm));                                          \
    wm = fmaxf(wm, pl_down16_f(wm));                                          \
    wm = fmaxf(wm, dpp_shl_f<8>(wm));                                         \
    wm = fmaxf(wm, dpp_shl_f<4>(wm));                                         \
    wm = fmaxf(wm, dpp_shl_f<2>(wm));                                         \
    wm = fmaxf(wm, dpp_shl_f<1>(wm));                                         \
    wm = bcast0_f(wm);                                                        \
    /* lsum: f64 partials (terms bit-identical; only f64 association        \
       changes, invisible after f32 rounding of the sum). */                  \
    double a0 = 0.0, a1 = 0.0;                                                \
    _Pragma("unroll")                                                         \
    for (int i = 0; i < NCPL; ++i) {                                          \
      float e = expf(un[i] - wm);                                             \
      if ((NCPL * wid + i) & 1) a1 += (double)e; else a0 += (double)e;        \
    }                                                                         \
    s_cd[wid][lane] = a0 + a1;                                                \
    LGKM_BAR();                                                               \
    double sw = ((s_cd[0][lane] + s_cd[1][lane]) + s_cd[2][lane])             \
                + s_cd[3][lane];                                              \
    sw += pl_down32_d(sw);                                                    \
    sw += pl_down16_d(sw);                                                    \
    sw += dpp_shl_d<8>(sw);                                                   \
    sw += dpp_shl_d<4>(sw);                                                   \
    sw += dpp_shl_d<2>(sw);                                                   \
    sw += dpp_shl_d<1>(sw);                                                   \
    const float lsum = logf((float)bcast0_d(sw));                             \
    /* argmax with explicit (z, lowest-k) total order: partition-invariant.  \
       Per-wave per-lane over 5, LDS combine over 4 waves, then the 6-level  \
       cross-lane tree (champion code). */                                    \
    float bz; int bi; float bu;                                               \
    {                                                                         \
      bz = ((un[0] - wm) - lsum) + GG[0];                                     \
      bi = ((64 * (NCPL * wid) + lane) << 16) | (int)CC[0];                   \
      bu = un[0];                                                             \
      _Pragma("unroll")                                                       \
      for (int i = 1; i < NCPL; ++i) {                                        \
        float zi = ((un[i] - wm) - lsum) + GG[i];                             \
        int   ii = ((64 * (NCPL * wid + i) + lane) << 16) | (int)CC[i];       \
        if (zi > bz || (zi == bz && ii < bi)) { bz = zi; bi = ii; bu = un[i]; }\
      }                                                                       \
    }                                                                         \
    s_cz[wid][lane] = bz; s_ci[wid][lane] = bi; s_cu[wid][lane] = bu;         \
    LGKM_BAR();                                                               \
    bz = s_cz[0][lane]; bi = s_ci[0][lane]; bu = s_cu[0][lane];               \
    _Pragma("unroll")                                                         \
    for (int w = 1; w < NWAVES; ++w) {                                        \
      float oz = s_cz[w][lane]; int oi = s_ci[w][lane];                       \
      float ou = s_cu[w][lane];                                               \
      if (oz > bz || (oz == bz && oi < bi)) { bz = oz; bi = oi; bu = ou; }    \
    }                                                                         \
    {                                                                         \
      float oz = pl_down32_f(bz); int oi = (int)pl_down32_u((unsigned)bi);    \
      float ou = pl_down32_f(bu);                                             \
      if (oz > bz || (oz == bz && oi < bi)) { bz = oz; bi = oi; bu = ou; }    \
    }                                                                         \
    {                                                                         \
      float oz = pl_down16_f(bz); int oi = (int)pl_down16_u((unsigned)bi);    \
      float ou = pl_down16_f(bu);                                             \
      if (oz > bz || (oz == bz && oi < bi)) { bz = oz; bi = oi; bu = ou; }    \
    }                                                                         \
    {                                                                         \
      float oz = dpp_shl_f<8>(bz); int oi = (int)dpp_shl_u<8>((unsigned)bi);  \
      float ou = dpp_shl_f<8>(bu);                                            \
      if (oz > bz || (oz == bz && oi < bi)) { bz = oz; bi = oi; bu = ou; }    \
    }                                                                         \
    {                                                                         \
      float oz = dpp_shl_f<4>(bz); int oi = (int)dpp_shl_u<4>((unsigned)bi);  \
      float ou = dpp_shl_f<4>(bu);                                            \
      if (oz > bz || (oz == bz && oi < bi)) { bz = oz; bi = oi; bu = ou; }    \
    }                                                                         \
    {                                                                         \
      float oz = dpp_shl_f<2>(bz); int oi = (int)dpp_shl_u<2>((unsigned)bi);  \
      float ou = dpp_shl_f<2>(bu);                                            \
      if (oz > bz || (oz == bz && oi < bi)) { bz = oz; bi = oi; bu = ou; }    \
    }                                                                         \
    {                                                                         \
      float oz = dpp_shl_f<1>(bz); int oi = (int)dpp_shl_u<1>((unsigned)bi);  \
      float ou = dpp_shl_f<1>(bu);                                            \
      if (oz > bz || (oz == bz && oi < bi)) { bz = oz; bi = oi; bu = ou; }    \
    }                                                                         \
    int wpk = bcast0_i(bi);                                                   \
    c_last = (uint32_t)wpk & 0xFFFFu;                                         \
    if (wid == 0 && lane == 0) {                                              \
      s_cint[step] = (unsigned short)c_last;                                  \
      lp_acc += (double)((bu - wm) - lsum);                                   \
    }                                                                         \
  }

__global__ void __launch_bounds__(256, 1)
mrf_seq_wave4(const float* __restrict__ pi, float* __restrict__ out,
              const float* __restrict__ gw,
              const unsigned short* __restrict__ candg) {
#pragma clang fp contract(off)
  const int b    = blockIdx.x;
  const int tid  = threadIdx.x;
  const int lane = tid & 63;
  const int wid  = tid >> 6;               // 0..3
  const size_t gb = (size_t)b * T_COLS * KC;

  __shared__ float          s_pi[T_COLS];
  __shared__ unsigned short s_cint[T_COLS];
  __shared__ float          s_T[4][16];
  __shared__ float          s_cf[NWAVES][64];   // rmax partials
  __shared__ double         s_cd[NWAVES][64];   // exp-sum partials
  __shared__ float          s_cz[NWAVES][64];   // argmax z
  __shared__ int            s_ci[NWAVES][64];   // argmax idx
  __shared__ float          s_cu[NWAVES][64];   // argmax un

  for (int t = tid; t < T_COLS; t += 256) s_pi[t] = pi[t];
  __syncthreads();

  double lp_acc = 0.0;                      // wave0 lane0 only
  uint32_t c_last = 0;
  double p1_d = 0.0, pt_d = 0.0;            // sliding window state (lanes<16)

  // prologue: load step-0 data into A buffers (per wave: its 5 candidates)
  float    gA[NCPL], gB[NCPL];
  uint32_t cA[NCPL], cB[NCPL];
#pragma unroll
  for (int i = 0; i < NCPL; ++i) {
    cA[i] = candg[(NCPL * wid + i) * 64 + lane];
    gA[i] = gw[gb + (NCPL * wid + i) * 64 + lane];
  }

  for (int s2 = 0; s2 < T_COLS; s2 += 2) {
    STEP_BODY4(s2,     cA, gA, cB, gB)
    STEP_BODY4(s2 + 1, cB, gB, cA, gA)
  }

  __syncthreads();
  // outputs (FP32): c_btls one-hot [B,T,L,S] then log_prob_b [B]
  for (int idx2 = tid; idx2 < T_COLS * 32; idx2 += 256) {
    int t    = idx2 >> 5;
    int rem  = idx2 & 31;
    int l    = rem >> 1;
    int sbit = rem & 1;
    uint32_t code = s_cint[t];
    int bit = (int)((code >> (15 - l)) & 1u);
    out[(size_t)b * 8192 + idx2] = (float)(sbit ? bit : (1 - bit));
  }
  if (tid == 0) {
    out[(size_t)B_ROWS * 8192 + b] = (float)(lp_acc / 256.0);
  }
}

// ---------------- legacy sequential kernel (fallback modes 0/1) -------------
template<int MODE>
__global__ void __launch_bounds__(BLOCK_S)
mrf_seq_kernel(const float* __restrict__ pi, float* __restrict__ out,
               const float* __restrict__ gw,
               const unsigned short* __restrict__ candg) {
#pragma clang fp contract(off)
  const int b    = blockIdx.x;
  const int tid  = threadIdx.x;
  const bool has1 = tid < (KC - BLOCK_S);

  __shared__ float          s_pi[T_COLS];
  __shared__ unsigned short s_cand[KC];
  __shared__ float          s_unnorm[KC];
  __shared__ unsigned short s_cint[T_COLS];
  __shared__ int            s_dC[17][17];
  __shared__ int            s_gw0[17], s_gw1[17], s_gbase[17];
  __shared__ int            s_ngrp;
  __shared__ uint32_t       s_keys[6];
  __shared__ float          s_pw[WWIN];
  __shared__ unsigned short s_wc[WWIN];
  __shared__ float          s_redf[NWAVE_S];
  __shared__ double         s_redd[NWAVE_S];
  __shared__ int            s_redi[NWAVE_S];
  __shared__ float          s_bcast[2];

  for (int t = tid; t < T_COLS; t += BLOCK_S) s_pi[t] = pi[t];
  if (MODE == 0) {
    for (int i = tid; i < 289; i += BLOCK_S) s_dC[i/17][i%17] = dC[i/17][i%17];
  }
  double lp_acc = 0.0;
  __syncthreads();

  for (int step = 0; step < T_COLS; ++step) {
    if (MODE <= 1 && tid == 0) {
      if (MODE == 1) {
        uint32_t ks[2];
        derive_keys(step, nullptr, ks, nullptr);
        s_keys[2] = ks[0]; s_keys[3] = ks[1];
      } else {
        uint32_t ks[2], k2[2];
        derive_keys(step, nullptr, ks, k2);
        s_keys[2] = ks[0]; s_keys[3] = ks[1];
        s_keys[4] = k2[0]; s_keys[5] = k2[1];
        int ws[17], am[17];
        for (int w = 0; w < 17; ++w) {
          int m = 16 * w - 256 + step;
          am[w] = m < 0 ? -m : m;
          ws[w] = w;
        }
        for (int a2 = 1; a2 < 17; ++a2) {
          int wvv = ws[a2], kv = am[wvv];
          int j2 = a2 - 1;
          while (j2 >= 0 && am[ws[j2]] > kv) { ws[j2 + 1] = ws[j2]; --j2; }
          ws[j2 + 1] = wvv;
        }
        int ng = 0, base = 0, idx = 0;
        while (idx < 17) {
          int w0 = ws[idx]; int a0v = am[w0]; int w1 = -1;
          if (idx + 1 < 17 && am[ws[idx + 1]] == a0v) { w1 = ws[idx + 1]; ++idx; }
          ++idx;
          s_gw0[ng] = w0; s_gw1[ng] = w1; s_gbase[ng] = base;
          base += dC[16][w0] + (w1 >= 0 ? dC[16][w1] : 0);
          ++ng;
          if (base >= PTOP) break;
        }
        s_ngrp = ng;
      }
    }
    if (tid < WWIN) {
      int win = step - WWIN + tid;
      s_pw[tid] = (win >= 0) ? s_pi[win] : 0.0f;
      s_wc[tid] = (win >= 0) ? s_cint[win] : (unsigned short)0;
    }
    __syncthreads();

    uint32_t c0, c1 = 0;
    if (MODE >= 1) {
      c0 = candg[step * KC + tid];
      if (has1) c1 = candg[step * KC + BLOCK_S + tid];
    } else {
      {
        int p = tid;
        int g = 0;
        for (int t2 = 1; t2 < s_ngrp; ++t2) if (s_gbase[t2] <= p) g = t2;
        int q  = p - s_gbase[g];
        int r0 = s_gw0[g], r1 = s_gw1[g];
        uint32_t code = 0;
        for (int pos = 15; pos >= 0; --pos) {
          int n0 = ((r0 >= 0 && r0 <= pos) ? s_dC[pos][r0] : 0)
                 + ((r1 >= 0 && r1 <= pos) ? s_dC[pos][r1] : 0);
          if (q >= n0) { q -= n0; code |= (1u << pos); --r0; if (r1 >= 0) --r1; }
        }
        c0 = code;
      }
      if (has1) {
        int t2 = tid;
        uint32_t a0, a1;
#if JAX_PARTITIONABLE
        tf_block(s_keys[4], s_keys[5], 0u, (uint32_t)t2, a0, a1);
        c1 = (a0 ^ a1) & 0xFFFFu;
#else
        if (t2 < 128) { tf_block(s_keys[4], s_keys[5], (uint32_t)t2, (uint32_t)(128 + t2), a0, a1);
                        c1 = a0 & 0xFFFFu; }
        else          { tf_block(s_keys[4], s_keys[5], (uint32_t)(t2 - 128), (uint32_t)t2, a0, a1);
                        c1 = a1 & 0xFFFFu; }
#endif
      }
    }
    s_cand[tid] = (unsigned short)c0;
    if (has1) s_cand[BLOCK_S + tid] = (unsigned short)c1;

    const float pi_i   = s_pi[step];
    const float i_pf   = (float)step;
    const float factor = (step > 0) ? (i_pf / fminf(i_pf, 32.0f)) : 0.0f;

    float un0, un1 = -3.402823466e+38f;
    {
      int w = __popc(c0);
      int m = 16 * w - 256 + step;
      float sq  = (float)(m * m) * 0.00390625f;
      float obk = (pi_i * sq) * 0.0625f;
      float s = 0.0f;
      for (int w2 = 0; w2 < WWIN; ++w2) {
        float ov = (float)(16 - __popc(c0 ^ (uint32_t)s_wc[w2]));
        s = s + s_pw[w2] * ov;
      }
      un0 = -(obk + factor * (pi_i * s));
    }
    if (has1) {
      int w = __popc(c1);
      int m = 16 * w - 256 + step;
      float sq  = (float)(m * m) * 0.00390625f;
      float obk = (pi_i * sq) * 0.0625f;
      float s = 0.0f;
      for (int w2 = 0; w2 < WWIN; ++w2) {
        float ov = (float)(16 - __popc(c1 ^ (uint32_t)s_wc[w2]));
        s = s + s_pw[w2] * ov;
      }
      un1 = -(obk + factor * (pi_i * s));
    }
    s_unnorm[tid] = un0;
    if (has1) s_unnorm[BLOCK_S + tid] = un1;

    float g0v = 0.0f, g1v = 0.0f;
    if (MODE == 2) {
      const size_t gbase = ((size_t)b * T_COLS + step) * KC;
      g0v = gw[gbase + tid];
      if (has1) g1v = gw[gbase + BLOCK_S + tid];
    } else {
      const uint32_t ks0 = s_keys[2], ks1 = s_keys[3];
      g0v = gumbel_at(ks0, ks1, (uint32_t)(b * KC + tid));
      if (has1) g1v = gumbel_at(ks0, ks1, (uint32_t)(b * KC + BLOCK_S + tid));
    }

    float pmax = has1 ? fmaxf(un0, un1) : un0;
    for (int off = 32; off > 0; off >>= 1) pmax = fmaxf(pmax, __shfl_down(pmax, off));
    if ((tid & 63) == 0) s_redf[tid >> 6] = pmax;
    __syncthreads();
    if (tid == 0) {
      float mm = s_redf[0];
      for (int w2 = 1; w2 < NWAVE_S; ++w2) mm = fmaxf(mm, s_redf[w2]);
      s_bcast[0] = mm;
    }
    __syncthreads();
    const float rmax = s_bcast[0];

    double acc = (double)((float)exp((double)(un0 - rmax)));
    if (has1) acc += (double)((float)exp((double)(un1 - rmax)));
    for (int off = 32; off > 0; off >>= 1) acc += __shfl_down(acc, off);
    if ((tid & 63) == 0) s_redd[tid >> 6] = acc;
    __syncthreads();
    if (tid == 0) {
      double ss = 0.0;
      for (int w2 = 0; w2 < NWAVE_S; ++w2) ss += s_redd[w2];
      float sum_f = (float)ss;
      s_bcast[1] = (float)log((double)sum_f);
    }
    __syncthreads();
    const float lsum = s_bcast[1];

    float bz = ((un0 - rmax) - lsum) + g0v;
    int   bi = tid;
    if (has1) {
      float z1 = ((un1 - rmax) - lsum) + g1v;
      if (z1 > bz) { bz = z1; bi = BLOCK_S + tid; }
    }
    for (int off = 32; off > 0; off >>= 1) {
      float oz = __shfl_down(bz, off);
      int   oi = __shfl_down(bi, off);
      if (oz > bz || (oz == bz && oi < bi)) { bz = oz; bi = oi; }
    }
    if ((tid & 63) == 0) { s_redf[tid >> 6] = bz; s_redi[tid >> 6] = bi; }
    __syncthreads();
    if (tid == 0) {
      float bz2 = s_redf[0]; int bi2 = s_redi[0];
      for (int w2 = 1; w2 < NWAVE_S; ++w2) {
        if (s_redf[w2] > bz2 || (s_redf[w2] == bz2 && s_redi[w2] < bi2)) {
          bz2 = s_redf[w2]; bi2 = s_redi[w2];
        }
      }
      s_cint[step] = s_cand[bi2];
      float lpw = (s_unnorm[bi2] - rmax) - lsum;
      lp_acc += (double)lpw;
    }
    __syncthreads();
  }

  for (int idx2 = tid; idx2 < T_COLS * 32; idx2 += BLOCK_S) {
    int t    = idx2 >> 5;
    int rem  = idx2 & 31;
    int l    = rem >> 1;
    int sbit = rem & 1;
    uint32_t code = s_cint[t];
    int bit = (int)((code >> (15 - l)) & 1u);
    out[(size_t)b * 8192 + idx2] = (float)(sbit ? bit : (1 - bit));
  }
  if (tid == 0) {
    out[(size_t)B_ROWS * 8192 + b] = (float)(lp_acc / 256.0);
  }
}

extern "C" void kernel_launch(void* const* d_in, const int* in_sizes, int n_in,
                              void* d_out, int out_size, void* d_ws, size_t ws_size,
                              hipStream_t stream) {
  const float* pi = (const float*)d_in[0];
  float* out = (float*)d_out;

  const size_t cand_bytes = (size_t)T_COLS * KC * sizeof(unsigned short); // 655,360
  const size_t gw_bytes   = (size_t)B_ROWS * T_COLS * KC * sizeof(float); // 167,772,160

  if (ws_size >= cand_bytes + gw_bytes) {
    unsigned short* candg = (unsigned short*)d_ws;
    float* gw = (float*)((char*)d_ws + cand_bytes);
    gumbel_kernel<<<dim3(T_COLS * B_ROWS), dim3(256), 0, stream>>>(gw);
    cand_kernel<<<dim3(T_COLS), dim3(256), 0, stream>>>(candg);
    mrf_seq_wave4<<<dim3(B_ROWS), dim3(256), 0, stream>>>(pi, out, gw, candg);
  } else if (ws_size >= cand_bytes) {
    unsigned short* candg = (unsigned short*)d_ws;
    cand_kernel<<<dim3(T_COLS), dim3(256), 0, stream>>>(candg);
    mrf_seq_kernel<1><<<dim3(B_ROWS), dim3(BLOCK_S), 0, stream>>>(pi, out, nullptr, candg);
  } else {
    mrf_seq_kernel<0><<<dim3(B_ROWS), dim3(BLOCK_S), 0, stream>>>(pi, out, nullptr, nullptr);
  }
}